// Round 1
// baseline (269.824 us; speedup 1.0000x reference)
//
#include <hip/hip_runtime.h>
#include <cstdint>
#include <cstddef>

#define NN 4096
#define FDIM 512
#define HDIM 64
#define NHEAD 8
#define CDIM 40
#define MAXD 256   // max neighbors kept per row (~41 expected, binomial tail negligible)

__device__ __forceinline__ float wave_max64(float v) {
  for (int o = 32; o; o >>= 1) v = fmaxf(v, __shfl_xor(v, o));
  return v;
}
__device__ __forceinline__ float wave_sum64(float v) {
  for (int o = 32; o; o >>= 1) v += __shfl_xor(v, o);
  return v;
}

// ---------------- Kernel 1: build ordered CSR from bias_mat (0.0f == edge) --
__global__ void k_build_csr(const float* __restrict__ bias,
                            int* __restrict__ nbr, int* __restrict__ cnt) {
  int row  = (blockIdx.x * blockDim.x + threadIdx.x) >> 6;
  int lane = threadIdx.x & 63;
  if (row >= NN) return;
  const float* r = bias + (size_t)row * NN;
  int base = 0;
  for (int c = 0; c < NN; c += 64) {
    float v = r[c + lane];
    bool pred = (v == 0.0f);
    unsigned long long mask = __ballot(pred);
    int pos = __popcll(mask & ((1ull << lane) - 1ull));
    if (pred && (base + pos) < MAXD) nbr[(size_t)row * MAXD + base + pos] = c + lane;
    base += __popcll(mask);
  }
  if (lane == 0) cnt[row] = base < MAXD ? base : MAXD;
}

// ---------------- Kernel 2: FTS[i][h*64+c] = seq @ W1 (all heads) -----------
// A: [4096][512], B(head h): W1[h][k][c], C: [4096][512]
__global__ __launch_bounds__(256) void k_gemm_fts(const float* __restrict__ A,
                                                  const float* __restrict__ W1,
                                                  float* __restrict__ C) {
  __shared__ float As[16][64 + 1];
  __shared__ float Bs[16][64 + 1];
  int bm = blockIdx.x;            // 64 row tiles
  int h  = blockIdx.y;            // 8 heads = col tiles of 64
  int tid = threadIdx.x;
  int tc = tid & 15, tr = tid >> 4;
  float acc[4][4] = {};
  const float* Bbase = W1 + (size_t)h * FDIM * HDIM;
  for (int k0 = 0; k0 < FDIM; k0 += 16) {
    for (int l = tid; l < 64 * 16; l += 256) {
      int r = l >> 4, c = l & 15;
      As[c][r] = A[(size_t)(bm * 64 + r) * FDIM + k0 + c];
    }
    for (int l = tid; l < 16 * 64; l += 256) {
      int r = l >> 6, c = l & 63;
      Bs[r][c] = Bbase[(size_t)(k0 + r) * HDIM + c];
    }
    __syncthreads();
#pragma unroll
    for (int kk = 0; kk < 16; ++kk) {
      float a[4], b[4];
#pragma unroll
      for (int i = 0; i < 4; ++i) a[i] = As[kk][tr * 4 + i];
#pragma unroll
      for (int j = 0; j < 4; ++j) b[j] = Bs[kk][tc * 4 + j];
#pragma unroll
      for (int i = 0; i < 4; ++i)
#pragma unroll
        for (int j = 0; j < 4; ++j) acc[i][j] += a[i] * b[j];
    }
    __syncthreads();
  }
#pragma unroll
  for (int i = 0; i < 4; ++i)
#pragma unroll
    for (int j = 0; j < 4; ++j)
      C[(size_t)(bm * 64 + tr * 4 + i) * FDIM + h * 64 + tc * 4 + j] = acc[i][j];
}

// ---------------- Kernel 3: f1/f2 = fts . a1/a2 + b ------------------------
__global__ void k_f12(const float* __restrict__ FTS,
                      const float* __restrict__ a1, const float* __restrict__ b1,
                      const float* __restrict__ a2, const float* __restrict__ b2,
                      float* __restrict__ F1, float* __restrict__ F2) {
  int gw = (blockIdx.x * blockDim.x + threadIdx.x) >> 6;
  int lane = threadIdx.x & 63;
  if (gw >= NN * NHEAD) return;
  int i = gw >> 3, h = gw & 7;
  float v = FTS[(size_t)i * FDIM + h * 64 + lane];
  float s1 = v * a1[h * 64 + lane];
  float s2 = v * a2[h * 64 + lane];
  s1 = wave_sum64(s1);
  s2 = wave_sum64(s2);
  if (lane == 0) {
    F1[(size_t)h * NN + i] = s1 + b1[h];
    F2[(size_t)h * NN + i] = s2 + b2[h];
  }
}

// ---------------- Kernel 4: sparse masked softmax + aggregation (layer 1) ---
__global__ void k_agg1(const float* __restrict__ FTS,
                       const float* __restrict__ F1, const float* __restrict__ F2,
                       const int* __restrict__ nbr, const int* __restrict__ cnt,
                       float* __restrict__ VALS) {
  int gw = (blockIdx.x * blockDim.x + threadIdx.x) >> 6;
  int lane = threadIdx.x & 63;
  if (gw >= NN * NHEAD) return;
  int i = gw >> 3, h = gw & 7;
  int deg = cnt[i];
  const int* nb = nbr + (size_t)i * MAXD;
  float f1i = F1[(size_t)h * NN + i];
  const float* F2h = F2 + (size_t)h * NN;

  int jreg[4];
  float p[4];
  float m = -1e30f;
#pragma unroll
  for (int r = 0; r < 4; ++r) { jreg[r] = 0; p[r] = -1e30f; }
#pragma unroll
  for (int r = 0; r < 4; ++r) {
    int t = r * 64 + lane;
    if (t < deg) {
      int j = nb[t];
      jreg[r] = j;
      float x = f1i + F2h[j];
      x = x >= 0.f ? x : 0.2f * x;     // leaky_relu(0.2)
      p[r] = x;
      m = fmaxf(m, x);
    }
  }
  m = wave_max64(m);
  float s = 0.f;
#pragma unroll
  for (int r = 0; r < 4; ++r) {
    int t = r * 64 + lane;
    float e = (t < deg) ? expf(p[r] - m) : 0.f;
    p[r] = e;
    s += e;
  }
  s = wave_sum64(s);

  float acc = 0.f;
  const float* Fh = FTS + h * 64;
#pragma unroll
  for (int r = 0; r < 4; ++r) {
    int base = r * 64;
    if (base >= deg) break;
    int lim = deg - base;
    lim = lim < 64 ? lim : 64;
    for (int sl = 0; sl < lim; ++sl) {
      float w = __shfl(p[r], sl);
      int j   = __shfl(jreg[r], sl);
      acc += w * Fh[(size_t)j * FDIM + lane];
    }
  }
  VALS[(size_t)i * FDIM + h * 64 + lane] = acc / s;
}

// ---------------- Kernel 5: head output = elu(vals @ W2 + bW) → H1 ---------
__global__ void k_headout(const float* __restrict__ VALS, const float* __restrict__ W2,
                          const float* __restrict__ bW, float* __restrict__ H1) {
  int gw = (blockIdx.x * blockDim.x + threadIdx.x) >> 6;
  int lane = threadIdx.x & 63;
  if (gw >= NN * NHEAD) return;
  int i = gw >> 3, h = gw & 7;
  float v = VALS[(size_t)i * FDIM + h * 64 + lane];
  const float* W2h = W2 + (size_t)h * HDIM * HDIM;
  float acc = bW[h * 64 + lane];
#pragma unroll 8
  for (int kk = 0; kk < 64; ++kk) {
    acc += __shfl(v, kk) * W2h[kk * 64 + lane];
  }
  acc = acc > 0.f ? acc : expm1f(acc);  // elu
  H1[(size_t)i * FDIM + h * 64 + lane] = acc;
}

// ---------------- Kernel 6: fts2 = H1 @ Wo1; f1o/f2o fused ------------------
__global__ void k_fts2(const float* __restrict__ H1, const float* __restrict__ Wo1,
                       const float* __restrict__ ao1, const float* __restrict__ bo1,
                       const float* __restrict__ ao2, const float* __restrict__ bo2,
                       float* __restrict__ FTS2, float* __restrict__ F1O,
                       float* __restrict__ F2O) {
  int i = (blockIdx.x * blockDim.x + threadIdx.x) >> 6;
  int lane = threadIdx.x & 63;
  if (i >= NN) return;
  float acc = 0.f;
  for (int k0 = 0; k0 < FDIM; k0 += 64) {
    float hv = H1[(size_t)i * FDIM + k0 + lane];
#pragma unroll 8
    for (int kk = 0; kk < 64; ++kk) {
      float b = (lane < CDIM) ? Wo1[(size_t)(k0 + kk) * CDIM + lane] : 0.f;
      acc += __shfl(hv, kk) * b;
    }
  }
  float s1 = (lane < CDIM) ? acc * ao1[lane] : 0.f;
  float s2 = (lane < CDIM) ? acc * ao2[lane] : 0.f;
  s1 = wave_sum64(s1);
  s2 = wave_sum64(s2);
  if (lane == 0) {
    F1O[i] = s1 + bo1[0];
    F2O[i] = s2 + bo2[0];
  }
  if (lane < CDIM) FTS2[(size_t)i * CDIM + lane] = acc;
}

// ---------------- Kernel 7: layer-2 attention + output GEMM (fused) ---------
__global__ void k_agg2(const float* __restrict__ FTS2,
                       const float* __restrict__ F1O, const float* __restrict__ F2O,
                       const int* __restrict__ nbr, const int* __restrict__ cnt,
                       const float* __restrict__ Wo2, const float* __restrict__ bo,
                       float* __restrict__ out) {
  int i = (blockIdx.x * blockDim.x + threadIdx.x) >> 6;
  int lane = threadIdx.x & 63;
  if (i >= NN) return;
  int deg = cnt[i];
  const int* nb = nbr + (size_t)i * MAXD;
  float f1i = F1O[i];

  int jreg[4];
  float p[4];
  float m = -1e30f;
#pragma unroll
  for (int r = 0; r < 4; ++r) { jreg[r] = 0; p[r] = -1e30f; }
#pragma unroll
  for (int r = 0; r < 4; ++r) {
    int t = r * 64 + lane;
    if (t < deg) {
      int j = nb[t];
      jreg[r] = j;
      float x = f1i + F2O[j];
      x = x >= 0.f ? x : 0.2f * x;
      p[r] = x;
      m = fmaxf(m, x);
    }
  }
  m = wave_max64(m);
  float s = 0.f;
#pragma unroll
  for (int r = 0; r < 4; ++r) {
    int t = r * 64 + lane;
    float e = (t < deg) ? expf(p[r] - m) : 0.f;
    p[r] = e;
    s += e;
  }
  s = wave_sum64(s);

  float acc = 0.f;
#pragma unroll
  for (int r = 0; r < 4; ++r) {
    int base = r * 64;
    if (base >= deg) break;
    int lim = deg - base;
    lim = lim < 64 ? lim : 64;
    for (int sl = 0; sl < lim; ++sl) {
      float w = __shfl(p[r], sl);
      int j   = __shfl(jreg[r], sl);
      float fv = (lane < CDIM) ? FTS2[(size_t)j * CDIM + lane] : 0.f;
      acc += w * fv;
    }
  }
  float v = acc / s;  // vals2[i][lane], lane<CDIM

  // out[i][c] = sum_kk vals2[kk] * Wo2[kk][c] + bo[c]
  float o = (lane < CDIM) ? bo[lane] : 0.f;
#pragma unroll 8
  for (int kk = 0; kk < CDIM; ++kk) {
    float w = __shfl(v, kk);
    float b = (lane < CDIM) ? Wo2[kk * CDIM + lane] : 0.f;
    o += w * b;
  }
  if (lane < CDIM) out[(size_t)i * CDIM + lane] = o;
}

extern "C" void kernel_launch(void* const* d_in, const int* in_sizes, int n_in,
                              void* d_out, int out_size, void* d_ws, size_t ws_size,
                              hipStream_t stream) {
  const float* seq  = (const float*)d_in[0];
  const float* bias = (const float*)d_in[1];
  const float* W1   = (const float*)d_in[2];
  const float* a1   = (const float*)d_in[3];
  const float* b1   = (const float*)d_in[4];
  const float* a2   = (const float*)d_in[5];
  const float* b2   = (const float*)d_in[6];
  const float* W2   = (const float*)d_in[7];
  const float* bW   = (const float*)d_in[8];
  const float* Wo1  = (const float*)d_in[9];
  const float* ao1  = (const float*)d_in[10];
  const float* bo1  = (const float*)d_in[11];
  const float* ao2  = (const float*)d_in[12];
  const float* bo2  = (const float*)d_in[13];
  const float* Wo2  = (const float*)d_in[14];
  const float* bo   = (const float*)d_in[15];
  float* out = (float*)d_out;

  float* ws   = (float*)d_ws;
  float* FTS  = ws;                          // N*512
  float* H1   = FTS  + (size_t)NN * FDIM;    // N*512
  float* F1   = H1   + (size_t)NN * FDIM;    // NH*N
  float* F2   = F1   + (size_t)NHEAD * NN;   // NH*N
  float* VALS = F2   + (size_t)NHEAD * NN;   // N*512
  float* FTS2 = VALS + (size_t)NN * FDIM;    // N*40
  float* F1O  = FTS2 + (size_t)NN * CDIM;    // N
  float* F2O  = F1O  + NN;                   // N
  int*   nbr  = (int*)(F2O + NN);            // N*MAXD
  int*   cnt  = nbr + (size_t)NN * MAXD;     // N
  // total ≈ 30.5 MB of workspace

  // 1. CSR from bias_mat (wave per row)
  k_build_csr<<<NN * 64 / 256, 256, 0, stream>>>(bias, nbr, cnt);
  // 2. per-head features (dense GEMM, all heads)
  k_gemm_fts<<<dim3(NN / 64, NHEAD), 256, 0, stream>>>(seq, W1, FTS);
  // 3. attention coefficients' row/col terms
  k_f12<<<NN * NHEAD * 64 / 256, 256, 0, stream>>>(FTS, a1, b1, a2, b2, F1, F2);
  // 4. sparse softmax + neighbor aggregation
  k_agg1<<<NN * NHEAD * 64 / 256, 256, 0, stream>>>(FTS, F1, F2, nbr, cnt, VALS);
  // 5. per-head output transform + elu, concatenated into H1
  k_headout<<<NN * NHEAD * 64 / 256, 256, 0, stream>>>(VALS, W2, bW, H1);
  // 6. layer-2 features + attention terms
  k_fts2<<<NN * 64 / 256, 256, 0, stream>>>(H1, Wo1, ao1, bo1, ao2, bo2, FTS2, F1O, F2O);
  // 7. layer-2 sparse attention + final dense + bias
  k_agg2<<<NN * 64 / 256, 256, 0, stream>>>(FTS2, F1O, F2O, nbr, cnt, Wo2, bo, out);
}

// Round 2
// 209.942 us; speedup vs baseline: 1.2852x; 1.2852x over previous
//
#include <hip/hip_runtime.h>
#include <cstdint>
#include <cstddef>

#define NN 4096
#define FDIM 512
#define HDIM 64
#define NHEAD 8
#define CDIM 40
#define MAXD 256   // max neighbors kept per row (~41 expected)

__device__ __forceinline__ float wave_max64(float v) {
  for (int o = 32; o; o >>= 1) v = fmaxf(v, __shfl_xor(v, o));
  return v;
}
__device__ __forceinline__ float wave_sum64(float v) {
  for (int o = 32; o; o >>= 1) v += __shfl_xor(v, o);
  return v;
}

// ---------------- Kernel 1: build ordered CSR from bias_mat (0.0f == edge) --
// float4 loads + wave prefix-sum compaction.
__global__ void k_build_csr(const float* __restrict__ bias,
                            int* __restrict__ nbr, int* __restrict__ cnt) {
  int row  = (blockIdx.x * blockDim.x + threadIdx.x) >> 6;
  int lane = threadIdx.x & 63;
  if (row >= NN) return;
  const float4* r = (const float4*)(bias + (size_t)row * NN);
  int* out = nbr + (size_t)row * MAXD;
  int base = 0;
  for (int c4 = 0; c4 < NN / 4; c4 += 64) {
    float4 v = r[c4 + lane];
    int nib = (v.x == 0.f ? 1 : 0) | (v.y == 0.f ? 2 : 0) |
              (v.z == 0.f ? 4 : 0) | (v.w == 0.f ? 8 : 0);
    int c = __popc(nib);
    int pre = c;
    for (int o = 1; o < 64; o <<= 1) {
      int u = __shfl_up(pre, o);
      if (lane >= o) pre += u;
    }
    int excl = base + pre - c;
    int col0 = (c4 + lane) * 4;
    int k = 0;
#pragma unroll
    for (int i = 0; i < 4; ++i) {
      if ((nib >> i) & 1) {
        int p = excl + k;
        if (p < MAXD) out[p] = col0 + i;
        ++k;
      }
    }
    base += __shfl(pre, 63);
  }
  if (lane == 0) cnt[row] = base < MAXD ? base : MAXD;
}

// ---------------- Kernel 2: FTS = seq @ W1 (all heads) + fused f1/f2 --------
// 64x64 tile per block (col tile == one head), BK=32, double-buffered LDS,
// one barrier per K-tile, b128 LDS fragment reads, 4x4 register blocking.
__global__ __launch_bounds__(256) void k_gemm_fts(
    const float* __restrict__ A, const float* __restrict__ W1,
    const float* __restrict__ a1, const float* __restrict__ b1,
    const float* __restrict__ a2, const float* __restrict__ b2,
    float* __restrict__ C, float* __restrict__ F1, float* __restrict__ F2) {
  __shared__ float As[2][32][68];   // [k][m], pad 68 keeps 16B align + spreads banks
  __shared__ float Bs[2][32][64];   // [k][n], linear (global layout is already k-major)
  const int bm = blockIdx.x;        // 64 row tiles
  const int h  = blockIdx.y;        // 8 heads
  const int tid = threadIdx.x;
  const int tc = tid & 15, tr = tid >> 4;

  const float* Ab = A + (size_t)(bm * 64) * FDIM;
  const float* Bb = W1 + (size_t)h * FDIM * HDIM;

  // staging coords: A: row = tid>>2 (0..63), kq = tid&3; 2 float4 each (16 k)
  const int arow = tid >> 2, akq = tid & 3;

  float4 ra0, ra1, rb0, rb1;
  // ---- stage tile 0 into regs
  ra0 = *(const float4*)(Ab + (size_t)arow * FDIM + akq * 4);
  ra1 = *(const float4*)(Ab + (size_t)arow * FDIM + 16 + akq * 4);
  rb0 = *(const float4*)(Bb + (size_t)tid * 4);
  rb1 = *(const float4*)(Bb + (size_t)(tid + 256) * 4);
  // ---- write tile 0 to LDS[0]
  {
    float av0[4] = {ra0.x, ra0.y, ra0.z, ra0.w};
    float av1[4] = {ra1.x, ra1.y, ra1.z, ra1.w};
#pragma unroll
    for (int i = 0; i < 4; ++i) {
      As[0][akq * 4 + i][arow]      = av0[i];
      As[0][16 + akq * 4 + i][arow] = av1[i];
    }
    *(float4*)&Bs[0][(tid * 4) >> 6][(tid * 4) & 63]       = rb0;
    *(float4*)&Bs[0][((tid + 256) * 4) >> 6][(tid * 4) & 63] = rb1;
  }
  __syncthreads();

  float acc[4][4] = {};
  const int NT = FDIM / 32;  // 16
  for (int t = 0; t < NT; ++t) {
    const int cur = t & 1;
    // prefetch next tile into regs (global latency hides under compute)
    if (t + 1 < NT) {
      const int k0 = (t + 1) * 32;
      ra0 = *(const float4*)(Ab + (size_t)arow * FDIM + k0 + akq * 4);
      ra1 = *(const float4*)(Ab + (size_t)arow * FDIM + k0 + 16 + akq * 4);
      rb0 = *(const float4*)(Bb + (size_t)(k0 * 64) + tid * 4);
      rb1 = *(const float4*)(Bb + (size_t)(k0 * 64) + (tid + 256) * 4);
    }
    // compute on LDS[cur]
#pragma unroll
    for (int kk = 0; kk < 32; ++kk) {
      float4 av = *(const float4*)&As[cur][kk][tr * 4];
      float4 bv = *(const float4*)&Bs[cur][kk][tc * 4];
      float a[4] = {av.x, av.y, av.z, av.w};
      float b[4] = {bv.x, bv.y, bv.z, bv.w};
#pragma unroll
      for (int i = 0; i < 4; ++i)
#pragma unroll
        for (int j = 0; j < 4; ++j) acc[i][j] += a[i] * b[j];
    }
    if (t + 1 < NT) {
      // safe: all waves finished reading LDS[cur^1] before iter-(t-1)'s barrier
      float av0[4] = {ra0.x, ra0.y, ra0.z, ra0.w};
      float av1[4] = {ra1.x, ra1.y, ra1.z, ra1.w};
#pragma unroll
      for (int i = 0; i < 4; ++i) {
        As[cur ^ 1][akq * 4 + i][arow]      = av0[i];
        As[cur ^ 1][16 + akq * 4 + i][arow] = av1[i];
      }
      *(float4*)&Bs[cur ^ 1][(tid * 4) >> 6][(tid * 4) & 63]       = rb0;
      *(float4*)&Bs[cur ^ 1][((tid + 256) * 4) >> 6][(tid * 4) & 63] = rb1;
      __syncthreads();
    }
  }

  // ---- epilogue: write C tile + fused f1/f2 row dot-products
  float4 a1v = *(const float4*)(a1 + h * 64 + tc * 4);
  float4 a2v = *(const float4*)(a2 + h * 64 + tc * 4);
  float a1l[4] = {a1v.x, a1v.y, a1v.z, a1v.w};
  float a2l[4] = {a2v.x, a2v.y, a2v.z, a2v.w};
#pragma unroll
  for (int i = 0; i < 4; ++i) {
    int row = bm * 64 + tr * 4 + i;
    float4 cv = make_float4(acc[i][0], acc[i][1], acc[i][2], acc[i][3]);
    *(float4*)(C + (size_t)row * FDIM + h * 64 + tc * 4) = cv;
    float p1 = acc[i][0] * a1l[0] + acc[i][1] * a1l[1] +
               acc[i][2] * a1l[2] + acc[i][3] * a1l[3];
    float p2 = acc[i][0] * a2l[0] + acc[i][1] * a2l[1] +
               acc[i][2] * a2l[2] + acc[i][3] * a2l[3];
    // reduce across the 16 tc lanes (same tr group = 16 consecutive lanes)
#pragma unroll
    for (int o = 1; o < 16; o <<= 1) {
      p1 += __shfl_xor(p1, o);
      p2 += __shfl_xor(p2, o);
    }
    if (tc == 0) {
      F1[(size_t)h * NN + row] = p1 + b1[h];
      F2[(size_t)h * NN + row] = p2 + b2[h];
    }
  }
}

// ---------------- Kernel 3: sparse softmax + aggregation + W2/elu (fused) ---
__global__ void k_agg1h(const float* __restrict__ FTS,
                        const float* __restrict__ F1, const float* __restrict__ F2,
                        const int* __restrict__ nbr, const int* __restrict__ cnt,
                        const float* __restrict__ W2, const float* __restrict__ bW,
                        float* __restrict__ H1) {
  int gw = (blockIdx.x * blockDim.x + threadIdx.x) >> 6;
  int lane = threadIdx.x & 63;
  if (gw >= NN * NHEAD) return;
  int i = gw >> 3, h = gw & 7;
  int deg = cnt[i];
  const int* nb = nbr + (size_t)i * MAXD;
  float f1i = F1[(size_t)h * NN + i];
  const float* F2h = F2 + (size_t)h * NN;

  int jreg[4];
  float p[4];
  float m = -1e30f;
#pragma unroll
  for (int r = 0; r < 4; ++r) { jreg[r] = 0; p[r] = -1e30f; }
#pragma unroll
  for (int r = 0; r < 4; ++r) {
    int t = r * 64 + lane;
    if (t < deg) {
      int j = nb[t];
      jreg[r] = j;
      float x = f1i + F2h[j];
      x = x >= 0.f ? x : 0.2f * x;   // leaky_relu(0.2)
      p[r] = x;
      m = fmaxf(m, x);
    }
  }
  m = wave_max64(m);
  float s = 0.f;
#pragma unroll
  for (int r = 0; r < 4; ++r) {
    int t = r * 64 + lane;
    float e = (t < deg) ? expf(p[r] - m) : 0.f;
    p[r] = e;
    s += e;
  }
  s = wave_sum64(s);

  float acc = 0.f;
  const float* Fh = FTS + h * 64;
#pragma unroll
  for (int r = 0; r < 4; ++r) {
    int base = r * 64;
    if (base >= deg) break;
    int lim = deg - base;
    lim = lim < 64 ? lim : 64;
    for (int sl = 0; sl < lim; ++sl) {
      float w = __shfl(p[r], sl);
      int j   = __shfl(jreg[r], sl);
      acc += w * Fh[(size_t)j * FDIM + lane];
    }
  }
  float v = acc / s;   // vals[i][h*64+lane]

  // fused head-output transform: H1 = elu(vals @ W2[h] + bW[h])
  const float* W2h = W2 + (size_t)h * HDIM * HDIM;
  float o = bW[h * 64 + lane];
#pragma unroll 8
  for (int kk = 0; kk < 64; ++kk) {
    o += __shfl(v, kk) * W2h[kk * 64 + lane];
  }
  o = o > 0.f ? o : expm1f(o);   // elu
  H1[(size_t)i * FDIM + h * 64 + lane] = o;
}

// ---------------- Kernel 4: fts2 = H1 @ Wo1; f1o/f2o fused ------------------
__global__ void k_fts2(const float* __restrict__ H1, const float* __restrict__ Wo1,
                       const float* __restrict__ ao1, const float* __restrict__ bo1,
                       const float* __restrict__ ao2, const float* __restrict__ bo2,
                       float* __restrict__ FTS2, float* __restrict__ F1O,
                       float* __restrict__ F2O) {
  int i = (blockIdx.x * blockDim.x + threadIdx.x) >> 6;
  int lane = threadIdx.x & 63;
  if (i >= NN) return;
  float acc = 0.f;
  for (int k0 = 0; k0 < FDIM; k0 += 64) {
    float hv = H1[(size_t)i * FDIM + k0 + lane];
#pragma unroll 8
    for (int kk = 0; kk < 64; ++kk) {
      float b = (lane < CDIM) ? Wo1[(size_t)(k0 + kk) * CDIM + lane] : 0.f;
      acc += __shfl(hv, kk) * b;
    }
  }
  float s1 = (lane < CDIM) ? acc * ao1[lane] : 0.f;
  float s2 = (lane < CDIM) ? acc * ao2[lane] : 0.f;
  s1 = wave_sum64(s1);
  s2 = wave_sum64(s2);
  if (lane == 0) {
    F1O[i] = s1 + bo1[0];
    F2O[i] = s2 + bo2[0];
  }
  if (lane < CDIM) FTS2[(size_t)i * CDIM + lane] = acc;
}

// ---------------- Kernel 5: layer-2 attention + output GEMM (fused) ---------
__global__ void k_agg2(const float* __restrict__ FTS2,
                       const float* __restrict__ F1O, const float* __restrict__ F2O,
                       const int* __restrict__ nbr, const int* __restrict__ cnt,
                       const float* __restrict__ Wo2, const float* __restrict__ bo,
                       float* __restrict__ out) {
  int i = (blockIdx.x * blockDim.x + threadIdx.x) >> 6;
  int lane = threadIdx.x & 63;
  if (i >= NN) return;
  int deg = cnt[i];
  const int* nb = nbr + (size_t)i * MAXD;
  float f1i = F1O[i];

  int jreg[4];
  float p[4];
  float m = -1e30f;
#pragma unroll
  for (int r = 0; r < 4; ++r) { jreg[r] = 0; p[r] = -1e30f; }
#pragma unroll
  for (int r = 0; r < 4; ++r) {
    int t = r * 64 + lane;
    if (t < deg) {
      int j = nb[t];
      jreg[r] = j;
      float x = f1i + F2O[j];
      x = x >= 0.f ? x : 0.2f * x;
      p[r] = x;
      m = fmaxf(m, x);
    }
  }
  m = wave_max64(m);
  float s = 0.f;
#pragma unroll
  for (int r = 0; r < 4; ++r) {
    int t = r * 64 + lane;
    float e = (t < deg) ? expf(p[r] - m) : 0.f;
    p[r] = e;
    s += e;
  }
  s = wave_sum64(s);

  float acc = 0.f;
#pragma unroll
  for (int r = 0; r < 4; ++r) {
    int base = r * 64;
    if (base >= deg) break;
    int lim = deg - base;
    lim = lim < 64 ? lim : 64;
    for (int sl = 0; sl < lim; ++sl) {
      float w = __shfl(p[r], sl);
      int j   = __shfl(jreg[r], sl);
      float fv = (lane < CDIM) ? FTS2[(size_t)j * CDIM + lane] : 0.f;
      acc += w * fv;
    }
  }
  float v = acc / s;  // vals2[i][lane], lane<CDIM

  float o = (lane < CDIM) ? bo[lane] : 0.f;
#pragma unroll 8
  for (int kk = 0; kk < CDIM; ++kk) {
    float w = __shfl(v, kk);
    float b = (lane < CDIM) ? Wo2[kk * CDIM + lane] : 0.f;
    o += w * b;
  }
  if (lane < CDIM) out[(size_t)i * CDIM + lane] = o;
}

extern "C" void kernel_launch(void* const* d_in, const int* in_sizes, int n_in,
                              void* d_out, int out_size, void* d_ws, size_t ws_size,
                              hipStream_t stream) {
  const float* seq  = (const float*)d_in[0];
  const float* bias = (const float*)d_in[1];
  const float* W1   = (const float*)d_in[2];
  const float* a1   = (const float*)d_in[3];
  const float* b1   = (const float*)d_in[4];
  const float* a2   = (const float*)d_in[5];
  const float* b2   = (const float*)d_in[6];
  const float* W2   = (const float*)d_in[7];
  const float* bW   = (const float*)d_in[8];
  const float* Wo1  = (const float*)d_in[9];
  const float* ao1  = (const float*)d_in[10];
  const float* bo1  = (const float*)d_in[11];
  const float* ao2  = (const float*)d_in[12];
  const float* bo2  = (const float*)d_in[13];
  const float* Wo2  = (const float*)d_in[14];
  const float* bo   = (const float*)d_in[15];
  float* out = (float*)d_out;

  float* ws   = (float*)d_ws;
  float* FTS  = ws;                          // N*512
  float* H1   = FTS  + (size_t)NN * FDIM;    // N*512
  float* F1   = H1   + (size_t)NN * FDIM;    // NH*N
  float* F2   = F1   + (size_t)NHEAD * NN;   // NH*N
  float* FTS2 = F2   + (size_t)NHEAD * NN;   // N*40
  float* F1O  = FTS2 + (size_t)NN * CDIM;    // N
  float* F2O  = F1O  + NN;                   // N
  int*   nbr  = (int*)(F2O + NN);            // N*MAXD
  int*   cnt  = nbr + (size_t)NN * MAXD;     // N

  // 1. CSR from bias_mat (wave per row, float4 + prefix-sum compaction)
  k_build_csr<<<NN * 64 / 256, 256, 0, stream>>>(bias, nbr, cnt);
  // 2. per-head features GEMM + fused f1/f2
  k_gemm_fts<<<dim3(NN / 64, NHEAD), 256, 0, stream>>>(seq, W1, a1, b1, a2, b2,
                                                       FTS, F1, F2);
  // 3. sparse softmax + aggregation + per-head W2/elu (fused)
  k_agg1h<<<NN * NHEAD * 64 / 256, 256, 0, stream>>>(FTS, F1, F2, nbr, cnt,
                                                     W2, bW, H1);
  // 4. layer-2 features + attention terms
  k_fts2<<<NN * 64 / 256, 256, 0, stream>>>(H1, Wo1, ao1, bo1, ao2, bo2, FTS2, F1O, F2O);
  // 5. layer-2 sparse attention + final dense + bias
  k_agg2<<<NN * 64 / 256, 256, 0, stream>>>(FTS2, F1O, F2O, nbr, cnt, Wo2, bo, out);
}

// Round 4
// 150.045 us; speedup vs baseline: 1.7983x; 1.3992x over previous
//
#include <hip/hip_runtime.h>
#include <cstdint>
#include <cstddef>

#define NN 4096
#define FDIM 512
#define HDIM 64
#define NHEAD 8
#define CDIM 40
#define MAXD 256   // max neighbors kept per row (~41 expected)

__device__ __forceinline__ float wave_max64(float v) {
  for (int o = 32; o; o >>= 1) v = fmaxf(v, __shfl_xor(v, o));
  return v;
}
__device__ __forceinline__ float wave_sum64(float v) {
  for (int o = 32; o; o >>= 1) v += __shfl_xor(v, o);
  return v;
}
// wave-uniform lane index -> v_readlane (SGPR result, no ds_bpermute)
__device__ __forceinline__ float readlane_f(float v, int sl) {
  return __uint_as_float((unsigned)__builtin_amdgcn_readlane((int)__float_as_uint(v), sl));
}
__device__ __forceinline__ int readlane_i(int v, int sl) {
  return __builtin_amdgcn_readlane(v, sl);
}

// ---------------- Kernel 1: CSR from bias_mat + Wo1 transpose ---------------
__global__ void k_build_csr(const float* __restrict__ bias, int* __restrict__ nbr,
                            int* __restrict__ cnt, const float* __restrict__ Wo1,
                            float* __restrict__ Wo1t) {
  if (blockIdx.x >= NN / 4) {   // one extra block: transpose Wo1 [512][40]->[40][512]
    for (int idx = threadIdx.x; idx < CDIM * FDIM; idx += 256) {
      int c = idx >> 9, k = idx & 511;
      Wo1t[idx] = Wo1[k * CDIM + c];
    }
    return;
  }
  int row  = blockIdx.x * 4 + (threadIdx.x >> 6);
  int lane = threadIdx.x & 63;
  const float4* r = (const float4*)(bias + (size_t)row * NN);
  int* out = nbr + (size_t)row * MAXD;
  int base = 0;
  for (int c4 = 0; c4 < NN / 4; c4 += 64) {
    float4 v = r[c4 + lane];
    int nib = (v.x == 0.f ? 1 : 0) | (v.y == 0.f ? 2 : 0) |
              (v.z == 0.f ? 4 : 0) | (v.w == 0.f ? 8 : 0);
    int c = __popc(nib);
    int pre = c;
    for (int o = 1; o < 64; o <<= 1) {
      int u = __shfl_up(pre, o);
      if (lane >= o) pre += u;
    }
    int excl = base + pre - c;
    int col0 = (c4 + lane) * 4;
    int k = 0;
#pragma unroll
    for (int i = 0; i < 4; ++i) {
      if ((nib >> i) & 1) {
        int p = excl + k;
        if (p < MAXD) out[p] = col0 + i;
        ++k;
      }
    }
    base += __shfl(pre, 63);
  }
  if (lane == 0) cnt[row] = base < MAXD ? base : MAXD;
}

// ---------------- Kernel 2: FTS = seq @ W1 (all heads) + fused f1/f2 --------
// 64x64 tile, BK=32, double-buffered LDS, 4x4 register blocking.
// F1t/F2t written in [N][8] layout (head-minor) for k_agg1's float4 reads.
__global__ __launch_bounds__(256) void k_gemm_fts(
    const float* __restrict__ A, const float* __restrict__ W1,
    const float* __restrict__ a1, const float* __restrict__ b1,
    const float* __restrict__ a2, const float* __restrict__ b2,
    float* __restrict__ C, float* __restrict__ F1t, float* __restrict__ F2t) {
  __shared__ float As[2][32][68];
  __shared__ float Bs[2][32][64];
  const int bm = blockIdx.x;
  const int h  = blockIdx.y;
  const int tid = threadIdx.x;
  const int tc = tid & 15, tr = tid >> 4;

  const float* Ab = A + (size_t)(bm * 64) * FDIM;
  const float* Bb = W1 + (size_t)h * FDIM * HDIM;
  const int arow = tid >> 2, akq = tid & 3;

  float4 ra0, ra1, rb0, rb1;
  ra0 = *(const float4*)(Ab + (size_t)arow * FDIM + akq * 4);
  ra1 = *(const float4*)(Ab + (size_t)arow * FDIM + 16 + akq * 4);
  rb0 = *(const float4*)(Bb + (size_t)tid * 4);
  rb1 = *(const float4*)(Bb + (size_t)(tid + 256) * 4);
  {
    float av0[4] = {ra0.x, ra0.y, ra0.z, ra0.w};
    float av1[4] = {ra1.x, ra1.y, ra1.z, ra1.w};
#pragma unroll
    for (int i = 0; i < 4; ++i) {
      As[0][akq * 4 + i][arow]      = av0[i];
      As[0][16 + akq * 4 + i][arow] = av1[i];
    }
    *(float4*)&Bs[0][(tid * 4) >> 6][(tid * 4) & 63]       = rb0;
    *(float4*)&Bs[0][((tid + 256) * 4) >> 6][(tid * 4) & 63] = rb1;
  }
  __syncthreads();

  float acc[4][4] = {};
  const int NT = FDIM / 32;
  for (int t = 0; t < NT; ++t) {
    const int cur = t & 1;
    if (t + 1 < NT) {
      const int k0 = (t + 1) * 32;
      ra0 = *(const float4*)(Ab + (size_t)arow * FDIM + k0 + akq * 4);
      ra1 = *(const float4*)(Ab + (size_t)arow * FDIM + k0 + 16 + akq * 4);
      rb0 = *(const float4*)(Bb + (size_t)(k0 * 64) + tid * 4);
      rb1 = *(const float4*)(Bb + (size_t)(k0 * 64) + (tid + 256) * 4);
    }
#pragma unroll
    for (int kk = 0; kk < 32; ++kk) {
      float4 av = *(const float4*)&As[cur][kk][tr * 4];
      float4 bv = *(const float4*)&Bs[cur][kk][tc * 4];
      float a[4] = {av.x, av.y, av.z, av.w};
      float b[4] = {bv.x, bv.y, bv.z, bv.w};
#pragma unroll
      for (int i = 0; i < 4; ++i)
#pragma unroll
        for (int j = 0; j < 4; ++j) acc[i][j] += a[i] * b[j];
    }
    if (t + 1 < NT) {
      float av0[4] = {ra0.x, ra0.y, ra0.z, ra0.w};
      float av1[4] = {ra1.x, ra1.y, ra1.z, ra1.w};
#pragma unroll
      for (int i = 0; i < 4; ++i) {
        As[cur ^ 1][akq * 4 + i][arow]      = av0[i];
        As[cur ^ 1][16 + akq * 4 + i][arow] = av1[i];
      }
      *(float4*)&Bs[cur ^ 1][(tid * 4) >> 6][(tid * 4) & 63]       = rb0;
      *(float4*)&Bs[cur ^ 1][((tid + 256) * 4) >> 6][(tid * 4) & 63] = rb1;
      __syncthreads();
    }
  }

  float4 a1v = *(const float4*)(a1 + h * 64 + tc * 4);
  float4 a2v = *(const float4*)(a2 + h * 64 + tc * 4);
  float a1l[4] = {a1v.x, a1v.y, a1v.z, a1v.w};
  float a2l[4] = {a2v.x, a2v.y, a2v.z, a2v.w};
#pragma unroll
  for (int i = 0; i < 4; ++i) {
    int row = bm * 64 + tr * 4 + i;
    float4 cv = make_float4(acc[i][0], acc[i][1], acc[i][2], acc[i][3]);
    *(float4*)(C + (size_t)row * FDIM + h * 64 + tc * 4) = cv;
    float p1 = acc[i][0] * a1l[0] + acc[i][1] * a1l[1] +
               acc[i][2] * a1l[2] + acc[i][3] * a1l[3];
    float p2 = acc[i][0] * a2l[0] + acc[i][1] * a2l[1] +
               acc[i][2] * a2l[2] + acc[i][3] * a2l[3];
#pragma unroll
    for (int o = 1; o < 16; o <<= 1) {
      p1 += __shfl_xor(p1, o);
      p2 += __shfl_xor(p2, o);
    }
    if (tc == 0) {
      F1t[(size_t)row * 8 + h] = p1 + b1[h];
      F2t[(size_t)row * 8 + h] = p2 + b2[h];
    }
  }
}

// ---------------- Kernel 3: sparse softmax + aggregation (4 heads/wave) -----
// wave = (row i, head-group hg of 4 heads); lane covers feature hg*256+lane*4..+3
__global__ __launch_bounds__(256) void k_agg1(
    const float* __restrict__ FTS, const float* __restrict__ F1t,
    const float* __restrict__ F2t, const int* __restrict__ nbr,
    const int* __restrict__ cnt, float* __restrict__ VALS) {
  int wv = threadIdx.x >> 6, lane = threadIdx.x & 63;
  int gw = blockIdx.x * 4 + wv;     // over NN*2
  int i = gw >> 1, hg = gw & 1;
  int deg = cnt[i];
  const int* nb = nbr + (size_t)i * MAXD;
  float4 f1v = *(const float4*)(F1t + (size_t)i * 8 + hg * 4);

  float4 p4[4];
  int jreg[4];
  float mx = -1e30f, my = -1e30f, mz = -1e30f, mw = -1e30f;
#pragma unroll
  for (int r = 0; r < 4; ++r) {
    int t = r * 64 + lane;
    jreg[r] = 0;
    p4[r] = make_float4(-1e30f, -1e30f, -1e30f, -1e30f);
    if (t < deg) {
      int j = nb[t];
      jreg[r] = j;
      float4 f2v = *(const float4*)(F2t + (size_t)j * 8 + hg * 4);
      float4 x;
      x.x = f1v.x + f2v.x; x.x = x.x >= 0.f ? x.x : 0.2f * x.x;
      x.y = f1v.y + f2v.y; x.y = x.y >= 0.f ? x.y : 0.2f * x.y;
      x.z = f1v.z + f2v.z; x.z = x.z >= 0.f ? x.z : 0.2f * x.z;
      x.w = f1v.w + f2v.w; x.w = x.w >= 0.f ? x.w : 0.2f * x.w;
      p4[r] = x;
      mx = fmaxf(mx, x.x); my = fmaxf(my, x.y);
      mz = fmaxf(mz, x.z); mw = fmaxf(mw, x.w);
    }
  }
  mx = wave_max64(mx); my = wave_max64(my);
  mz = wave_max64(mz); mw = wave_max64(mw);
  float sx = 0.f, sy = 0.f, sz = 0.f, sw = 0.f;
#pragma unroll
  for (int r = 0; r < 4; ++r) {
    int t = r * 64 + lane;
    float4 e = make_float4(0.f, 0.f, 0.f, 0.f);
    if (t < deg) {
      e.x = __expf(p4[r].x - mx); e.y = __expf(p4[r].y - my);
      e.z = __expf(p4[r].z - mz); e.w = __expf(p4[r].w - mw);
    }
    p4[r] = e;
    sx += e.x; sy += e.y; sz += e.z; sw += e.w;
  }
  sx = wave_sum64(sx); sy = wave_sum64(sy);
  sz = wave_sum64(sz); sw = wave_sum64(sw);

  int q = lane >> 4;   // which of the 4 heads this lane's features belong to
  float invh = (q < 2) ? (q == 0 ? 1.f / sx : 1.f / sy)
                       : (q == 2 ? 1.f / sz : 1.f / sw);

  float4 acc = make_float4(0.f, 0.f, 0.f, 0.f);
  const float* Fb = FTS + hg * 256;
#pragma unroll
  for (int r = 0; r < 4; ++r) {
    int base = r * 64;
    if (base >= deg) break;
    int lim = deg - base;
    lim = lim < 64 ? lim : 64;
    for (int sl = 0; sl < lim; ++sl) {
      int j   = readlane_i(jreg[r], sl);
      float w0 = readlane_f(p4[r].x, sl);
      float w1 = readlane_f(p4[r].y, sl);
      float w2 = readlane_f(p4[r].z, sl);
      float w3 = readlane_f(p4[r].w, sl);
      float w = (q < 2) ? (q == 0 ? w0 : w1) : (q == 2 ? w2 : w3);
      float4 fv = *(const float4*)(Fb + (size_t)j * FDIM + lane * 4);
      acc.x += w * fv.x; acc.y += w * fv.y;
      acc.z += w * fv.z; acc.w += w * fv.w;
    }
  }
  acc.x *= invh; acc.y *= invh; acc.z *= invh; acc.w *= invh;
  *(float4*)(VALS + (size_t)i * FDIM + hg * 256 + lane * 4) = acc;
}

// ---------------- Kernel 4: H1 = elu(VALS @ blockdiag(W2) + bW) -------------
// per-head 64x64 GEMM, K=64, single LDS stage, 4x4 register blocking
__global__ __launch_bounds__(256) void k_w2(
    const float* __restrict__ VALS, const float* __restrict__ W2,
    const float* __restrict__ bW, float* __restrict__ H1) {
  __shared__ float As[64][68];   // [k][m]
  __shared__ float Bs[64][64];   // [k][n]
  const int rb = blockIdx.x, h = blockIdx.y;
  const int tid = threadIdx.x;
  const int tc = tid & 15, tr = tid >> 4;
  {
    const int arow = tid >> 2, akq = tid & 3;
    const float* Ab = VALS + (size_t)(rb * 64 + arow) * FDIM + h * 64;
#pragma unroll
    for (int qq = 0; qq < 4; ++qq) {
      float4 v = *(const float4*)(Ab + akq * 16 + qq * 4);
      int k = akq * 16 + qq * 4;
      As[k + 0][arow] = v.x; As[k + 1][arow] = v.y;
      As[k + 2][arow] = v.z; As[k + 3][arow] = v.w;
    }
    const float* Bb = W2 + (size_t)h * HDIM * HDIM;
#pragma unroll
    for (int qq = 0; qq < 4; ++qq) {
      int idx = qq * 256 + tid;           // float4 index into 64x64
      int kr = idx >> 4, nc = (idx & 15) * 4;
      *(float4*)&Bs[kr][nc] = *(const float4*)(Bb + kr * 64 + nc);
    }
  }
  __syncthreads();
  float acc[4][4] = {};
#pragma unroll
  for (int kk = 0; kk < 64; ++kk) {
    float4 av = *(const float4*)&As[kk][tr * 4];
    float4 bv = *(const float4*)&Bs[kk][tc * 4];
    float a[4] = {av.x, av.y, av.z, av.w};
    float b[4] = {bv.x, bv.y, bv.z, bv.w};
#pragma unroll
    for (int i = 0; i < 4; ++i)
#pragma unroll
      for (int j = 0; j < 4; ++j) acc[i][j] += a[i] * b[j];
  }
  float4 bwv = *(const float4*)(bW + h * 64 + tc * 4);
  float bl[4] = {bwv.x, bwv.y, bwv.z, bwv.w};
#pragma unroll
  for (int i = 0; i < 4; ++i) {
    int row = rb * 64 + tr * 4 + i;
    float4 o;
    o.x = acc[i][0] + bl[0]; o.y = acc[i][1] + bl[1];
    o.z = acc[i][2] + bl[2]; o.w = acc[i][3] + bl[3];
    o.x = o.x > 0.f ? o.x : __expf(o.x) - 1.f;
    o.y = o.y > 0.f ? o.y : __expf(o.y) - 1.f;
    o.z = o.z > 0.f ? o.z : __expf(o.z) - 1.f;
    o.w = o.w > 0.f ? o.w : __expf(o.w) - 1.f;
    *(float4*)(H1 + (size_t)row * FDIM + h * 64 + tc * 4) = o;
  }
}

// ---------------- Kernel 5: fts2 = H1 @ Wo1 (+ f1o/f2o) ---------------------
// block = 8 rows staged in LDS; wave handles 2 rows; lane = output col (<40)
__global__ __launch_bounds__(256) void k_fts2(
    const float* __restrict__ H1, const float* __restrict__ Wo1t,
    const float* __restrict__ ao1, const float* __restrict__ bo1s,
    const float* __restrict__ ao2, const float* __restrict__ bo2s,
    float* __restrict__ FTS2, float* __restrict__ F1O, float* __restrict__ F2O) {
  __shared__ float HL[8][512];
  const int tid = threadIdx.x;
  const int i0 = blockIdx.x * 8;
#pragma unroll
  for (int qq = 0; qq < 4; ++qq) {
    int idx = qq * 256 + tid;            // float4 index
    int r = idx >> 7, c4 = idx & 127;
    *(float4*)&HL[r][c4 * 4] = *(const float4*)(H1 + (size_t)(i0 + r) * FDIM + c4 * 4);
  }
  __syncthreads();
  const int wv = tid >> 6, lane = tid & 63;
  float acc0 = 0.f, acc1 = 0.f;
  const bool act = lane < CDIM;
  const float* wrow = Wo1t + (size_t)lane * FDIM;
  for (int k0 = 0; k0 < FDIM; k0 += 4) {
    float4 w4 = act ? *(const float4*)(wrow + k0) : make_float4(0.f, 0.f, 0.f, 0.f);
    float4 h0 = *(const float4*)&HL[wv * 2][k0];
    float4 h1 = *(const float4*)&HL[wv * 2 + 1][k0];
    acc0 += h0.x * w4.x + h0.y * w4.y + h0.z * w4.z + h0.w * w4.w;
    acc1 += h1.x * w4.x + h1.y * w4.y + h1.z * w4.z + h1.w * w4.w;
  }
  float ao1l = act ? ao1[lane] : 0.f;
  float ao2l = act ? ao2[lane] : 0.f;
#pragma unroll 2
  for (int r = 0; r < 2; ++r) {
    float a = r == 0 ? acc0 : acc1;
    int i = i0 + wv * 2 + r;
    float s1 = wave_sum64(a * ao1l);
    float s2 = wave_sum64(a * ao2l);
    if (lane == 0) {
      F1O[i] = s1 + bo1s[0];
      F2O[i] = s2 + bo2s[0];
    }
    if (act) FTS2[(size_t)i * CDIM + lane] = a;
  }
}

// ---------------- Kernel 6: layer-2 attention + output GEMM (fused) ---------
__global__ __launch_bounds__(256) void k_agg2(
    const float* __restrict__ FTS2, const float* __restrict__ F1O,
    const float* __restrict__ F2O, const int* __restrict__ nbr,
    const int* __restrict__ cnt, const float* __restrict__ Wo2,
    const float* __restrict__ bo, float* __restrict__ out) {
  int i = blockIdx.x * 4 + (threadIdx.x >> 6);
  int lane = threadIdx.x & 63;
  int deg = cnt[i];
  const int* nb = nbr + (size_t)i * MAXD;
  float f1i = F1O[i];

  int jreg[4];
  float p[4];
  float m = -1e30f;
#pragma unroll
  for (int r = 0; r < 4; ++r) { jreg[r] = 0; p[r] = -1e30f; }
#pragma unroll
  for (int r = 0; r < 4; ++r) {
    int t = r * 64 + lane;
    if (t < deg) {
      int j = nb[t];
      jreg[r] = j;
      float x = f1i + F2O[j];
      x = x >= 0.f ? x : 0.2f * x;
      p[r] = x;
      m = fmaxf(m, x);
    }
  }
  m = wave_max64(m);
  float s = 0.f;
#pragma unroll
  for (int r = 0; r < 4; ++r) {
    int t = r * 64 + lane;
    float e = (t < deg) ? __expf(p[r] - m) : 0.f;
    p[r] = e;
    s += e;
  }
  s = wave_sum64(s);

  const bool act = lane < CDIM;
  float acc = 0.f;
#pragma unroll
  for (int r = 0; r < 4; ++r) {
    int base = r * 64;
    if (base >= deg) break;
    int lim = deg - base;
    lim = lim < 64 ? lim : 64;
    for (int sl = 0; sl < lim; ++sl) {
      float w = readlane_f(p[r], sl);
      int j   = readlane_i(jreg[r], sl);
      float fv = act ? FTS2[(size_t)j * CDIM + lane] : 0.f;
      acc += w * fv;
    }
  }
  float v = acc / s;

  float o = act ? bo[lane] : 0.f;
  for (int kk = 0; kk < CDIM; ++kk) {
    float w = readlane_f(v, kk);
    float b = act ? Wo2[kk * CDIM + lane] : 0.f;
    o += w * b;
  }
  if (act) out[(size_t)i * CDIM + lane] = o;
}

extern "C" void kernel_launch(void* const* d_in, const int* in_sizes, int n_in,
                              void* d_out, int out_size, void* d_ws, size_t ws_size,
                              hipStream_t stream) {
  const float* seq  = (const float*)d_in[0];
  const float* bias = (const float*)d_in[1];
  const float* W1   = (const float*)d_in[2];
  const float* a1   = (const float*)d_in[3];
  const float* b1   = (const float*)d_in[4];
  const float* a2   = (const float*)d_in[5];
  const float* b2   = (const float*)d_in[6];
  const float* W2   = (const float*)d_in[7];
  const float* bW   = (const float*)d_in[8];
  const float* Wo1  = (const float*)d_in[9];
  const float* ao1  = (const float*)d_in[10];
  const float* bo1  = (const float*)d_in[11];
  const float* ao2  = (const float*)d_in[12];
  const float* bo2  = (const float*)d_in[13];
  const float* Wo2  = (const float*)d_in[14];
  const float* bo   = (const float*)d_in[15];
  float* out = (float*)d_out;

  float* ws   = (float*)d_ws;
  float* FTS  = ws;                          // N*512
  float* H1   = FTS  + (size_t)NN * FDIM;    // N*512
  float* VALS = H1   + (size_t)NN * FDIM;    // N*512
  float* F1t  = VALS + (size_t)NN * FDIM;    // N*8
  float* F2t  = F1t  + (size_t)NN * NHEAD;   // N*8
  float* FTS2 = F2t  + (size_t)NN * NHEAD;   // N*40
  float* F1O  = FTS2 + (size_t)NN * CDIM;    // N
  float* F2O  = F1O  + NN;                   // N
  float* Wo1t = F2O  + NN;                   // 40*512
  int*   nbr  = (int*)(Wo1t + (size_t)CDIM * FDIM);  // N*MAXD
  int*   cnt  = nbr + (size_t)NN * MAXD;     // N
  // total ~30.4 MB

  // 1. CSR from bias_mat (+ Wo1 transpose in the extra block)
  k_build_csr<<<NN / 4 + 1, 256, 0, stream>>>(bias, nbr, cnt, Wo1, Wo1t);
  // 2. per-head features GEMM + fused f1/f2 ([N][8] layout)
  k_gemm_fts<<<dim3(NN / 64, NHEAD), 256, 0, stream>>>(seq, W1, a1, b1, a2, b2,
                                                       FTS, F1t, F2t);
  // 3. sparse softmax + aggregation, 4 heads per wave
  k_agg1<<<NN * 2 / 4, 256, 0, stream>>>(FTS, F1t, F2t, nbr, cnt, VALS);
  // 4. per-head W2 GEMM + elu
  k_w2<<<dim3(NN / 64, NHEAD), 256, 0, stream>>>(VALS, W2, bW, H1);
  // 5. layer-2 features + attention terms
  k_fts2<<<NN / 8, 256, 0, stream>>>(H1, Wo1t, ao1, bo1, ao2, bo2, FTS2, F1O, F2O);
  // 6. layer-2 sparse attention + final dense + bias
  k_agg2<<<NN / 4, 256, 0, stream>>>(FTS2, F1O, F2O, nbr, cnt, Wo2, bo, out);
}

// Round 5
// 127.513 us; speedup vs baseline: 2.1160x; 1.1767x over previous
//
#include <hip/hip_runtime.h>
#include <cstdint>
#include <cstddef>

#define NN 4096
#define FDIM 512
#define HDIM 64
#define NHEAD 8
#define CDIM 40
#define MAXD 256   // max neighbors kept per row (~41 expected)

typedef __attribute__((ext_vector_type(8))) short bf16x8;
typedef __attribute__((ext_vector_type(16))) float f32x16;

__device__ __forceinline__ float wave_max64(float v) {
  for (int o = 32; o; o >>= 1) v = fmaxf(v, __shfl_xor(v, o));
  return v;
}
__device__ __forceinline__ float wave_sum64(float v) {
  for (int o = 32; o; o >>= 1) v += __shfl_xor(v, o);
  return v;
}
__device__ __forceinline__ float readlane_f(float v, int sl) {
  return __uint_as_float((unsigned)__builtin_amdgcn_readlane((int)__float_as_uint(v), sl));
}
__device__ __forceinline__ int readlane_i(int v, int sl) {
  return __builtin_amdgcn_readlane(v, sl);
}
// fp32 -> bf16 (RNE) and back, via bit ops (avoids header type issues)
__device__ __forceinline__ unsigned short f2bf(float x) {
  unsigned u = __float_as_uint(x);
  return (unsigned short)((u + 0x7fffu + ((u >> 16) & 1u)) >> 16);
}
__device__ __forceinline__ float bf2f(unsigned short b) {
  return __uint_as_float(((unsigned)b) << 16);
}

// ---------------- Kernel 1: prep = CSR + seq->bf16 hi/lo + W1 transpose+cvt +
//                  Wo1 transpose.  Grid = 1024 csr + 1024 cvt + 64 + 1 = 2113.
__global__ void k_prep(const float* __restrict__ bias, int* __restrict__ nbr,
                       int* __restrict__ cnt, const float* __restrict__ seq,
                       short* __restrict__ Ahi, short* __restrict__ Alo,
                       const float* __restrict__ W1, short* __restrict__ Bhi,
                       short* __restrict__ Blo, const float* __restrict__ Wo1,
                       float* __restrict__ Wo1t) {
  int bx = blockIdx.x, tid = threadIdx.x;
  if (bx < NN / 4) {   // ---- CSR rows (4 per block, wave per row)
    int row  = bx * 4 + (tid >> 6);
    int lane = tid & 63;
    const float4* r = (const float4*)(bias + (size_t)row * NN);
    int* out = nbr + (size_t)row * MAXD;
    int base = 0;
    for (int c4 = 0; c4 < NN / 4; c4 += 64) {
      float4 v = r[c4 + lane];
      int nib = (v.x == 0.f ? 1 : 0) | (v.y == 0.f ? 2 : 0) |
                (v.z == 0.f ? 4 : 0) | (v.w == 0.f ? 8 : 0);
      int c = __popc(nib);
      int pre = c;
      for (int o = 1; o < 64; o <<= 1) {
        int u = __shfl_up(pre, o);
        if (lane >= o) pre += u;
      }
      int excl = base + pre - c;
      int col0 = (c4 + lane) * 4;
      int k = 0;
#pragma unroll
      for (int i = 0; i < 4; ++i) {
        if ((nib >> i) & 1) {
          int p = excl + k;
          if (p < MAXD) out[p] = col0 + i;
          ++k;
        }
      }
      base += __shfl(pre, 63);
    }
    if (lane == 0) cnt[row] = base < MAXD ? base : MAXD;
    return;
  }
  bx -= NN / 4;
  if (bx < 1024) {     // ---- seq -> bf16 hi/lo (8 elems/thread)
    size_t off = (size_t)bx * 2048 + (size_t)tid * 8;
    float4 v0 = *(const float4*)(seq + off);
    float4 v1 = *(const float4*)(seq + off + 4);
    unsigned short h0 = f2bf(v0.x), h1 = f2bf(v0.y), h2 = f2bf(v0.z), h3 = f2bf(v0.w);
    unsigned short h4 = f2bf(v1.x), h5 = f2bf(v1.y), h6 = f2bf(v1.z), h7 = f2bf(v1.w);
    *(uint4*)(Ahi + off) = make_uint4(
        (unsigned)h0 | ((unsigned)h1 << 16), (unsigned)h2 | ((unsigned)h3 << 16),
        (unsigned)h4 | ((unsigned)h5 << 16), (unsigned)h6 | ((unsigned)h7 << 16));
    unsigned short l0 = f2bf(v0.x - bf2f(h0)), l1 = f2bf(v0.y - bf2f(h1));
    unsigned short l2 = f2bf(v0.z - bf2f(h2)), l3 = f2bf(v0.w - bf2f(h3));
    unsigned short l4 = f2bf(v1.x - bf2f(h4)), l5 = f2bf(v1.y - bf2f(h5));
    unsigned short l6 = f2bf(v1.z - bf2f(h6)), l7 = f2bf(v1.w - bf2f(h7));
    *(uint4*)(Alo + off) = make_uint4(
        (unsigned)l0 | ((unsigned)l1 << 16), (unsigned)l2 | ((unsigned)l3 << 16),
        (unsigned)l4 | ((unsigned)l5 << 16), (unsigned)l6 | ((unsigned)l7 << 16));
    return;
  }
  bx -= 1024;
  if (bx < 64) {       // ---- W1 tile transpose + bf16 hi/lo: [k][n] -> [n][k]
    __shared__ float T[64][65];
    int h = bx >> 3, kb = bx & 7;
    const float* src = W1 + ((size_t)h * FDIM + kb * 64) * HDIM;
#pragma unroll
    for (int q = 0; q < 4; ++q) {
      int fi = q * 256 + tid, kk = fi >> 4, n4 = fi & 15;
      float4 v = *(const float4*)(src + (size_t)kk * HDIM + n4 * 4);
      T[n4 * 4 + 0][kk] = v.x; T[n4 * 4 + 1][kk] = v.y;
      T[n4 * 4 + 2][kk] = v.z; T[n4 * 4 + 3][kk] = v.w;
    }
    __syncthreads();
#pragma unroll
    for (int q = 0; q < 4; ++q) {
      int fi = q * 256 + tid, n = fi >> 4, k4 = fi & 15;
      float a = T[n][k4 * 4], b = T[n][k4 * 4 + 1];
      float c = T[n][k4 * 4 + 2], d = T[n][k4 * 4 + 3];
      size_t o = ((size_t)h * 64 + n) * FDIM + kb * 64 + k4 * 4;
      unsigned short ha = f2bf(a), hb = f2bf(b), hc = f2bf(c), hd = f2bf(d);
      *(short4*)(Bhi + o) = make_short4((short)ha, (short)hb, (short)hc, (short)hd);
      *(short4*)(Blo + o) = make_short4((short)f2bf(a - bf2f(ha)), (short)f2bf(b - bf2f(hb)),
                                        (short)f2bf(c - bf2f(hc)), (short)f2bf(d - bf2f(hd)));
    }
    return;
  }
  // ---- Wo1 transpose [512][40] -> [40][512]
  for (int idx = tid; idx < CDIM * FDIM; idx += 256) {
    int c = idx >> 9, k = idx & 511;
    Wo1t[idx] = Wo1[k * CDIM + c];
  }
}

// ---------------- Kernel 2: MFMA GEMM, bf16 hi/lo -> fp32-accurate ---------
// Block tile M=64 x N=128 (2 heads), Kc=256 (kslice in z). 4 waves, each wave
// a 32x64 sub-tile = 2 frags of 32x32, K-step 16, 3 MFMAs per frag (hh,lh,hl).
// Both operands packed with the SAME slot->k map => correct for any hw k-order.
__global__ __launch_bounds__(256) void k_gemm(
    const short* __restrict__ Ahi, const short* __restrict__ Alo,
    const short* __restrict__ Bhi, const short* __restrict__ Blo,
    float* __restrict__ PC) {
  __shared__ short AH[4][64][16], AL[4][64][16];    // [kstep16][m][k-slot]
  __shared__ short BH[4][128][16], BL[4][128][16];  // [kstep16][n][k-slot]
  const int mtile = blockIdx.x, npair = blockIdx.y, kslice = blockIdx.z;
  const int tid = threadIdx.x, lane = tid & 63, w = tid >> 6;
  const int wm = w >> 1, wn = w & 1;
  const int ml = lane & 31, g = lane >> 5, g8 = g * 8;

  f32x16 acc0, acc1;
#pragma unroll
  for (int r = 0; r < 16; ++r) { acc0[r] = 0.f; acc1[r] = 0.f; }

  const size_t kbase = (size_t)kslice * 256;
  const short* Abh = Ahi + (((size_t)mtile * 64) << 9) + kbase;
  const short* Abl = Alo + (((size_t)mtile * 64) << 9) + kbase;
  const short* Bbh = Bhi + (((size_t)npair * 128) << 9) + kbase;  // [n][512k], n<128
  const short* Bbl = Blo + (((size_t)npair * 128) << 9) + kbase;

  const int tn = tid >> 3, k8 = tid & 7;       // staging coords
  const int ks = k8 >> 1, ko = (k8 & 1) * 8;
  const size_t so = ((size_t)tn << 9) + (size_t)k8 * 8;  // + c*64 at use

  int4 rah0, rah1, ral0, ral1, rbh0, rbh1, rbh2, rbh3, rbl0, rbl1, rbl2, rbl3;
  // prologue: load chunk 0
  {
    rah0 = *(const int4*)(Abh + so);              ral0 = *(const int4*)(Abl + so);
    rah1 = *(const int4*)(Abh + so + (32 << 9));  ral1 = *(const int4*)(Abl + so + (32 << 9));
    rbh0 = *(const int4*)(Bbh + so);              rbl0 = *(const int4*)(Bbl + so);
    rbh1 = *(const int4*)(Bbh + so + (32 << 9));  rbl1 = *(const int4*)(Bbl + so + (32 << 9));
    rbh2 = *(const int4*)(Bbh + so + (64 << 9));  rbl2 = *(const int4*)(Bbl + so + (64 << 9));
    rbh3 = *(const int4*)(Bbh + so + (96 << 9));  rbl3 = *(const int4*)(Bbl + so + (96 << 9));
  }

  for (int c = 0; c < 4; ++c) {
    // write staged regs to LDS
    *(int4*)&AH[ks][tn][ko] = rah0;       *(int4*)&AL[ks][tn][ko] = ral0;
    *(int4*)&AH[ks][32 + tn][ko] = rah1;  *(int4*)&AL[ks][32 + tn][ko] = ral1;
    *(int4*)&BH[ks][tn][ko] = rbh0;       *(int4*)&BL[ks][tn][ko] = rbl0;
    *(int4*)&BH[ks][32 + tn][ko] = rbh1;  *(int4*)&BL[ks][32 + tn][ko] = rbl1;
    *(int4*)&BH[ks][64 + tn][ko] = rbh2;  *(int4*)&BL[ks][64 + tn][ko] = rbl2;
    *(int4*)&BH[ks][96 + tn][ko] = rbh3;  *(int4*)&BL[ks][96 + tn][ko] = rbl3;
    __syncthreads();
    if (c < 3) {   // prefetch next chunk (latency hides under MFMAs)
      size_t o = so + (size_t)(c + 1) * 64;
      rah0 = *(const int4*)(Abh + o);              ral0 = *(const int4*)(Abl + o);
      rah1 = *(const int4*)(Abh + o + (32 << 9));  ral1 = *(const int4*)(Abl + o + (32 << 9));
      rbh0 = *(const int4*)(Bbh + o);              rbl0 = *(const int4*)(Bbl + o);
      rbh1 = *(const int4*)(Bbh + o + (32 << 9));  rbl1 = *(const int4*)(Bbl + o + (32 << 9));
      rbh2 = *(const int4*)(Bbh + o + (64 << 9));  rbl2 = *(const int4*)(Bbl + o + (64 << 9));
      rbh3 = *(const int4*)(Bbh + o + (96 << 9));  rbl3 = *(const int4*)(Bbl + o + (96 << 9));
    }
#pragma unroll
    for (int t = 0; t < 4; ++t) {
      bf16x8 ah = *(const bf16x8*)&AH[t][wm * 32 + ml][g8];
      bf16x8 al = *(const bf16x8*)&AL[t][wm * 32 + ml][g8];
      bf16x8 bh0 = *(const bf16x8*)&BH[t][wn * 64 + ml][g8];
      bf16x8 bl0 = *(const bf16x8*)&BL[t][wn * 64 + ml][g8];
      acc0 = __builtin_amdgcn_mfma_f32_32x32x16_bf16(ah, bh0, acc0, 0, 0, 0);
      acc0 = __builtin_amdgcn_mfma_f32_32x32x16_bf16(al, bh0, acc0, 0, 0, 0);
      acc0 = __builtin_amdgcn_mfma_f32_32x32x16_bf16(ah, bl0, acc0, 0, 0, 0);
      bf16x8 bh1 = *(const bf16x8*)&BH[t][wn * 64 + 32 + ml][g8];
      bf16x8 bl1 = *(const bf16x8*)&BL[t][wn * 64 + 32 + ml][g8];
      acc1 = __builtin_amdgcn_mfma_f32_32x32x16_bf16(ah, bh1, acc1, 0, 0, 0);
      acc1 = __builtin_amdgcn_mfma_f32_32x32x16_bf16(al, bh1, acc1, 0, 0, 0);
      acc1 = __builtin_amdgcn_mfma_f32_32x32x16_bf16(ah, bl1, acc1, 0, 0, 0);
    }
    __syncthreads();
  }

  // epilogue: C/D layout (m74-verified): col = lane&31, row = (r&3)+8*(r>>2)+4*(lane>>5)
  float* pc = PC + (size_t)kslice * NN * FDIM;
  const int row0 = mtile * 64 + wm * 32 + 4 * g;
  const int col0 = npair * 128 + wn * 64 + ml;
#pragma unroll
  for (int r = 0; r < 16; ++r) {
    int row = row0 + (r & 3) + 8 * (r >> 2);
    pc[(size_t)row * FDIM + col0] = acc0[r];
    pc[(size_t)row * FDIM + col0 + 32] = acc1[r];
  }
}

// ---------------- Kernel 3: reduce K-slices + fused f1/f2 ------------------
__global__ __launch_bounds__(256) void k_red(
    const float* __restrict__ PC, const float* __restrict__ a1,
    const float* __restrict__ b1, const float* __restrict__ a2,
    const float* __restrict__ b2, float* __restrict__ FTS,
    float* __restrict__ F1t, float* __restrict__ F2t) {
  int i = blockIdx.x * 4 + (threadIdx.x >> 6);
  int lane = threadIdx.x & 63;
  size_t o = (size_t)i * FDIM + lane * 8;
  float4 u0 = *(const float4*)(PC + o);
  float4 u1 = *(const float4*)(PC + o + 4);
  float4 v0 = *(const float4*)(PC + (size_t)NN * FDIM + o);
  float4 v1 = *(const float4*)(PC + (size_t)NN * FDIM + o + 4);
  float4 s0 = make_float4(u0.x + v0.x, u0.y + v0.y, u0.z + v0.z, u0.w + v0.w);
  float4 s1 = make_float4(u1.x + v1.x, u1.y + v1.y, u1.z + v1.z, u1.w + v1.w);
  *(float4*)(FTS + o) = s0;
  *(float4*)(FTS + o + 4) = s1;
  float4 w0 = *(const float4*)(a1 + lane * 8);
  float4 w1 = *(const float4*)(a1 + lane * 8 + 4);
  float4 x0 = *(const float4*)(a2 + lane * 8);
  float4 x1 = *(const float4*)(a2 + lane * 8 + 4);
  float p1 = s0.x * w0.x + s0.y * w0.y + s0.z * w0.z + s0.w * w0.w +
             s1.x * w1.x + s1.y * w1.y + s1.z * w1.z + s1.w * w1.w;
  float p2 = s0.x * x0.x + s0.y * x0.y + s0.z * x0.z + s0.w * x0.w +
             s1.x * x1.x + s1.y * x1.y + s1.z * x1.z + s1.w * x1.w;
  p1 += __shfl_xor(p1, 1); p1 += __shfl_xor(p1, 2); p1 += __shfl_xor(p1, 4);
  p2 += __shfl_xor(p2, 1); p2 += __shfl_xor(p2, 2); p2 += __shfl_xor(p2, 4);
  if ((lane & 7) == 0) {
    int h = lane >> 3;
    F1t[(size_t)i * 8 + h] = p1 + b1[h];
    F2t[(size_t)i * 8 + h] = p2 + b2[h];
  }
}

// ---------------- Kernel 4: sparse softmax + aggregation (4 heads/wave) -----
__global__ __launch_bounds__(256) void k_agg1(
    const float* __restrict__ FTS, const float* __restrict__ F1t,
    const float* __restrict__ F2t, const int* __restrict__ nbr,
    const int* __restrict__ cnt, float* __restrict__ VALS) {
  int wv = threadIdx.x >> 6, lane = threadIdx.x & 63;
  int gw = blockIdx.x * 4 + wv;     // over NN*2
  int i = gw >> 1, hg = gw & 1;
  int deg = cnt[i];
  const int* nb = nbr + (size_t)i * MAXD;
  float4 f1v = *(const float4*)(F1t + (size_t)i * 8 + hg * 4);

  float4 p4[4];
  int jreg[4];
  float mx = -1e30f, my = -1e30f, mz = -1e30f, mw = -1e30f;
#pragma unroll
  for (int r = 0; r < 4; ++r) {
    int t = r * 64 + lane;
    jreg[r] = 0;
    p4[r] = make_float4(-1e30f, -1e30f, -1e30f, -1e30f);
    if (t < deg) {
      int j = nb[t];
      jreg[r] = j;
      float4 f2v = *(const float4*)(F2t + (size_t)j * 8 + hg * 4);
      float4 x;
      x.x = f1v.x + f2v.x; x.x = x.x >= 0.f ? x.x : 0.2f * x.x;
      x.y = f1v.y + f2v.y; x.y = x.y >= 0.f ? x.y : 0.2f * x.y;
      x.z = f1v.z + f2v.z; x.z = x.z >= 0.f ? x.z : 0.2f * x.z;
      x.w = f1v.w + f2v.w; x.w = x.w >= 0.f ? x.w : 0.2f * x.w;
      p4[r] = x;
      mx = fmaxf(mx, x.x); my = fmaxf(my, x.y);
      mz = fmaxf(mz, x.z); mw = fmaxf(mw, x.w);
    }
  }
  mx = wave_max64(mx); my = wave_max64(my);
  mz = wave_max64(mz); mw = wave_max64(mw);
  float sx = 0.f, sy = 0.f, sz = 0.f, sw = 0.f;
#pragma unroll
  for (int r = 0; r < 4; ++r) {
    int t = r * 64 + lane;
    float4 e = make_float4(0.f, 0.f, 0.f, 0.f);
    if (t < deg) {
      e.x = __expf(p4[r].x - mx); e.y = __expf(p4[r].y - my);
      e.z = __expf(p4[r].z - mz); e.w = __expf(p4[r].w - mw);
    }
    p4[r] = e;
    sx += e.x; sy += e.y; sz += e.z; sw += e.w;
  }
  sx = wave_sum64(sx); sy = wave_sum64(sy);
  sz = wave_sum64(sz); sw = wave_sum64(sw);

  int q = lane >> 4;
  float invh = (q < 2) ? (q == 0 ? 1.f / sx : 1.f / sy)
                       : (q == 2 ? 1.f / sz : 1.f / sw);

  float4 acc = make_float4(0.f, 0.f, 0.f, 0.f);
  const float* Fb = FTS + hg * 256;
#pragma unroll
  for (int r = 0; r < 4; ++r) {
    int base = r * 64;
    if (base >= deg) break;
    int lim = deg - base;
    lim = lim < 64 ? lim : 64;
    for (int sl = 0; sl < lim; ++sl) {
      int j   = readlane_i(jreg[r], sl);
      float w0 = readlane_f(p4[r].x, sl);
      float w1 = readlane_f(p4[r].y, sl);
      float w2 = readlane_f(p4[r].z, sl);
      float w3 = readlane_f(p4[r].w, sl);
      float w = (q < 2) ? (q == 0 ? w0 : w1) : (q == 2 ? w2 : w3);
      float4 fv = *(const float4*)(Fb + (size_t)j * FDIM + lane * 4);
      acc.x += w * fv.x; acc.y += w * fv.y;
      acc.z += w * fv.z; acc.w += w * fv.w;
    }
  }
  acc.x *= invh; acc.y *= invh; acc.z *= invh; acc.w *= invh;
  *(float4*)(VALS + (size_t)i * FDIM + hg * 256 + lane * 4) = acc;
}

// ---------------- Kernel 5: H1 = elu(VALS @ blockdiag(W2) + bW) -------------
__global__ __launch_bounds__(256) void k_w2(
    const float* __restrict__ VALS, const float* __restrict__ W2,
    const float* __restrict__ bW, float* __restrict__ H1) {
  __shared__ float As[64][68];
  __shared__ float Bs[64][64];
  const int rb = blockIdx.x, h = blockIdx.y;
  const int tid = threadIdx.x;
  const int tc = tid & 15, tr = tid >> 4;
  {
    const int arow = tid >> 2, akq = tid & 3;
    const float* Ab = VALS + (size_t)(rb * 64 + arow) * FDIM + h * 64;
#pragma unroll
    for (int qq = 0; qq < 4; ++qq) {
      float4 v = *(const float4*)(Ab + akq * 16 + qq * 4);
      int k = akq * 16 + qq * 4;
      As[k + 0][arow] = v.x; As[k + 1][arow] = v.y;
      As[k + 2][arow] = v.z; As[k + 3][arow] = v.w;
    }
    const float* Bb = W2 + (size_t)h * HDIM * HDIM;
#pragma unroll
    for (int qq = 0; qq < 4; ++qq) {
      int idx = qq * 256 + tid;
      int kr = idx >> 4, nc = (idx & 15) * 4;
      *(float4*)&Bs[kr][nc] = *(const float4*)(Bb + kr * 64 + nc);
    }
  }
  __syncthreads();
  float acc[4][4] = {};
#pragma unroll
  for (int kk = 0; kk < 64; ++kk) {
    float4 av = *(const float4*)&As[kk][tr * 4];
    float4 bv = *(const float4*)&Bs[kk][tc * 4];
    float a[4] = {av.x, av.y, av.z, av.w};
    float b[4] = {bv.x, bv.y, bv.z, bv.w};
#pragma unroll
    for (int i = 0; i < 4; ++i)
#pragma unroll
      for (int j = 0; j < 4; ++j) acc[i][j] += a[i] * b[j];
  }
  float4 bwv = *(const float4*)(bW + h * 64 + tc * 4);
  float bl[4] = {bwv.x, bwv.y, bwv.z, bwv.w};
#pragma unroll
  for (int i = 0; i < 4; ++i) {
    int row = rb * 64 + tr * 4 + i;
    float4 o;
    o.x = acc[i][0] + bl[0]; o.y = acc[i][1] + bl[1];
    o.z = acc[i][2] + bl[2]; o.w = acc[i][3] + bl[3];
    o.x = o.x > 0.f ? o.x : __expf(o.x) - 1.f;
    o.y = o.y > 0.f ? o.y : __expf(o.y) - 1.f;
    o.z = o.z > 0.f ? o.z : __expf(o.z) - 1.f;
    o.w = o.w > 0.f ? o.w : __expf(o.w) - 1.f;
    *(float4*)(H1 + (size_t)row * FDIM + h * 64 + tc * 4) = o;
  }
}

// ---------------- Kernel 6: fts2 = H1 @ Wo1 (+ f1o/f2o) ---------------------
__global__ __launch_bounds__(256) void k_fts2(
    const float* __restrict__ H1, const float* __restrict__ Wo1t,
    const float* __restrict__ ao1, const float* __restrict__ bo1s,
    const float* __restrict__ ao2, const float* __restrict__ bo2s,
    float* __restrict__ FTS2, float* __restrict__ F1O, float* __restrict__ F2O) {
  __shared__ float HL[8][512];
  const int tid = threadIdx.x;
  const int i0 = blockIdx.x * 8;
#pragma unroll
  for (int qq = 0; qq < 4; ++qq) {
    int idx = qq * 256 + tid;
    int r = idx >> 7, c4 = idx & 127;
    *(float4*)&HL[r][c4 * 4] = *(const float4*)(H1 + (size_t)(i0 + r) * FDIM + c4 * 4);
  }
  __syncthreads();
  const int wv = tid >> 6, lane = tid & 63;
  float acc0 = 0.f, acc1 = 0.f;
  const bool act = lane < CDIM;
  const float* wrow = Wo1t + (size_t)lane * FDIM;
  for (int k0 = 0; k0 < FDIM; k0 += 4) {
    float4 w4 = act ? *(const float4*)(wrow + k0) : make_float4(0.f, 0.f, 0.f, 0.f);
    float4 h0 = *(const float4*)&HL[wv * 2][k0];
    float4 h1 = *(const float4*)&HL[wv * 2 + 1][k0];
    acc0 += h0.x * w4.x + h0.y * w4.y + h0.z * w4.z + h0.w * w4.w;
    acc1 += h1.x * w4.x + h1.y * w4.y + h1.z * w4.z + h1.w * w4.w;
  }
  float ao1l = act ? ao1[lane] : 0.f;
  float ao2l = act ? ao2[lane] : 0.f;
#pragma unroll 2
  for (int r = 0; r < 2; ++r) {
    float a = r == 0 ? acc0 : acc1;
    int i = i0 + wv * 2 + r;
    float s1 = wave_sum64(a * ao1l);
    float s2 = wave_sum64(a * ao2l);
    if (lane == 0) {
      F1O[i] = s1 + bo1s[0];
      F2O[i] = s2 + bo2s[0];
    }
    if (act) FTS2[(size_t)i * CDIM + lane] = a;
  }
}

// ---------------- Kernel 7: layer-2 attention + output GEMM (fused) ---------
__global__ __launch_bounds__(256) void k_agg2(
    const float* __restrict__ FTS2, const float* __restrict__ F1O,
    const float* __restrict__ F2O, const int* __restrict__ nbr,
    const int* __restrict__ cnt, const float* __restrict__ Wo2,
    const float* __restrict__ bo, float* __restrict__ out) {
  int i = blockIdx.x * 4 + (threadIdx.x >> 6);
  int lane = threadIdx.x & 63;
  int deg = cnt[i];
  const int* nb = nbr + (size_t)i * MAXD;
  float f1i = F1O[i];

  int jreg[4];
  float p[4];
  float m = -1e30f;
#pragma unroll
  for (int r = 0; r < 4; ++r) { jreg[r] = 0; p[r] = -1e30f; }
#pragma unroll
  for (int r = 0; r < 4; ++r) {
    int t = r * 64 + lane;
    if (t < deg) {
      int j = nb[t];
      jreg[r] = j;
      float x = f1i + F2O[j];
      x = x >= 0.f ? x : 0.2f * x;
      p[r] = x;
      m = fmaxf(m, x);
    }
  }
  m = wave_max64(m);
  float s = 0.f;
#pragma unroll
  for (int r = 0; r < 4; ++r) {
    int t = r * 64 + lane;
    float e = (t < deg) ? __expf(p[r] - m) : 0.f;
    p[r] = e;
    s += e;
  }
  s = wave_sum64(s);

  const bool act = lane < CDIM;
  float acc = 0.f;
#pragma unroll
  for (int r = 0; r < 4; ++r) {
    int base = r * 64;
    if (base >= deg) break;
    int lim = deg - base;
    lim = lim < 64 ? lim : 64;
    for (int sl = 0; sl < lim; ++sl) {
      float w = readlane_f(p[r], sl);
      int j   = readlane_i(jreg[r], sl);
      float fv = act ? FTS2[(size_t)j * CDIM + lane] : 0.f;
      acc += w * fv;
    }
  }
  float v = acc / s;

  float o = act ? bo[lane] : 0.f;
  for (int kk = 0; kk < CDIM; ++kk) {
    float w = readlane_f(v, kk);
    float b = act ? Wo2[kk * CDIM + lane] : 0.f;
    o += w * b;
  }
  if (act) out[(size_t)i * CDIM + lane] = o;
}

extern "C" void kernel_launch(void* const* d_in, const int* in_sizes, int n_in,
                              void* d_out, int out_size, void* d_ws, size_t ws_size,
                              hipStream_t stream) {
  const float* seq  = (const float*)d_in[0];
  const float* bias = (const float*)d_in[1];
  const float* W1   = (const float*)d_in[2];
  const float* a1   = (const float*)d_in[3];
  const float* b1   = (const float*)d_in[4];
  const float* a2   = (const float*)d_in[5];
  const float* b2   = (const float*)d_in[6];
  const float* W2   = (const float*)d_in[7];
  const float* bW   = (const float*)d_in[8];
  const float* Wo1  = (const float*)d_in[9];
  const float* ao1  = (const float*)d_in[10];
  const float* bo1  = (const float*)d_in[11];
  const float* ao2  = (const float*)d_in[12];
  const float* bo2  = (const float*)d_in[13];
  const float* Wo2  = (const float*)d_in[14];
  const float* bo   = (const float*)d_in[15];
  float* out = (float*)d_out;

  float* ws   = (float*)d_ws;
  float* FTS  = ws;                           // N*512 f32
  float* H1   = FTS  + (size_t)NN * FDIM;     // N*512 f32
  float* VALS = H1   + (size_t)NN * FDIM;     // N*512 f32
  float* PC   = H1;                           // GEMM partials [2][N][512] alias H1+VALS
  float* F1t  = VALS + (size_t)NN * FDIM;     // N*8
  float* F2t  = F1t  + (size_t)NN * NHEAD;    // N*8
  float* FTS2 = F2t  + (size_t)NN * NHEAD;    // N*40
  float* F1O  = FTS2 + (size_t)NN * CDIM;     // N
  float* F2O  = F1O  + NN;                    // N
  float* Wo1t = F2O  + NN;                    // 40*512
  short* Ahi  = (short*)(Wo1t + (size_t)CDIM * FDIM);  // N*512 bf16
  short* Alo  = Ahi + (size_t)NN * FDIM;               // N*512 bf16
  short* Bhi  = Alo + (size_t)NN * FDIM;               // 8*64*512 bf16 (k-minor)
  short* Blo  = Bhi + (size_t)NHEAD * HDIM * FDIM;
  int*   nbr  = (int*)(Blo + (size_t)NHEAD * HDIM * FDIM);  // N*MAXD
  int*   cnt  = nbr + (size_t)NN * MAXD;      // N
  // total ~38.6 MB

  // 1. CSR + seq->bf16 hi/lo + W1 transpose/convert + Wo1 transpose
  k_prep<<<NN / 4 + 1024 + 64 + 1, 256, 0, stream>>>(
      bias, nbr, cnt, seq, Ahi, Alo, W1, Bhi, Blo, Wo1, Wo1t);
  // 2. MFMA hi/lo GEMM -> partials
  k_gemm<<<dim3(NN / 64, NHEAD / 2, 2), 256, 0, stream>>>(Ahi, Alo, Bhi, Blo, PC);
  // 3. reduce K-slices + fused f1/f2
  k_red<<<NN / 4, 256, 0, stream>>>(PC, a1, b1, a2, b2, FTS, F1t, F2t);
  // 4. sparse softmax + aggregation, 4 heads per wave
  k_agg1<<<NN * 2 / 4, 256, 0, stream>>>(FTS, F1t, F2t, nbr, cnt, VALS);
  // 5. per-head W2 GEMM + elu
  k_w2<<<dim3(NN / 64, NHEAD), 256, 0, stream>>>(VALS, W2, bW, H1);
  // 6. layer-2 features + attention terms
  k_fts2<<<NN / 8, 256, 0, stream>>>(H1, Wo1t, ao1, bo1, ao2, bo2, FTS2, F1O, F2O);
  // 7. layer-2 sparse attention + final dense + bias
  k_agg2<<<NN / 4, 256, 0, stream>>>(FTS2, F1O, F2O, nbr, cnt, Wo2, bo, out);
}

// Round 6
// 126.991 us; speedup vs baseline: 2.1248x; 1.0041x over previous
//
#include <hip/hip_runtime.h>
#include <cstdint>
#include <cstddef>

#define NN 4096
#define FDIM 512
#define HDIM 64
#define NHEAD 8
#define CDIM 40
#define MAXD 256   // max neighbors kept per row (~41 expected)

typedef __attribute__((ext_vector_type(8))) short bf16x8;
typedef __attribute__((ext_vector_type(16))) float f32x16;

__device__ __forceinline__ float wave_max64(float v) {
  for (int o = 32; o; o >>= 1) v = fmaxf(v, __shfl_xor(v, o));
  return v;
}
__device__ __forceinline__ float wave_sum64(float v) {
  for (int o = 32; o; o >>= 1) v += __shfl_xor(v, o);
  return v;
}
__device__ __forceinline__ float readlane_f(float v, int sl) {
  return __uint_as_float((unsigned)__builtin_amdgcn_readlane((int)__float_as_uint(v), sl));
}
__device__ __forceinline__ int readlane_i(int v, int sl) {
  return __builtin_amdgcn_readlane(v, sl);
}
// fp32 -> bf16 (RNE) and back, via bit ops
__device__ __forceinline__ unsigned short f2bf(float x) {
  unsigned u = __float_as_uint(x);
  return (unsigned short)((u + 0x7fffu + ((u >> 16) & 1u)) >> 16);
}
__device__ __forceinline__ float bf2f(unsigned short b) {
  return __uint_as_float(((unsigned)b) << 16);
}

// ---------------- Kernel 1: prep = CSR (block/row) + seq->bf16 hi/lo +
//                  W1 transpose+cvt + Wo1 transpose.
// Grid = 4096 csr + 1024 cvt + 64 + 1 = 5185.
__global__ __launch_bounds__(256) void k_prep(
    const float* __restrict__ bias, int* __restrict__ nbr, int* __restrict__ cnt,
    const float* __restrict__ seq, short* __restrict__ Ahi, short* __restrict__ Alo,
    const float* __restrict__ W1, short* __restrict__ Bhi, short* __restrict__ Blo,
    const float* __restrict__ Wo1, float* __restrict__ Wo1t) {
  __shared__ int wtot[4];
  __shared__ float T[64][65];
  int bx = blockIdx.x, tid = threadIdx.x;
  if (bx < NN) {       // ---- CSR: one block per row, thread owns 16 cols
    int row = bx;
    int lane = tid & 63, wv = tid >> 6;
    const float4* r = (const float4*)(bias + (size_t)row * NN);
    // load 16 consecutive cols = 4 contiguous float4
    unsigned mask = 0;
#pragma unroll
    for (int i = 0; i < 4; ++i) {
      float4 v = r[tid * 4 + i];
      mask |= (unsigned)((v.x == 0.f ? 1 : 0) | (v.y == 0.f ? 2 : 0) |
                         (v.z == 0.f ? 4 : 0) | (v.w == 0.f ? 8 : 0)) << (i * 4);
    }
    int c = __popc(mask);
    // wave inclusive scan
    int pre = c;
#pragma unroll
    for (int o = 1; o < 64; o <<= 1) {
      int u = __shfl_up(pre, o);
      if (lane >= o) pre += u;
    }
    if (lane == 63) wtot[wv] = pre;
    __syncthreads();
    int woff = 0;
#pragma unroll
    for (int w = 0; w < 4; ++w)
      if (w < wv) woff += wtot[w];
    int excl = woff + pre - c;
    int* out = nbr + (size_t)row * MAXD;
    int col0 = tid * 16, k = 0;
#pragma unroll
    for (int i = 0; i < 16; ++i) {
      if ((mask >> i) & 1) {
        int p = excl + k;
        if (p < MAXD) out[p] = col0 + i;
        ++k;
      }
    }
    if (tid == 0) {
      int total = wtot[0] + wtot[1] + wtot[2] + wtot[3];
      cnt[row] = total < MAXD ? total : MAXD;
    }
    return;
  }
  bx -= NN;
  if (bx < 1024) {     // ---- seq -> bf16 hi/lo (8 elems/thread)
    size_t off = (size_t)bx * 2048 + (size_t)tid * 8;
    float4 v0 = *(const float4*)(seq + off);
    float4 v1 = *(const float4*)(seq + off + 4);
    unsigned short h0 = f2bf(v0.x), h1 = f2bf(v0.y), h2 = f2bf(v0.z), h3 = f2bf(v0.w);
    unsigned short h4 = f2bf(v1.x), h5 = f2bf(v1.y), h6 = f2bf(v1.z), h7 = f2bf(v1.w);
    *(uint4*)(Ahi + off) = make_uint4(
        (unsigned)h0 | ((unsigned)h1 << 16), (unsigned)h2 | ((unsigned)h3 << 16),
        (unsigned)h4 | ((unsigned)h5 << 16), (unsigned)h6 | ((unsigned)h7 << 16));
    unsigned short l0 = f2bf(v0.x - bf2f(h0)), l1 = f2bf(v0.y - bf2f(h1));
    unsigned short l2 = f2bf(v0.z - bf2f(h2)), l3 = f2bf(v0.w - bf2f(h3));
    unsigned short l4 = f2bf(v1.x - bf2f(h4)), l5 = f2bf(v1.y - bf2f(h5));
    unsigned short l6 = f2bf(v1.z - bf2f(h6)), l7 = f2bf(v1.w - bf2f(h7));
    *(uint4*)(Alo + off) = make_uint4(
        (unsigned)l0 | ((unsigned)l1 << 16), (unsigned)l2 | ((unsigned)l3 << 16),
        (unsigned)l4 | ((unsigned)l5 << 16), (unsigned)l6 | ((unsigned)l7 << 16));
    return;
  }
  bx -= 1024;
  if (bx < 64) {       // ---- W1 tile transpose + bf16 hi/lo: [k][n] -> [n][k]
    int h = bx >> 3, kb = bx & 7;
    const float* src = W1 + ((size_t)h * FDIM + kb * 64) * HDIM;
#pragma unroll
    for (int q = 0; q < 4; ++q) {
      int fi = q * 256 + tid, kk = fi >> 4, n4 = fi & 15;
      float4 v = *(const float4*)(src + (size_t)kk * HDIM + n4 * 4);
      T[n4 * 4 + 0][kk] = v.x; T[n4 * 4 + 1][kk] = v.y;
      T[n4 * 4 + 2][kk] = v.z; T[n4 * 4 + 3][kk] = v.w;
    }
    __syncthreads();
#pragma unroll
    for (int q = 0; q < 4; ++q) {
      int fi = q * 256 + tid, n = fi >> 4, k4 = fi & 15;
      float a = T[n][k4 * 4], b = T[n][k4 * 4 + 1];
      float c = T[n][k4 * 4 + 2], d = T[n][k4 * 4 + 3];
      size_t o = ((size_t)h * 64 + n) * FDIM + kb * 64 + k4 * 4;
      unsigned short ha = f2bf(a), hb = f2bf(b), hc = f2bf(c), hd = f2bf(d);
      *(short4*)(Bhi + o) = make_short4((short)ha, (short)hb, (short)hc, (short)hd);
      *(short4*)(Blo + o) = make_short4((short)f2bf(a - bf2f(ha)), (short)f2bf(b - bf2f(hb)),
                                        (short)f2bf(c - bf2f(hc)), (short)f2bf(d - bf2f(hd)));
    }
    return;
  }
  // ---- Wo1 transpose [512][40] -> [40][512]
  for (int idx = tid; idx < CDIM * FDIM; idx += 256) {
    int c = idx >> 9, k = idx & 511;
    Wo1t[idx] = Wo1[k * CDIM + c];
  }
}

// ---------------- Kernel 2: MFMA GEMM, bf16 hi/lo -> fp32-accurate ---------
__global__ __launch_bounds__(256) void k_gemm(
    const short* __restrict__ Ahi, const short* __restrict__ Alo,
    const short* __restrict__ Bhi, const short* __restrict__ Blo,
    float* __restrict__ PC) {
  __shared__ short AH[4][64][16], AL[4][64][16];    // [kstep16][m][k-slot]
  __shared__ short BH[4][128][16], BL[4][128][16];  // [kstep16][n][k-slot]
  const int mtile = blockIdx.x, npair = blockIdx.y, kslice = blockIdx.z;
  const int tid = threadIdx.x, lane = tid & 63, w = tid >> 6;
  const int wm = w >> 1, wn = w & 1;
  const int ml = lane & 31, g = lane >> 5, g8 = g * 8;

  f32x16 acc0, acc1;
#pragma unroll
  for (int r = 0; r < 16; ++r) { acc0[r] = 0.f; acc1[r] = 0.f; }

  const size_t kbase = (size_t)kslice * 256;
  const short* Abh = Ahi + (((size_t)mtile * 64) << 9) + kbase;
  const short* Abl = Alo + (((size_t)mtile * 64) << 9) + kbase;
  const short* Bbh = Bhi + (((size_t)npair * 128) << 9) + kbase;
  const short* Bbl = Blo + (((size_t)npair * 128) << 9) + kbase;

  const int tn = tid >> 3, k8 = tid & 7;
  const int ks = k8 >> 1, ko = (k8 & 1) * 8;
  const size_t so = ((size_t)tn << 9) + (size_t)k8 * 8;

  int4 rah0, rah1, ral0, ral1, rbh0, rbh1, rbh2, rbh3, rbl0, rbl1, rbl2, rbl3;
  {
    rah0 = *(const int4*)(Abh + so);              ral0 = *(const int4*)(Abl + so);
    rah1 = *(const int4*)(Abh + so + (32 << 9));  ral1 = *(const int4*)(Abl + so + (32 << 9));
    rbh0 = *(const int4*)(Bbh + so);              rbl0 = *(const int4*)(Bbl + so);
    rbh1 = *(const int4*)(Bbh + so + (32 << 9));  rbl1 = *(const int4*)(Bbl + so + (32 << 9));
    rbh2 = *(const int4*)(Bbh + so + (64 << 9));  rbl2 = *(const int4*)(Bbl + so + (64 << 9));
    rbh3 = *(const int4*)(Bbh + so + (96 << 9));  rbl3 = *(const int4*)(Bbl + so + (96 << 9));
  }

  for (int c = 0; c < 4; ++c) {
    *(int4*)&AH[ks][tn][ko] = rah0;       *(int4*)&AL[ks][tn][ko] = ral0;
    *(int4*)&AH[ks][32 + tn][ko] = rah1;  *(int4*)&AL[ks][32 + tn][ko] = ral1;
    *(int4*)&BH[ks][tn][ko] = rbh0;       *(int4*)&BL[ks][tn][ko] = rbl0;
    *(int4*)&BH[ks][32 + tn][ko] = rbh1;  *(int4*)&BL[ks][32 + tn][ko] = rbl1;
    *(int4*)&BH[ks][64 + tn][ko] = rbh2;  *(int4*)&BL[ks][64 + tn][ko] = rbl2;
    *(int4*)&BH[ks][96 + tn][ko] = rbh3;  *(int4*)&BL[ks][96 + tn][ko] = rbl3;
    __syncthreads();
    if (c < 3) {
      size_t o = so + (size_t)(c + 1) * 64;
      rah0 = *(const int4*)(Abh + o);              ral0 = *(const int4*)(Abl + o);
      rah1 = *(const int4*)(Abh + o + (32 << 9));  ral1 = *(const int4*)(Abl + o + (32 << 9));
      rbh0 = *(const int4*)(Bbh + o);              rbl0 = *(const int4*)(Bbl + o);
      rbh1 = *(const int4*)(Bbh + o + (32 << 9));  rbl1 = *(const int4*)(Bbl + o + (32 << 9));
      rbh2 = *(const int4*)(Bbh + o + (64 << 9));  rbl2 = *(const int4*)(Bbl + o + (64 << 9));
      rbh3 = *(const int4*)(Bbh + o + (96 << 9));  rbl3 = *(const int4*)(Bbl + o + (96 << 9));
    }
#pragma unroll
    for (int t = 0; t < 4; ++t) {
      bf16x8 ah = *(const bf16x8*)&AH[t][wm * 32 + ml][g8];
      bf16x8 al = *(const bf16x8*)&AL[t][wm * 32 + ml][g8];
      bf16x8 bh0 = *(const bf16x8*)&BH[t][wn * 64 + ml][g8];
      bf16x8 bl0 = *(const bf16x8*)&BL[t][wn * 64 + ml][g8];
      acc0 = __builtin_amdgcn_mfma_f32_32x32x16_bf16(ah, bh0, acc0, 0, 0, 0);
      acc0 = __builtin_amdgcn_mfma_f32_32x32x16_bf16(al, bh0, acc0, 0, 0, 0);
      acc0 = __builtin_amdgcn_mfma_f32_32x32x16_bf16(ah, bl0, acc0, 0, 0, 0);
      bf16x8 bh1 = *(const bf16x8*)&BH[t][wn * 64 + 32 + ml][g8];
      bf16x8 bl1 = *(const bf16x8*)&BL[t][wn * 64 + 32 + ml][g8];
      acc1 = __builtin_amdgcn_mfma_f32_32x32x16_bf16(ah, bh1, acc1, 0, 0, 0);
      acc1 = __builtin_amdgcn_mfma_f32_32x32x16_bf16(al, bh1, acc1, 0, 0, 0);
      acc1 = __builtin_amdgcn_mfma_f32_32x32x16_bf16(ah, bl1, acc1, 0, 0, 0);
    }
    __syncthreads();
  }

  float* pc = PC + (size_t)kslice * NN * FDIM;
  const int row0 = mtile * 64 + wm * 32 + 4 * g;
  const int col0 = npair * 128 + wn * 64 + ml;
#pragma unroll
  for (int r = 0; r < 16; ++r) {
    int row = row0 + (r & 3) + 8 * (r >> 2);
    pc[(size_t)row * FDIM + col0] = acc0[r];
    pc[(size_t)row * FDIM + col0 + 32] = acc1[r];
  }
}

// ---------------- Kernel 3: reduce K-slices + fused f1/f2 ------------------
__global__ __launch_bounds__(256) void k_red(
    const float* __restrict__ PC, const float* __restrict__ a1,
    const float* __restrict__ b1, const float* __restrict__ a2,
    const float* __restrict__ b2, float* __restrict__ FTS,
    float* __restrict__ F1t, float* __restrict__ F2t) {
  int i = blockIdx.x * 4 + (threadIdx.x >> 6);
  int lane = threadIdx.x & 63;
  size_t o = (size_t)i * FDIM + lane * 8;
  float4 u0 = *(const float4*)(PC + o);
  float4 u1 = *(const float4*)(PC + o + 4);
  float4 v0 = *(const float4*)(PC + (size_t)NN * FDIM + o);
  float4 v1 = *(const float4*)(PC + (size_t)NN * FDIM + o + 4);
  float4 s0 = make_float4(u0.x + v0.x, u0.y + v0.y, u0.z + v0.z, u0.w + v0.w);
  float4 s1 = make_float4(u1.x + v1.x, u1.y + v1.y, u1.z + v1.z, u1.w + v1.w);
  *(float4*)(FTS + o) = s0;
  *(float4*)(FTS + o + 4) = s1;
  float4 w0 = *(const float4*)(a1 + lane * 8);
  float4 w1 = *(const float4*)(a1 + lane * 8 + 4);
  float4 x0 = *(const float4*)(a2 + lane * 8);
  float4 x1 = *(const float4*)(a2 + lane * 8 + 4);
  float p1 = s0.x * w0.x + s0.y * w0.y + s0.z * w0.z + s0.w * w0.w +
             s1.x * w1.x + s1.y * w1.y + s1.z * w1.z + s1.w * w1.w;
  float p2 = s0.x * x0.x + s0.y * x0.y + s0.z * x0.z + s0.w * x0.w +
             s1.x * x1.x + s1.y * x1.y + s1.z * x1.z + s1.w * x1.w;
  p1 += __shfl_xor(p1, 1); p1 += __shfl_xor(p1, 2); p1 += __shfl_xor(p1, 4);
  p2 += __shfl_xor(p2, 1); p2 += __shfl_xor(p2, 2); p2 += __shfl_xor(p2, 4);
  if ((lane & 7) == 0) {
    int h = lane >> 3;
    F1t[(size_t)i * 8 + h] = p1 + b1[h];
    F2t[(size_t)i * 8 + h] = p2 + b2[h];
  }
}

// ---------------- Kernel 4: sparse softmax + aggregation (4 heads/wave) -----
__global__ __launch_bounds__(256) void k_agg1(
    const float* __restrict__ FTS, const float* __restrict__ F1t,
    const float* __restrict__ F2t, const int* __restrict__ nbr,
    const int* __restrict__ cnt, float* __restrict__ VALS) {
  int wv = threadIdx.x >> 6, lane = threadIdx.x & 63;
  int gw = blockIdx.x * 4 + wv;     // over NN*2
  int i = gw >> 1, hg = gw & 1;
  int deg = cnt[i];
  const int* nb = nbr + (size_t)i * MAXD;
  float4 f1v = *(const float4*)(F1t + (size_t)i * 8 + hg * 4);

  float4 p4[4];
  int jreg[4];
  float mx = -1e30f, my = -1e30f, mz = -1e30f, mw = -1e30f;
#pragma unroll
  for (int r = 0; r < 4; ++r) {
    int t = r * 64 + lane;
    jreg[r] = 0;
    p4[r] = make_float4(-1e30f, -1e30f, -1e30f, -1e30f);
    if (t < deg) {
      int j = nb[t];
      jreg[r] = j;
      float4 f2v = *(const float4*)(F2t + (size_t)j * 8 + hg * 4);
      float4 x;
      x.x = f1v.x + f2v.x; x.x = x.x >= 0.f ? x.x : 0.2f * x.x;
      x.y = f1v.y + f2v.y; x.y = x.y >= 0.f ? x.y : 0.2f * x.y;
      x.z = f1v.z + f2v.z; x.z = x.z >= 0.f ? x.z : 0.2f * x.z;
      x.w = f1v.w + f2v.w; x.w = x.w >= 0.f ? x.w : 0.2f * x.w;
      p4[r] = x;
      mx = fmaxf(mx, x.x); my = fmaxf(my, x.y);
      mz = fmaxf(mz, x.z); mw = fmaxf(mw, x.w);
    }
  }
  mx = wave_max64(mx); my = wave_max64(my);
  mz = wave_max64(mz); mw = wave_max64(mw);
  float sx = 0.f, sy = 0.f, sz = 0.f, sw = 0.f;
#pragma unroll
  for (int r = 0; r < 4; ++r) {
    int t = r * 64 + lane;
    float4 e = make_float4(0.f, 0.f, 0.f, 0.f);
    if (t < deg) {
      e.x = __expf(p4[r].x - mx); e.y = __expf(p4[r].y - my);
      e.z = __expf(p4[r].z - mz); e.w = __expf(p4[r].w - mw);
    }
    p4[r] = e;
    sx += e.x; sy += e.y; sz += e.z; sw += e.w;
  }
  sx = wave_sum64(sx); sy = wave_sum64(sy);
  sz = wave_sum64(sz); sw = wave_sum64(sw);

  int q = lane >> 4;
  float invh = (q < 2) ? (q == 0 ? 1.f / sx : 1.f / sy)
                       : (q == 2 ? 1.f / sz : 1.f / sw);

  // dual-accumulator gather loop (2 neighbors in flight)
  float4 accA = make_float4(0.f, 0.f, 0.f, 0.f);
  float4 accB = make_float4(0.f, 0.f, 0.f, 0.f);
  const float* Fb = FTS + hg * 256;
#pragma unroll
  for (int r = 0; r < 4; ++r) {
    int base = r * 64;
    if (base >= deg) break;
    int lim = deg - base;
    lim = lim < 64 ? lim : 64;
    int sl = 0;
    for (; sl + 2 <= lim; sl += 2) {
      int j0 = readlane_i(jreg[r], sl);
      int j1 = readlane_i(jreg[r], sl + 1);
      float w00 = readlane_f(p4[r].x, sl),     w01 = readlane_f(p4[r].y, sl);
      float w02 = readlane_f(p4[r].z, sl),     w03 = readlane_f(p4[r].w, sl);
      float w10 = readlane_f(p4[r].x, sl + 1), w11 = readlane_f(p4[r].y, sl + 1);
      float w12 = readlane_f(p4[r].z, sl + 1), w13 = readlane_f(p4[r].w, sl + 1);
      float wA = (q < 2) ? (q == 0 ? w00 : w01) : (q == 2 ? w02 : w03);
      float wB = (q < 2) ? (q == 0 ? w10 : w11) : (q == 2 ? w12 : w13);
      float4 f0 = *(const float4*)(Fb + (size_t)j0 * FDIM + lane * 4);
      float4 f1 = *(const float4*)(Fb + (size_t)j1 * FDIM + lane * 4);
      accA.x += wA * f0.x; accA.y += wA * f0.y; accA.z += wA * f0.z; accA.w += wA * f0.w;
      accB.x += wB * f1.x; accB.y += wB * f1.y; accB.z += wB * f1.z; accB.w += wB * f1.w;
    }
    if (sl < lim) {
      int j0 = readlane_i(jreg[r], sl);
      float w00 = readlane_f(p4[r].x, sl), w01 = readlane_f(p4[r].y, sl);
      float w02 = readlane_f(p4[r].z, sl), w03 = readlane_f(p4[r].w, sl);
      float wA = (q < 2) ? (q == 0 ? w00 : w01) : (q == 2 ? w02 : w03);
      float4 f0 = *(const float4*)(Fb + (size_t)j0 * FDIM + lane * 4);
      accA.x += wA * f0.x; accA.y += wA * f0.y; accA.z += wA * f0.z; accA.w += wA * f0.w;
    }
  }
  float4 acc = make_float4((accA.x + accB.x) * invh, (accA.y + accB.y) * invh,
                           (accA.z + accB.z) * invh, (accA.w + accB.w) * invh);
  *(float4*)(VALS + (size_t)i * FDIM + hg * 256 + lane * 4) = acc;
}

// ---------------- Kernel 5: H1 = elu(VALS @ blockdiag(W2) + bW) -------------
__global__ __launch_bounds__(256) void k_w2(
    const float* __restrict__ VALS, const float* __restrict__ W2,
    const float* __restrict__ bW, float* __restrict__ H1) {
  __shared__ float As[64][68];
  __shared__ float Bs[64][64];
  const int rb = blockIdx.x, h = blockIdx.y;
  const int tid = threadIdx.x;
  const int tc = tid & 15, tr = tid >> 4;
  {
    const int arow = tid >> 2, akq = tid & 3;
    const float* Ab = VALS + (size_t)(rb * 64 + arow) * FDIM + h * 64;
#pragma unroll
    for (int qq = 0; qq < 4; ++qq) {
      float4 v = *(const float4*)(Ab + akq * 16 + qq * 4);
      int k = akq * 16 + qq * 4;
      As[k + 0][arow] = v.x; As[k + 1][arow] = v.y;
      As[k + 2][arow] = v.z; As[k + 3][arow] = v.w;
    }
    const float* Bb = W2 + (size_t)h * HDIM * HDIM;
#pragma unroll
    for (int qq = 0; qq < 4; ++qq) {
      int idx = qq * 256 + tid;
      int kr = idx >> 4, nc = (idx & 15) * 4;
      *(float4*)&Bs[kr][nc] = *(const float4*)(Bb + kr * 64 + nc);
    }
  }
  __syncthreads();
  float acc[4][4] = {};
#pragma unroll
  for (int kk = 0; kk < 64; ++kk) {
    float4 av = *(const float4*)&As[kk][tr * 4];
    float4 bv = *(const float4*)&Bs[kk][tc * 4];
    float a[4] = {av.x, av.y, av.z, av.w};
    float b[4] = {bv.x, bv.y, bv.z, bv.w};
#pragma unroll
    for (int i = 0; i < 4; ++i)
#pragma unroll
      for (int j = 0; j < 4; ++j) acc[i][j] += a[i] * b[j];
  }
  float4 bwv = *(const float4*)(bW + h * 64 + tc * 4);
  float bl[4] = {bwv.x, bwv.y, bwv.z, bwv.w};
#pragma unroll
  for (int i = 0; i < 4; ++i) {
    int row = rb * 64 + tr * 4 + i;
    float4 o;
    o.x = acc[i][0] + bl[0]; o.y = acc[i][1] + bl[1];
    o.z = acc[i][2] + bl[2]; o.w = acc[i][3] + bl[3];
    o.x = o.x > 0.f ? o.x : __expf(o.x) - 1.f;
    o.y = o.y > 0.f ? o.y : __expf(o.y) - 1.f;
    o.z = o.z > 0.f ? o.z : __expf(o.z) - 1.f;
    o.w = o.w > 0.f ? o.w : __expf(o.w) - 1.f;
    *(float4*)(H1 + (size_t)row * FDIM + h * 64 + tc * 4) = o;
  }
}

// ---------------- Kernel 6: fts2 = H1 @ Wo1 (+ f1o/f2o) ---------------------
__global__ __launch_bounds__(256) void k_fts2(
    const float* __restrict__ H1, const float* __restrict__ Wo1t,
    const float* __restrict__ ao1, const float* __restrict__ bo1s,
    const float* __restrict__ ao2, const float* __restrict__ bo2s,
    float* __restrict__ FTS2, float* __restrict__ F1O, float* __restrict__ F2O) {
  __shared__ float HL[8][512];
  const int tid = threadIdx.x;
  const int i0 = blockIdx.x * 8;
#pragma unroll
  for (int qq = 0; qq < 4; ++qq) {
    int idx = qq * 256 + tid;
    int r = idx >> 7, c4 = idx & 127;
    *(float4*)&HL[r][c4 * 4] = *(const float4*)(H1 + (size_t)(i0 + r) * FDIM + c4 * 4);
  }
  __syncthreads();
  const int wv = tid >> 6, lane = tid & 63;
  float acc0 = 0.f, acc1 = 0.f;
  const bool act = lane < CDIM;
  const float* wrow = Wo1t + (size_t)lane * FDIM;
  for (int k0 = 0; k0 < FDIM; k0 += 4) {
    float4 w4 = act ? *(const float4*)(wrow + k0) : make_float4(0.f, 0.f, 0.f, 0.f);
    float4 h0 = *(const float4*)&HL[wv * 2][k0];
    float4 h1 = *(const float4*)&HL[wv * 2 + 1][k0];
    acc0 += h0.x * w4.x + h0.y * w4.y + h0.z * w4.z + h0.w * w4.w;
    acc1 += h1.x * w4.x + h1.y * w4.y + h1.z * w4.z + h1.w * w4.w;
  }
  float ao1l = act ? ao1[lane] : 0.f;
  float ao2l = act ? ao2[lane] : 0.f;
#pragma unroll 2
  for (int r = 0; r < 2; ++r) {
    float a = r == 0 ? acc0 : acc1;
    int i = i0 + wv * 2 + r;
    float s1 = wave_sum64(a * ao1l);
    float s2 = wave_sum64(a * ao2l);
    if (lane == 0) {
      F1O[i] = s1 + bo1s[0];
      F2O[i] = s2 + bo2s[0];
    }
    if (act) FTS2[(size_t)i * CDIM + lane] = a;
  }
}

// ---------------- Kernel 7: layer-2 attention + output GEMM (fused) ---------
__global__ __launch_bounds__(256) void k_agg2(
    const float* __restrict__ FTS2, const float* __restrict__ F1O,
    const float* __restrict__ F2O, const int* __restrict__ nbr,
    const int* __restrict__ cnt, const float* __restrict__ Wo2,
    const float* __restrict__ bo, float* __restrict__ out) {
  int i = blockIdx.x * 4 + (threadIdx.x >> 6);
  int lane = threadIdx.x & 63;
  int deg = cnt[i];
  const int* nb = nbr + (size_t)i * MAXD;
  float f1i = F1O[i];

  int jreg[4];
  float p[4];
  float m = -1e30f;
#pragma unroll
  for (int r = 0; r < 4; ++r) { jreg[r] = 0; p[r] = -1e30f; }
#pragma unroll
  for (int r = 0; r < 4; ++r) {
    int t = r * 64 + lane;
    if (t < deg) {
      int j = nb[t];
      jreg[r] = j;
      float x = f1i + F2O[j];
      x = x >= 0.f ? x : 0.2f * x;
      p[r] = x;
      m = fmaxf(m, x);
    }
  }
  m = wave_max64(m);
  float s = 0.f;
#pragma unroll
  for (int r = 0; r < 4; ++r) {
    int t = r * 64 + lane;
    float e = (t < deg) ? __expf(p[r] - m) : 0.f;
    p[r] = e;
    s += e;
  }
  s = wave_sum64(s);

  const bool act = lane < CDIM;
  float acc = 0.f;
#pragma unroll
  for (int r = 0; r < 4; ++r) {
    int base = r * 64;
    if (base >= deg) break;
    int lim = deg - base;
    lim = lim < 64 ? lim : 64;
    for (int sl = 0; sl < lim; ++sl) {
      float w = readlane_f(p[r], sl);
      int j   = readlane_i(jreg[r], sl);
      float fv = act ? FTS2[(size_t)j * CDIM + lane] : 0.f;
      acc += w * fv;
    }
  }
  float v = acc / s;

  float o = act ? bo[lane] : 0.f;
  for (int kk = 0; kk < CDIM; ++kk) {
    float w = readlane_f(v, kk);
    float b = act ? Wo2[kk * CDIM + lane] : 0.f;
    o += w * b;
  }
  if (act) out[(size_t)i * CDIM + lane] = o;
}

extern "C" void kernel_launch(void* const* d_in, const int* in_sizes, int n_in,
                              void* d_out, int out_size, void* d_ws, size_t ws_size,
                              hipStream_t stream) {
  const float* seq  = (const float*)d_in[0];
  const float* bias = (const float*)d_in[1];
  const float* W1   = (const float*)d_in[2];
  const float* a1   = (const float*)d_in[3];
  const float* b1   = (const float*)d_in[4];
  const float* a2   = (const float*)d_in[5];
  const float* b2   = (const float*)d_in[6];
  const float* W2   = (const float*)d_in[7];
  const float* bW   = (const float*)d_in[8];
  const float* Wo1  = (const float*)d_in[9];
  const float* ao1  = (const float*)d_in[10];
  const float* bo1  = (const float*)d_in[11];
  const float* ao2  = (const float*)d_in[12];
  const float* bo2  = (const float*)d_in[13];
  const float* Wo2  = (const float*)d_in[14];
  const float* bo   = (const float*)d_in[15];
  float* out = (float*)d_out;

  float* ws   = (float*)d_ws;
  float* FTS  = ws;                           // N*512 f32
  float* H1   = FTS  + (size_t)NN * FDIM;     // N*512 f32
  float* VALS = H1   + (size_t)NN * FDIM;     // N*512 f32
  float* PC   = H1;                           // GEMM partials [2][N][512] alias H1+VALS
  float* F1t  = VALS + (size_t)NN * FDIM;     // N*8
  float* F2t  = F1t  + (size_t)NN * NHEAD;    // N*8
  float* FTS2 = F2t  + (size_t)NN * NHEAD;    // N*40
  float* F1O  = FTS2 + (size_t)NN * CDIM;     // N
  float* F2O  = F1O  + NN;                    // N
  float* Wo1t = F2O  + NN;                    // 40*512
  short* Ahi  = (short*)(Wo1t + (size_t)CDIM * FDIM);  // N*512 bf16
  short* Alo  = Ahi + (size_t)NN * FDIM;               // N*512 bf16
  short* Bhi  = Alo + (size_t)NN * FDIM;               // 8*64*512 bf16 (k-minor)
  short* Blo  = Bhi + (size_t)NHEAD * HDIM * FDIM;
  int*   nbr  = (int*)(Blo + (size_t)NHEAD * HDIM * FDIM);  // N*MAXD
  int*   cnt  = nbr + (size_t)NN * MAXD;      // N

  // 1. CSR (block/row) + seq->bf16 hi/lo + W1 transpose/convert + Wo1 transpose
  k_prep<<<NN + 1024 + 64 + 1, 256, 0, stream>>>(
      bias, nbr, cnt, seq, Ahi, Alo, W1, Bhi, Blo, Wo1, Wo1t);
  // 2. MFMA hi/lo GEMM -> partials
  k_gemm<<<dim3(NN / 64, NHEAD / 2, 2), 256, 0, stream>>>(Ahi, Alo, Bhi, Blo, PC);
  // 3. reduce K-slices + fused f1/f2
  k_red<<<NN / 4, 256, 0, stream>>>(PC, a1, b1, a2, b2, FTS, F1t, F2t);
  // 4. sparse softmax + aggregation, 4 heads per wave
  k_agg1<<<NN * 2 / 4, 256, 0, stream>>>(FTS, F1t, F2t, nbr, cnt, VALS);
  // 5. per-head W2 GEMM + elu
  k_w2<<<dim3(NN / 64, NHEAD), 256, 0, stream>>>(VALS, W2, bW, H1);
  // 6. layer-2 features + attention terms
  k_fts2<<<NN / 8, 256, 0, stream>>>(H1, Wo1t, ao1, bo1, ao2, bo2, FTS2, F1O, F2O);
  // 7. layer-2 sparse attention + final dense + bias
  k_agg2<<<NN / 4, 256, 0, stream>>>(FTS2, F1O, F2O, nbr, cnt, Wo2, bo, out);
}

// Round 7
// 125.464 us; speedup vs baseline: 2.1506x; 1.0122x over previous
//
#include <hip/hip_runtime.h>
#include <cstdint>
#include <cstddef>

#define NN 4096
#define FDIM 512
#define HDIM 64
#define NHEAD 8
#define CDIM 40
#define MAXD 256   // max neighbors kept per row (~41 expected)

typedef __attribute__((ext_vector_type(8))) short bf16x8;
typedef __attribute__((ext_vector_type(16))) float f32x16;

__device__ __forceinline__ float wave_max64(float v) {
  for (int o = 32; o; o >>= 1) v = fmaxf(v, __shfl_xor(v, o));
  return v;
}
__device__ __forceinline__ float wave_sum64(float v) {
  for (int o = 32; o; o >>= 1) v += __shfl_xor(v, o);
  return v;
}
__device__ __forceinline__ float readlane_f(float v, int sl) {
  return __uint_as_float((unsigned)__builtin_amdgcn_readlane((int)__float_as_uint(v), sl));
}
__device__ __forceinline__ int readlane_i(int v, int sl) {
  return __builtin_amdgcn_readlane(v, sl);
}
// fp32 -> bf16 (RNE) and back, via bit ops
__device__ __forceinline__ unsigned short f2bf(float x) {
  unsigned u = __float_as_uint(x);
  return (unsigned short)((u + 0x7fffu + ((u >> 16) & 1u)) >> 16);
}
__device__ __forceinline__ float bf2f(unsigned short b) {
  return __uint_as_float(((unsigned)b) << 16);
}

// ---------------- Kernel 1: prep = CSR (block/row) + seq->bf16 hi/lo +
//                  W1 transpose+cvt + Wo1 transpose.
__global__ __launch_bounds__(256) void k_prep(
    const float* __restrict__ bias, int* __restrict__ nbr, int* __restrict__ cnt,
    const float* __restrict__ seq, short* __restrict__ Ahi, short* __restrict__ Alo,
    const float* __restrict__ W1, short* __restrict__ Bhi, short* __restrict__ Blo,
    const float* __restrict__ Wo1, float* __restrict__ Wo1t) {
  __shared__ int wtot[4];
  __shared__ float T[64][65];
  int bx = blockIdx.x, tid = threadIdx.x;
  if (bx < NN) {       // ---- CSR: one block per row, thread owns 16 cols
    int row = bx;
    int lane = tid & 63, wv = tid >> 6;
    const float4* r = (const float4*)(bias + (size_t)row * NN);
    unsigned mask = 0;
#pragma unroll
    for (int i = 0; i < 4; ++i) {
      float4 v = r[tid * 4 + i];
      mask |= (unsigned)((v.x == 0.f ? 1 : 0) | (v.y == 0.f ? 2 : 0) |
                         (v.z == 0.f ? 4 : 0) | (v.w == 0.f ? 8 : 0)) << (i * 4);
    }
    int c = __popc(mask);
    int pre = c;
#pragma unroll
    for (int o = 1; o < 64; o <<= 1) {
      int u = __shfl_up(pre, o);
      if (lane >= o) pre += u;
    }
    if (lane == 63) wtot[wv] = pre;
    __syncthreads();
    int woff = 0;
#pragma unroll
    for (int w = 0; w < 4; ++w)
      if (w < wv) woff += wtot[w];
    int excl = woff + pre - c;
    int* out = nbr + (size_t)row * MAXD;
    int col0 = tid * 16, k = 0;
#pragma unroll
    for (int i = 0; i < 16; ++i) {
      if ((mask >> i) & 1) {
        int p = excl + k;
        if (p < MAXD) out[p] = col0 + i;
        ++k;
      }
    }
    if (tid == 0) {
      int total = wtot[0] + wtot[1] + wtot[2] + wtot[3];
      cnt[row] = total < MAXD ? total : MAXD;
    }
    return;
  }
  bx -= NN;
  if (bx < 1024) {     // ---- seq -> bf16 hi/lo (8 elems/thread)
    size_t off = (size_t)bx * 2048 + (size_t)tid * 8;
    float4 v0 = *(const float4*)(seq + off);
    float4 v1 = *(const float4*)(seq + off + 4);
    unsigned short h0 = f2bf(v0.x), h1 = f2bf(v0.y), h2 = f2bf(v0.z), h3 = f2bf(v0.w);
    unsigned short h4 = f2bf(v1.x), h5 = f2bf(v1.y), h6 = f2bf(v1.z), h7 = f2bf(v1.w);
    *(uint4*)(Ahi + off) = make_uint4(
        (unsigned)h0 | ((unsigned)h1 << 16), (unsigned)h2 | ((unsigned)h3 << 16),
        (unsigned)h4 | ((unsigned)h5 << 16), (unsigned)h6 | ((unsigned)h7 << 16));
    unsigned short l0 = f2bf(v0.x - bf2f(h0)), l1 = f2bf(v0.y - bf2f(h1));
    unsigned short l2 = f2bf(v0.z - bf2f(h2)), l3 = f2bf(v0.w - bf2f(h3));
    unsigned short l4 = f2bf(v1.x - bf2f(h4)), l5 = f2bf(v1.y - bf2f(h5));
    unsigned short l6 = f2bf(v1.z - bf2f(h6)), l7 = f2bf(v1.w - bf2f(h7));
    *(uint4*)(Alo + off) = make_uint4(
        (unsigned)l0 | ((unsigned)l1 << 16), (unsigned)l2 | ((unsigned)l3 << 16),
        (unsigned)l4 | ((unsigned)l5 << 16), (unsigned)l6 | ((unsigned)l7 << 16));
    return;
  }
  bx -= 1024;
  if (bx < 64) {       // ---- W1 tile transpose + bf16 hi/lo: [k][n] -> [n][k]
    int h = bx >> 3, kb = bx & 7;
    const float* src = W1 + ((size_t)h * FDIM + kb * 64) * HDIM;
#pragma unroll
    for (int q = 0; q < 4; ++q) {
      int fi = q * 256 + tid, kk = fi >> 4, n4 = fi & 15;
      float4 v = *(const float4*)(src + (size_t)kk * HDIM + n4 * 4);
      T[n4 * 4 + 0][kk] = v.x; T[n4 * 4 + 1][kk] = v.y;
      T[n4 * 4 + 2][kk] = v.z; T[n4 * 4 + 3][kk] = v.w;
    }
    __syncthreads();
#pragma unroll
    for (int q = 0; q < 4; ++q) {
      int fi = q * 256 + tid, n = fi >> 4, k4 = fi & 15;
      float a = T[n][k4 * 4], b = T[n][k4 * 4 + 1];
      float c = T[n][k4 * 4 + 2], d = T[n][k4 * 4 + 3];
      size_t o = ((size_t)h * 64 + n) * FDIM + kb * 64 + k4 * 4;
      unsigned short ha = f2bf(a), hb = f2bf(b), hc = f2bf(c), hd = f2bf(d);
      *(short4*)(Bhi + o) = make_short4((short)ha, (short)hb, (short)hc, (short)hd);
      *(short4*)(Blo + o) = make_short4((short)f2bf(a - bf2f(ha)), (short)f2bf(b - bf2f(hb)),
                                        (short)f2bf(c - bf2f(hc)), (short)f2bf(d - bf2f(hd)));
    }
    return;
  }
  // ---- Wo1 transpose [512][40] -> [40][512]
  for (int idx = tid; idx < CDIM * FDIM; idx += 256) {
    int c = idx >> 9, k = idx & 511;
    Wo1t[idx] = Wo1[k * CDIM + c];
  }
}

// ---------------- Kernel 2: MFMA GEMM (full K) + fused f1/f2 ---------------
// Tile M=64 x N=128 (2 heads), 4 waves; wave = 32 rows x 64 cols = ONE head.
// K-loop: 8 chunks of 64, reg-prefetch staging, 48KB LDS.
// Epilogue writes FTS and F1t/F2t directly (k_red eliminated).
__global__ __launch_bounds__(256) void k_gemm(
    const short* __restrict__ Ahi, const short* __restrict__ Alo,
    const short* __restrict__ Bhi, const short* __restrict__ Blo,
    const float* __restrict__ a1, const float* __restrict__ b1,
    const float* __restrict__ a2, const float* __restrict__ b2,
    float* __restrict__ FTS, float* __restrict__ F1t, float* __restrict__ F2t) {
  __shared__ short AH[4][64][16], AL[4][64][16];    // [kstep16][m][k-slot]
  __shared__ short BH[4][128][16], BL[4][128][16];  // [kstep16][n][k-slot]
  const int mtile = blockIdx.x, npair = blockIdx.y;
  const int tid = threadIdx.x, lane = tid & 63, w = tid >> 6;
  const int wm = w >> 1, wn = w & 1;
  const int ml = lane & 31, g = lane >> 5, g8 = g * 8;

  f32x16 acc0, acc1;
#pragma unroll
  for (int r = 0; r < 16; ++r) { acc0[r] = 0.f; acc1[r] = 0.f; }

  const short* Abh = Ahi + (((size_t)mtile * 64) << 9);
  const short* Abl = Alo + (((size_t)mtile * 64) << 9);
  const short* Bbh = Bhi + (((size_t)npair * 128) << 9);
  const short* Bbl = Blo + (((size_t)npair * 128) << 9);

  const int tn = tid >> 3, k8 = tid & 7;
  const int ks = k8 >> 1, ko = (k8 & 1) * 8;
  const size_t so = ((size_t)tn << 9) + (size_t)k8 * 8;

  int4 rah0, rah1, ral0, ral1, rbh0, rbh1, rbh2, rbh3, rbl0, rbl1, rbl2, rbl3;
  {
    rah0 = *(const int4*)(Abh + so);              ral0 = *(const int4*)(Abl + so);
    rah1 = *(const int4*)(Abh + so + (32 << 9));  ral1 = *(const int4*)(Abl + so + (32 << 9));
    rbh0 = *(const int4*)(Bbh + so);              rbl0 = *(const int4*)(Bbl + so);
    rbh1 = *(const int4*)(Bbh + so + (32 << 9));  rbl1 = *(const int4*)(Bbl + so + (32 << 9));
    rbh2 = *(const int4*)(Bbh + so + (64 << 9));  rbl2 = *(const int4*)(Bbl + so + (64 << 9));
    rbh3 = *(const int4*)(Bbh + so + (96 << 9));  rbl3 = *(const int4*)(Bbl + so + (96 << 9));
  }

  const int NCH = FDIM / 64;   // 8 chunks
  for (int c = 0; c < NCH; ++c) {
    *(int4*)&AH[ks][tn][ko] = rah0;       *(int4*)&AL[ks][tn][ko] = ral0;
    *(int4*)&AH[ks][32 + tn][ko] = rah1;  *(int4*)&AL[ks][32 + tn][ko] = ral1;
    *(int4*)&BH[ks][tn][ko] = rbh0;       *(int4*)&BL[ks][tn][ko] = rbl0;
    *(int4*)&BH[ks][32 + tn][ko] = rbh1;  *(int4*)&BL[ks][32 + tn][ko] = rbl1;
    *(int4*)&BH[ks][64 + tn][ko] = rbh2;  *(int4*)&BL[ks][64 + tn][ko] = rbl2;
    *(int4*)&BH[ks][96 + tn][ko] = rbh3;  *(int4*)&BL[ks][96 + tn][ko] = rbl3;
    __syncthreads();
    if (c + 1 < NCH) {
      size_t o = so + (size_t)(c + 1) * 64;
      rah0 = *(const int4*)(Abh + o);              ral0 = *(const int4*)(Abl + o);
      rah1 = *(const int4*)(Abh + o + (32 << 9));  ral1 = *(const int4*)(Abl + o + (32 << 9));
      rbh0 = *(const int4*)(Bbh + o);              rbl0 = *(const int4*)(Bbl + o);
      rbh1 = *(const int4*)(Bbh + o + (32 << 9));  rbl1 = *(const int4*)(Bbl + o + (32 << 9));
      rbh2 = *(const int4*)(Bbh + o + (64 << 9));  rbl2 = *(const int4*)(Bbl + o + (64 << 9));
      rbh3 = *(const int4*)(Bbh + o + (96 << 9));  rbl3 = *(const int4*)(Bbl + o + (96 << 9));
    }
#pragma unroll
    for (int t = 0; t < 4; ++t) {
      bf16x8 ah = *(const bf16x8*)&AH[t][wm * 32 + ml][g8];
      bf16x8 al = *(const bf16x8*)&AL[t][wm * 32 + ml][g8];
      bf16x8 bh0 = *(const bf16x8*)&BH[t][wn * 64 + ml][g8];
      bf16x8 bl0 = *(const bf16x8*)&BL[t][wn * 64 + ml][g8];
      acc0 = __builtin_amdgcn_mfma_f32_32x32x16_bf16(ah, bh0, acc0, 0, 0, 0);
      acc0 = __builtin_amdgcn_mfma_f32_32x32x16_bf16(al, bh0, acc0, 0, 0, 0);
      acc0 = __builtin_amdgcn_mfma_f32_32x32x16_bf16(ah, bl0, acc0, 0, 0, 0);
      bf16x8 bh1 = *(const bf16x8*)&BH[t][wn * 64 + 32 + ml][g8];
      bf16x8 bl1 = *(const bf16x8*)&BL[t][wn * 64 + 32 + ml][g8];
      acc1 = __builtin_amdgcn_mfma_f32_32x32x16_bf16(ah, bh1, acc1, 0, 0, 0);
      acc1 = __builtin_amdgcn_mfma_f32_32x32x16_bf16(al, bh1, acc1, 0, 0, 0);
      acc1 = __builtin_amdgcn_mfma_f32_32x32x16_bf16(ah, bl1, acc1, 0, 0, 0);
    }
    __syncthreads();
  }

  // epilogue: C layout col=lane&31, row=(r&3)+8*(r>>2)+4*(lane>>5)
  // wave covers one full head h: cols wn*64..wn*64+63 of pair npair.
  const int h = npair * 2 + wn;
  const float a1lo = a1[h * 64 + ml], a1hi = a1[h * 64 + 32 + ml];
  const float a2lo = a2[h * 64 + ml], a2hi = a2[h * 64 + 32 + ml];
  const float b1h = b1[h], b2h = b2[h];
  const int row0 = mtile * 64 + wm * 32 + 4 * g;
  const int col0 = npair * 128 + wn * 64 + ml;
#pragma unroll
  for (int r = 0; r < 16; ++r) {
    int row = row0 + (r & 3) + 8 * (r >> 2);
    FTS[(size_t)row * FDIM + col0] = acc0[r];
    FTS[(size_t)row * FDIM + col0 + 32] = acc1[r];
    float p1 = acc0[r] * a1lo + acc1[r] * a1hi;
    float p2 = acc0[r] * a2lo + acc1[r] * a2hi;
#pragma unroll
    for (int o = 1; o < 32; o <<= 1) {
      p1 += __shfl_xor(p1, o);
      p2 += __shfl_xor(p2, o);
    }
    if (ml == 0) {
      F1t[(size_t)row * 8 + h] = p1 + b1h;
      F2t[(size_t)row * 8 + h] = p2 + b2h;
    }
  }
}

// ---------------- Kernel 3: sparse softmax + aggregation (4 heads/wave) -----
__global__ __launch_bounds__(256) void k_agg1(
    const float* __restrict__ FTS, const float* __restrict__ F1t,
    const float* __restrict__ F2t, const int* __restrict__ nbr,
    const int* __restrict__ cnt, float* __restrict__ VALS) {
  int wv = threadIdx.x >> 6, lane = threadIdx.x & 63;
  int gw = blockIdx.x * 4 + wv;     // over NN*2
  int i = gw >> 1, hg = gw & 1;
  int deg = cnt[i];
  const int* nb = nbr + (size_t)i * MAXD;
  float4 f1v = *(const float4*)(F1t + (size_t)i * 8 + hg * 4);

  float4 p4[4];
  int jreg[4];
  float mx = -1e30f, my = -1e30f, mz = -1e30f, mw = -1e30f;
#pragma unroll
  for (int r = 0; r < 4; ++r) {
    int t = r * 64 + lane;
    jreg[r] = 0;
    p4[r] = make_float4(-1e30f, -1e30f, -1e30f, -1e30f);
    if (t < deg) {
      int j = nb[t];
      jreg[r] = j;
      float4 f2v = *(const float4*)(F2t + (size_t)j * 8 + hg * 4);
      float4 x;
      x.x = f1v.x + f2v.x; x.x = x.x >= 0.f ? x.x : 0.2f * x.x;
      x.y = f1v.y + f2v.y; x.y = x.y >= 0.f ? x.y : 0.2f * x.y;
      x.z = f1v.z + f2v.z; x.z = x.z >= 0.f ? x.z : 0.2f * x.z;
      x.w = f1v.w + f2v.w; x.w = x.w >= 0.f ? x.w : 0.2f * x.w;
      p4[r] = x;
      mx = fmaxf(mx, x.x); my = fmaxf(my, x.y);
      mz = fmaxf(mz, x.z); mw = fmaxf(mw, x.w);
    }
  }
  mx = wave_max64(mx); my = wave_max64(my);
  mz = wave_max64(mz); mw = wave_max64(mw);
  float sx = 0.f, sy = 0.f, sz = 0.f, sw = 0.f;
#pragma unroll
  for (int r = 0; r < 4; ++r) {
    int t = r * 64 + lane;
    float4 e = make_float4(0.f, 0.f, 0.f, 0.f);
    if (t < deg) {
      e.x = __expf(p4[r].x - mx); e.y = __expf(p4[r].y - my);
      e.z = __expf(p4[r].z - mz); e.w = __expf(p4[r].w - mw);
    }
    p4[r] = e;
    sx += e.x; sy += e.y; sz += e.z; sw += e.w;
  }
  sx = wave_sum64(sx); sy = wave_sum64(sy);
  sz = wave_sum64(sz); sw = wave_sum64(sw);

  int q = lane >> 4;
  float invh = (q < 2) ? (q == 0 ? 1.f / sx : 1.f / sy)
                       : (q == 2 ? 1.f / sz : 1.f / sw);

  float4 accA = make_float4(0.f, 0.f, 0.f, 0.f);
  float4 accB = make_float4(0.f, 0.f, 0.f, 0.f);
  const float* Fb = FTS + hg * 256;
#pragma unroll
  for (int r = 0; r < 4; ++r) {
    int base = r * 64;
    if (base >= deg) break;
    int lim = deg - base;
    lim = lim < 64 ? lim : 64;
    int sl = 0;
    for (; sl + 2 <= lim; sl += 2) {
      int j0 = readlane_i(jreg[r], sl);
      int j1 = readlane_i(jreg[r], sl + 1);
      float w00 = readlane_f(p4[r].x, sl),     w01 = readlane_f(p4[r].y, sl);
      float w02 = readlane_f(p4[r].z, sl),     w03 = readlane_f(p4[r].w, sl);
      float w10 = readlane_f(p4[r].x, sl + 1), w11 = readlane_f(p4[r].y, sl + 1);
      float w12 = readlane_f(p4[r].z, sl + 1), w13 = readlane_f(p4[r].w, sl + 1);
      float wA = (q < 2) ? (q == 0 ? w00 : w01) : (q == 2 ? w02 : w03);
      float wB = (q < 2) ? (q == 0 ? w10 : w11) : (q == 2 ? w12 : w13);
      float4 f0 = *(const float4*)(Fb + (size_t)j0 * FDIM + lane * 4);
      float4 f1 = *(const float4*)(Fb + (size_t)j1 * FDIM + lane * 4);
      accA.x += wA * f0.x; accA.y += wA * f0.y; accA.z += wA * f0.z; accA.w += wA * f0.w;
      accB.x += wB * f1.x; accB.y += wB * f1.y; accB.z += wB * f1.z; accB.w += wB * f1.w;
    }
    if (sl < lim) {
      int j0 = readlane_i(jreg[r], sl);
      float w00 = readlane_f(p4[r].x, sl), w01 = readlane_f(p4[r].y, sl);
      float w02 = readlane_f(p4[r].z, sl), w03 = readlane_f(p4[r].w, sl);
      float wA = (q < 2) ? (q == 0 ? w00 : w01) : (q == 2 ? w02 : w03);
      float4 f0 = *(const float4*)(Fb + (size_t)j0 * FDIM + lane * 4);
      accA.x += wA * f0.x; accA.y += wA * f0.y; accA.z += wA * f0.z; accA.w += wA * f0.w;
    }
  }
  float4 acc = make_float4((accA.x + accB.x) * invh, (accA.y + accB.y) * invh,
                           (accA.z + accB.z) * invh, (accA.w + accB.w) * invh);
  *(float4*)(VALS + (size_t)i * FDIM + hg * 256 + lane * 4) = acc;
}

// ---------------- Kernel 4: H1 = elu(VALS @ blockdiag(W2) + bW) -------------
__global__ __launch_bounds__(256) void k_w2(
    const float* __restrict__ VALS, const float* __restrict__ W2,
    const float* __restrict__ bW, float* __restrict__ H1) {
  __shared__ float As[64][68];
  __shared__ float Bs[64][64];
  const int rb = blockIdx.x, h = blockIdx.y;
  const int tid = threadIdx.x;
  const int tc = tid & 15, tr = tid >> 4;
  {
    const int arow = tid >> 2, akq = tid & 3;
    const float* Ab = VALS + (size_t)(rb * 64 + arow) * FDIM + h * 64;
#pragma unroll
    for (int qq = 0; qq < 4; ++qq) {
      float4 v = *(const float4*)(Ab + akq * 16 + qq * 4);
      int k = akq * 16 + qq * 4;
      As[k + 0][arow] = v.x; As[k + 1][arow] = v.y;
      As[k + 2][arow] = v.z; As[k + 3][arow] = v.w;
    }
    const float* Bb = W2 + (size_t)h * HDIM * HDIM;
#pragma unroll
    for (int qq = 0; qq < 4; ++qq) {
      int idx = qq * 256 + tid;
      int kr = idx >> 4, nc = (idx & 15) * 4;
      *(float4*)&Bs[kr][nc] = *(const float4*)(Bb + kr * 64 + nc);
    }
  }
  __syncthreads();
  float acc[4][4] = {};
#pragma unroll
  for (int kk = 0; kk < 64; ++kk) {
    float4 av = *(const float4*)&As[kk][tr * 4];
    float4 bv = *(const float4*)&Bs[kk][tc * 4];
    float a[4] = {av.x, av.y, av.z, av.w};
    float b[4] = {bv.x, bv.y, bv.z, bv.w};
#pragma unroll
    for (int i = 0; i < 4; ++i)
#pragma unroll
      for (int j = 0; j < 4; ++j) acc[i][j] += a[i] * b[j];
  }
  float4 bwv = *(const float4*)(bW + h * 64 + tc * 4);
  float bl[4] = {bwv.x, bwv.y, bwv.z, bwv.w};
#pragma unroll
  for (int i = 0; i < 4; ++i) {
    int row = rb * 64 + tr * 4 + i;
    float4 o;
    o.x = acc[i][0] + bl[0]; o.y = acc[i][1] + bl[1];
    o.z = acc[i][2] + bl[2]; o.w = acc[i][3] + bl[3];
    o.x = o.x > 0.f ? o.x : __expf(o.x) - 1.f;
    o.y = o.y > 0.f ? o.y : __expf(o.y) - 1.f;
    o.z = o.z > 0.f ? o.z : __expf(o.z) - 1.f;
    o.w = o.w > 0.f ? o.w : __expf(o.w) - 1.f;
    *(float4*)(H1 + (size_t)row * FDIM + h * 64 + tc * 4) = o;
  }
}

// ---------------- Kernel 5: fts2 = H1 @ Wo1 (+ f1o/f2o) ---------------------
__global__ __launch_bounds__(256) void k_fts2(
    const float* __restrict__ H1, const float* __restrict__ Wo1t,
    const float* __restrict__ ao1, const float* __restrict__ bo1s,
    const float* __restrict__ ao2, const float* __restrict__ bo2s,
    float* __restrict__ FTS2, float* __restrict__ F1O, float* __restrict__ F2O) {
  __shared__ float HL[8][512];
  const int tid = threadIdx.x;
  const int i0 = blockIdx.x * 8;
#pragma unroll
  for (int qq = 0; qq < 4; ++qq) {
    int idx = qq * 256 + tid;
    int r = idx >> 7, c4 = idx & 127;
    *(float4*)&HL[r][c4 * 4] = *(const float4*)(H1 + (size_t)(i0 + r) * FDIM + c4 * 4);
  }
  __syncthreads();
  const int wv = tid >> 6, lane = tid & 63;
  float acc0 = 0.f, acc1 = 0.f;
  const bool act = lane < CDIM;
  const float* wrow = Wo1t + (size_t)lane * FDIM;
  for (int k0 = 0; k0 < FDIM; k0 += 4) {
    float4 w4 = act ? *(const float4*)(wrow + k0) : make_float4(0.f, 0.f, 0.f, 0.f);
    float4 h0 = *(const float4*)&HL[wv * 2][k0];
    float4 h1 = *(const float4*)&HL[wv * 2 + 1][k0];
    acc0 += h0.x * w4.x + h0.y * w4.y + h0.z * w4.z + h0.w * w4.w;
    acc1 += h1.x * w4.x + h1.y * w4.y + h1.z * w4.z + h1.w * w4.w;
  }
  float ao1l = act ? ao1[lane] : 0.f;
  float ao2l = act ? ao2[lane] : 0.f;
#pragma unroll 2
  for (int r = 0; r < 2; ++r) {
    float a = r == 0 ? acc0 : acc1;
    int i = i0 + wv * 2 + r;
    float s1 = wave_sum64(a * ao1l);
    float s2 = wave_sum64(a * ao2l);
    if (lane == 0) {
      F1O[i] = s1 + bo1s[0];
      F2O[i] = s2 + bo2s[0];
    }
    if (act) FTS2[(size_t)i * CDIM + lane] = a;
  }
}

// ---------------- Kernel 6: layer-2 attention + output GEMM (fused) ---------
__global__ __launch_bounds__(256) void k_agg2(
    const float* __restrict__ FTS2, const float* __restrict__ F1O,
    const float* __restrict__ F2O, const int* __restrict__ nbr,
    const int* __restrict__ cnt, const float* __restrict__ Wo2,
    const float* __restrict__ bo, float* __restrict__ out) {
  int i = blockIdx.x * 4 + (threadIdx.x >> 6);
  int lane = threadIdx.x & 63;
  int deg = cnt[i];
  const int* nb = nbr + (size_t)i * MAXD;
  float f1i = F1O[i];

  int jreg[4];
  float p[4];
  float m = -1e30f;
#pragma unroll
  for (int r = 0; r < 4; ++r) { jreg[r] = 0; p[r] = -1e30f; }
#pragma unroll
  for (int r = 0; r < 4; ++r) {
    int t = r * 64 + lane;
    if (t < deg) {
      int j = nb[t];
      jreg[r] = j;
      float x = f1i + F2O[j];
      x = x >= 0.f ? x : 0.2f * x;
      p[r] = x;
      m = fmaxf(m, x);
    }
  }
  m = wave_max64(m);
  float s = 0.f;
#pragma unroll
  for (int r = 0; r < 4; ++r) {
    int t = r * 64 + lane;
    float e = (t < deg) ? __expf(p[r] - m) : 0.f;
    p[r] = e;
    s += e;
  }
  s = wave_sum64(s);

  const bool act = lane < CDIM;
  float acc = 0.f;
#pragma unroll
  for (int r = 0; r < 4; ++r) {
    int base = r * 64;
    if (base >= deg) break;
    int lim = deg - base;
    lim = lim < 64 ? lim : 64;
    for (int sl = 0; sl < lim; ++sl) {
      float w = readlane_f(p[r], sl);
      int j   = readlane_i(jreg[r], sl);
      float fv = act ? FTS2[(size_t)j * CDIM + lane] : 0.f;
      acc += w * fv;
    }
  }
  float v = acc / s;

  float o = act ? bo[lane] : 0.f;
  for (int kk = 0; kk < CDIM; ++kk) {
    float w = readlane_f(v, kk);
    float b = act ? Wo2[kk * CDIM + lane] : 0.f;
    o += w * b;
  }
  if (act) out[(size_t)i * CDIM + lane] = o;
}

extern "C" void kernel_launch(void* const* d_in, const int* in_sizes, int n_in,
                              void* d_out, int out_size, void* d_ws, size_t ws_size,
                              hipStream_t stream) {
  const float* seq  = (const float*)d_in[0];
  const float* bias = (const float*)d_in[1];
  const float* W1   = (const float*)d_in[2];
  const float* a1   = (const float*)d_in[3];
  const float* b1   = (const float*)d_in[4];
  const float* a2   = (const float*)d_in[5];
  const float* b2   = (const float*)d_in[6];
  const float* W2   = (const float*)d_in[7];
  const float* bW   = (const float*)d_in[8];
  const float* Wo1  = (const float*)d_in[9];
  const float* ao1  = (const float*)d_in[10];
  const float* bo1  = (const float*)d_in[11];
  const float* ao2  = (const float*)d_in[12];
  const float* bo2  = (const float*)d_in[13];
  const float* Wo2  = (const float*)d_in[14];
  const float* bo   = (const float*)d_in[15];
  float* out = (float*)d_out;

  float* ws   = (float*)d_ws;
  float* FTS  = ws;                           // N*512 f32
  float* H1   = FTS  + (size_t)NN * FDIM;     // N*512 f32
  float* VALS = H1   + (size_t)NN * FDIM;     // N*512 f32
  float* F1t  = VALS + (size_t)NN * FDIM;     // N*8
  float* F2t  = F1t  + (size_t)NN * NHEAD;    // N*8
  float* FTS2 = F2t  + (size_t)NN * NHEAD;    // N*40
  float* F1O  = FTS2 + (size_t)NN * CDIM;     // N
  float* F2O  = F1O  + NN;                    // N
  float* Wo1t = F2O  + NN;                    // 40*512
  short* Ahi  = (short*)(Wo1t + (size_t)CDIM * FDIM);  // N*512 bf16
  short* Alo  = Ahi + (size_t)NN * FDIM;               // N*512 bf16
  short* Bhi  = Alo + (size_t)NN * FDIM;               // 8*64*512 bf16 (k-minor)
  short* Blo  = Bhi + (size_t)NHEAD * HDIM * FDIM;
  int*   nbr  = (int*)(Blo + (size_t)NHEAD * HDIM * FDIM);  // N*MAXD
  int*   cnt  = nbr + (size_t)NN * MAXD;      // N

  // 1. CSR (block/row) + seq->bf16 hi/lo + W1 transpose/convert + Wo1 transpose
  k_prep<<<NN + 1024 + 64 + 1, 256, 0, stream>>>(
      bias, nbr, cnt, seq, Ahi, Alo, W1, Bhi, Blo, Wo1, Wo1t);
  // 2. MFMA hi/lo GEMM (full K) + fused f1/f2 -> FTS, F1t, F2t
  k_gemm<<<dim3(NN / 64, NHEAD / 2), 256, 0, stream>>>(
      Ahi, Alo, Bhi, Blo, a1, b1, a2, b2, FTS, F1t, F2t);
  // 3. sparse softmax + aggregation, 4 heads per wave
  k_agg1<<<NN * 2 / 4, 256, 0, stream>>>(FTS, F1t, F2t, nbr, cnt, VALS);
  // 4. per-head W2 GEMM + elu
  k_w2<<<dim3(NN / 64, NHEAD), 256, 0, stream>>>(VALS, W2, bW, H1);
  // 5. layer-2 features + attention terms
  k_fts2<<<NN / 8, 256, 0, stream>>>(H1, Wo1t, ao1, bo1, ao2, bo2, FTS2, F1O, F2O);
  // 6. layer-2 sparse attention + final dense + bias
  k_agg2<<<NN / 4, 256, 0, stream>>>(FTS2, F1O, F2O, nbr, cnt, Wo2, bo, out);
}

// Round 8
// 101.931 us; speedup vs baseline: 2.6471x; 1.2309x over previous
//
#include <hip/hip_runtime.h>
#include <cstdint>
#include <cstddef>

#define NN 4096
#define FDIM 512
#define HDIM 64
#define NHEAD 8
#define CDIM 40
#define MAXD 256   // max neighbors kept per row (~41 expected)

typedef __attribute__((ext_vector_type(8))) short bf16x8;
typedef __attribute__((ext_vector_type(16))) float f32x16;

__device__ __forceinline__ float wave_max64(float v) {
  for (int o = 32; o; o >>= 1) v = fmaxf(v, __shfl_xor(v, o));
  return v;
}
__device__ __forceinline__ float wave_sum64(float v) {
  for (int o = 32; o; o >>= 1) v += __shfl_xor(v, o);
  return v;
}
__device__ __forceinline__ float readlane_f(float v, int sl) {
  return __uint_as_float((unsigned)__builtin_amdgcn_readlane((int)__float_as_uint(v), sl));
}
__device__ __forceinline__ int readlane_i(int v, int sl) {
  return __builtin_amdgcn_readlane(v, sl);
}
// fp32 -> bf16 (RNE) and back, via bit ops
__device__ __forceinline__ unsigned short f2bf(float x) {
  unsigned u = __float_as_uint(x);
  return (unsigned short)((u + 0x7fffu + ((u >> 16) & 1u)) >> 16);
}
__device__ __forceinline__ float bf2f(unsigned short b) {
  return __uint_as_float(((unsigned)b) << 16);
}

// ---------------- Kernel 1: prep -------------------------------------------
// Grid = 4096 csr + 1024 seq-cvt + 64 W1 + 8 W2t + 8 Wo1t = 5200 blocks.
__global__ __launch_bounds__(256) void k_prep(
    const float* __restrict__ bias, int* __restrict__ nbr, int* __restrict__ cnt,
    const float* __restrict__ seq, short* __restrict__ Ahi, short* __restrict__ Alo,
    const float* __restrict__ W1, short* __restrict__ Bhi, short* __restrict__ Blo,
    const float* __restrict__ W2, short* __restrict__ W2thi, short* __restrict__ W2tlo,
    const float* __restrict__ Wo1, short* __restrict__ Wo1thi, short* __restrict__ Wo1tlo) {
  __shared__ int wtot[4];
  __shared__ float T[64][65];
  int bx = blockIdx.x, tid = threadIdx.x;
  if (bx < NN) {       // ---- CSR: one block per row, thread owns 16 cols
    int row = bx;
    int lane = tid & 63, wv = tid >> 6;
    const float4* r = (const float4*)(bias + (size_t)row * NN);
    unsigned mask = 0;
#pragma unroll
    for (int i = 0; i < 4; ++i) {
      float4 v = r[tid * 4 + i];
      mask |= (unsigned)((v.x == 0.f ? 1 : 0) | (v.y == 0.f ? 2 : 0) |
                         (v.z == 0.f ? 4 : 0) | (v.w == 0.f ? 8 : 0)) << (i * 4);
    }
    int c = __popc(mask);
    int pre = c;
#pragma unroll
    for (int o = 1; o < 64; o <<= 1) {
      int u = __shfl_up(pre, o);
      if (lane >= o) pre += u;
    }
    if (lane == 63) wtot[wv] = pre;
    __syncthreads();
    int woff = 0;
#pragma unroll
    for (int w = 0; w < 4; ++w)
      if (w < wv) woff += wtot[w];
    int excl = woff + pre - c;
    int* out = nbr + (size_t)row * MAXD;
    int col0 = tid * 16, k = 0;
#pragma unroll
    for (int i = 0; i < 16; ++i) {
      if ((mask >> i) & 1) {
        int p = excl + k;
        if (p < MAXD) out[p] = col0 + i;
        ++k;
      }
    }
    if (tid == 0) {
      int total = wtot[0] + wtot[1] + wtot[2] + wtot[3];
      cnt[row] = total < MAXD ? total : MAXD;
    }
    return;
  }
  bx -= NN;
  if (bx < 1024) {     // ---- seq -> bf16 hi/lo (8 elems/thread)
    size_t off = (size_t)bx * 2048 + (size_t)tid * 8;
    float4 v0 = *(const float4*)(seq + off);
    float4 v1 = *(const float4*)(seq + off + 4);
    unsigned short h0 = f2bf(v0.x), h1 = f2bf(v0.y), h2 = f2bf(v0.z), h3 = f2bf(v0.w);
    unsigned short h4 = f2bf(v1.x), h5 = f2bf(v1.y), h6 = f2bf(v1.z), h7 = f2bf(v1.w);
    *(uint4*)(Ahi + off) = make_uint4(
        (unsigned)h0 | ((unsigned)h1 << 16), (unsigned)h2 | ((unsigned)h3 << 16),
        (unsigned)h4 | ((unsigned)h5 << 16), (unsigned)h6 | ((unsigned)h7 << 16));
    unsigned short l0 = f2bf(v0.x - bf2f(h0)), l1 = f2bf(v0.y - bf2f(h1));
    unsigned short l2 = f2bf(v0.z - bf2f(h2)), l3 = f2bf(v0.w - bf2f(h3));
    unsigned short l4 = f2bf(v1.x - bf2f(h4)), l5 = f2bf(v1.y - bf2f(h5));
    unsigned short l6 = f2bf(v1.z - bf2f(h6)), l7 = f2bf(v1.w - bf2f(h7));
    *(uint4*)(Alo + off) = make_uint4(
        (unsigned)l0 | ((unsigned)l1 << 16), (unsigned)l2 | ((unsigned)l3 << 16),
        (unsigned)l4 | ((unsigned)l5 << 16), (unsigned)l6 | ((unsigned)l7 << 16));
    return;
  }
  bx -= 1024;
  if (bx < 64) {       // ---- W1 tile transpose + bf16 hi/lo: [k][n] -> [n][k]
    int h = bx >> 3, kb = bx & 7;
    const float* src = W1 + ((size_t)h * FDIM + kb * 64) * HDIM;
#pragma unroll
    for (int q = 0; q < 4; ++q) {
      int fi = q * 256 + tid, kk = fi >> 4, n4 = fi & 15;
      float4 v = *(const float4*)(src + (size_t)kk * HDIM + n4 * 4);
      T[n4 * 4 + 0][kk] = v.x; T[n4 * 4 + 1][kk] = v.y;
      T[n4 * 4 + 2][kk] = v.z; T[n4 * 4 + 3][kk] = v.w;
    }
    __syncthreads();
#pragma unroll
    for (int q = 0; q < 4; ++q) {
      int fi = q * 256 + tid, n = fi >> 4, k4 = fi & 15;
      float a = T[n][k4 * 4], b = T[n][k4 * 4 + 1];
      float c = T[n][k4 * 4 + 2], d = T[n][k4 * 4 + 3];
      size_t o = ((size_t)h * 64 + n) * FDIM + kb * 64 + k4 * 4;
      unsigned short ha = f2bf(a), hb = f2bf(b), hc = f2bf(c), hd = f2bf(d);
      *(short4*)(Bhi + o) = make_short4((short)ha, (short)hb, (short)hc, (short)hd);
      *(short4*)(Blo + o) = make_short4((short)f2bf(a - bf2f(ha)), (short)f2bf(b - bf2f(hb)),
                                        (short)f2bf(c - bf2f(hc)), (short)f2bf(d - bf2f(hd)));
    }
    return;
  }
  bx -= 64;
  if (bx < 8) {        // ---- W2[h] transpose [64k][64n] -> [n][k] hi/lo
    int h = bx;
    const float* src = W2 + (size_t)h * HDIM * HDIM;
#pragma unroll
    for (int q = 0; q < 4; ++q) {
      int fi = q * 256 + tid, kk = fi >> 4, n4 = fi & 15;
      float4 v = *(const float4*)(src + (size_t)kk * HDIM + n4 * 4);
      T[n4 * 4 + 0][kk] = v.x; T[n4 * 4 + 1][kk] = v.y;
      T[n4 * 4 + 2][kk] = v.z; T[n4 * 4 + 3][kk] = v.w;
    }
    __syncthreads();
#pragma unroll
    for (int q = 0; q < 4; ++q) {
      int fi = q * 256 + tid, n = fi >> 4, k4 = fi & 15;
      float a = T[n][k4 * 4], b = T[n][k4 * 4 + 1];
      float c = T[n][k4 * 4 + 2], d = T[n][k4 * 4 + 3];
      size_t o = (size_t)h * 4096 + (size_t)n * 64 + k4 * 4;
      unsigned short ha = f2bf(a), hb = f2bf(b), hc = f2bf(c), hd = f2bf(d);
      *(short4*)(W2thi + o) = make_short4((short)ha, (short)hb, (short)hc, (short)hd);
      *(short4*)(W2tlo + o) = make_short4((short)f2bf(a - bf2f(ha)), (short)f2bf(b - bf2f(hb)),
                                          (short)f2bf(c - bf2f(hc)), (short)f2bf(d - bf2f(hd)));
    }
    return;
  }
  bx -= 8;
  {                    // ---- Wo1 transpose+pad [512][40] -> [64][512] hi/lo
    // block bx handles n-rows bx*8 .. bx*8+7
#pragma unroll
    for (int q = 0; q < 16; ++q) {
      int idx = q * 256 + tid;          // 0..4095
      int n = bx * 8 + (idx >> 9), k = idx & 511;
      float v = (n < CDIM) ? Wo1[(size_t)k * CDIM + n] : 0.f;
      unsigned short hv = f2bf(v);
      Wo1thi[(size_t)n * FDIM + k] = (short)hv;
      Wo1tlo[(size_t)n * FDIM + k] = (short)f2bf(v - bf2f(hv));
    }
  }
}

// ---------------- Kernel 2: MFMA GEMM (full K) + fused f1/f2 ---------------
__global__ __launch_bounds__(256) void k_gemm(
    const short* __restrict__ Ahi, const short* __restrict__ Alo,
    const short* __restrict__ Bhi, const short* __restrict__ Blo,
    const float* __restrict__ a1, const float* __restrict__ b1,
    const float* __restrict__ a2, const float* __restrict__ b2,
    float* __restrict__ FTS, float* __restrict__ F1t, float* __restrict__ F2t) {
  __shared__ short AH[4][64][16], AL[4][64][16];    // [kstep16][m][k-slot]
  __shared__ short BH[4][128][16], BL[4][128][16];  // [kstep16][n][k-slot]
  const int mtile = blockIdx.x, npair = blockIdx.y;
  const int tid = threadIdx.x, lane = tid & 63, w = tid >> 6;
  const int wm = w >> 1, wn = w & 1;
  const int ml = lane & 31, g = lane >> 5, g8 = g * 8;

  f32x16 acc0, acc1;
#pragma unroll
  for (int r = 0; r < 16; ++r) { acc0[r] = 0.f; acc1[r] = 0.f; }

  const short* Abh = Ahi + (((size_t)mtile * 64) << 9);
  const short* Abl = Alo + (((size_t)mtile * 64) << 9);
  const short* Bbh = Bhi + (((size_t)npair * 128) << 9);
  const short* Bbl = Blo + (((size_t)npair * 128) << 9);

  const int tn = tid >> 3, k8 = tid & 7;
  const int ks = k8 >> 1, ko = (k8 & 1) * 8;
  const size_t so = ((size_t)tn << 9) + (size_t)k8 * 8;

  int4 rah0, rah1, ral0, ral1, rbh0, rbh1, rbh2, rbh3, rbl0, rbl1, rbl2, rbl3;
  {
    rah0 = *(const int4*)(Abh + so);              ral0 = *(const int4*)(Abl + so);
    rah1 = *(const int4*)(Abh + so + (32 << 9));  ral1 = *(const int4*)(Abl + so + (32 << 9));
    rbh0 = *(const int4*)(Bbh + so);              rbl0 = *(const int4*)(Bbl + so);
    rbh1 = *(const int4*)(Bbh + so + (32 << 9));  rbl1 = *(const int4*)(Bbl + so + (32 << 9));
    rbh2 = *(const int4*)(Bbh + so + (64 << 9));  rbl2 = *(const int4*)(Bbl + so + (64 << 9));
    rbh3 = *(const int4*)(Bbh + so + (96 << 9));  rbl3 = *(const int4*)(Bbl + so + (96 << 9));
  }

  const int NCH = FDIM / 64;   // 8 chunks
  for (int c = 0; c < NCH; ++c) {
    *(int4*)&AH[ks][tn][ko] = rah0;       *(int4*)&AL[ks][tn][ko] = ral0;
    *(int4*)&AH[ks][32 + tn][ko] = rah1;  *(int4*)&AL[ks][32 + tn][ko] = ral1;
    *(int4*)&BH[ks][tn][ko] = rbh0;       *(int4*)&BL[ks][tn][ko] = rbl0;
    *(int4*)&BH[ks][32 + tn][ko] = rbh1;  *(int4*)&BL[ks][32 + tn][ko] = rbl1;
    *(int4*)&BH[ks][64 + tn][ko] = rbh2;  *(int4*)&BL[ks][64 + tn][ko] = rbl2;
    *(int4*)&BH[ks][96 + tn][ko] = rbh3;  *(int4*)&BL[ks][96 + tn][ko] = rbl3;
    __syncthreads();
    if (c + 1 < NCH) {
      size_t o = so + (size_t)(c + 1) * 64;
      rah0 = *(const int4*)(Abh + o);              ral0 = *(const int4*)(Abl + o);
      rah1 = *(const int4*)(Abh + o + (32 << 9));  ral1 = *(const int4*)(Abl + o + (32 << 9));
      rbh0 = *(const int4*)(Bbh + o);              rbl0 = *(const int4*)(Bbl + o);
      rbh1 = *(const int4*)(Bbh + o + (32 << 9));  rbl1 = *(const int4*)(Bbl + o + (32 << 9));
      rbh2 = *(const int4*)(Bbh + o + (64 << 9));  rbl2 = *(const int4*)(Bbl + o + (64 << 9));
      rbh3 = *(const int4*)(Bbh + o + (96 << 9));  rbl3 = *(const int4*)(Bbl + o + (96 << 9));
    }
#pragma unroll
    for (int t = 0; t < 4; ++t) {
      bf16x8 ah = *(const bf16x8*)&AH[t][wm * 32 + ml][g8];
      bf16x8 al = *(const bf16x8*)&AL[t][wm * 32 + ml][g8];
      bf16x8 bh0 = *(const bf16x8*)&BH[t][wn * 64 + ml][g8];
      bf16x8 bl0 = *(const bf16x8*)&BL[t][wn * 64 + ml][g8];
      acc0 = __builtin_amdgcn_mfma_f32_32x32x16_bf16(ah, bh0, acc0, 0, 0, 0);
      acc0 = __builtin_amdgcn_mfma_f32_32x32x16_bf16(al, bh0, acc0, 0, 0, 0);
      acc0 = __builtin_amdgcn_mfma_f32_32x32x16_bf16(ah, bl0, acc0, 0, 0, 0);
      bf16x8 bh1 = *(const bf16x8*)&BH[t][wn * 64 + 32 + ml][g8];
      bf16x8 bl1 = *(const bf16x8*)&BL[t][wn * 64 + 32 + ml][g8];
      acc1 = __builtin_amdgcn_mfma_f32_32x32x16_bf16(ah, bh1, acc1, 0, 0, 0);
      acc1 = __builtin_amdgcn_mfma_f32_32x32x16_bf16(al, bh1, acc1, 0, 0, 0);
      acc1 = __builtin_amdgcn_mfma_f32_32x32x16_bf16(ah, bl1, acc1, 0, 0, 0);
    }
    __syncthreads();
  }

  // epilogue: C layout col=lane&31, row=(r&3)+8*(r>>2)+4*(lane>>5)
  const int h = npair * 2 + wn;
  const float a1lo = a1[h * 64 + ml], a1hi = a1[h * 64 + 32 + ml];
  const float a2lo = a2[h * 64 + ml], a2hi = a2[h * 64 + 32 + ml];
  const float b1h = b1[h], b2h = b2[h];
  const int row0 = mtile * 64 + wm * 32 + 4 * g;
  const int col0 = npair * 128 + wn * 64 + ml;
#pragma unroll
  for (int r = 0; r < 16; ++r) {
    int row = row0 + (r & 3) + 8 * (r >> 2);
    FTS[(size_t)row * FDIM + col0] = acc0[r];
    FTS[(size_t)row * FDIM + col0 + 32] = acc1[r];
    float p1 = acc0[r] * a1lo + acc1[r] * a1hi;
    float p2 = acc0[r] * a2lo + acc1[r] * a2hi;
#pragma unroll
    for (int o = 1; o < 32; o <<= 1) {
      p1 += __shfl_xor(p1, o);
      p2 += __shfl_xor(p2, o);
    }
    if (ml == 0) {
      F1t[(size_t)row * 8 + h] = p1 + b1h;
      F2t[(size_t)row * 8 + h] = p2 + b2h;
    }
  }
}

// ---------------- Kernel 3: sparse softmax + aggregation (4 heads/wave) -----
// Output VALS as bf16 hi/lo for the MFMA W2 stage.
__global__ __launch_bounds__(256) void k_agg1(
    const float* __restrict__ FTS, const float* __restrict__ F1t,
    const float* __restrict__ F2t, const int* __restrict__ nbr,
    const int* __restrict__ cnt, short* __restrict__ VALShi,
    short* __restrict__ VALSlo) {
  int wv = threadIdx.x >> 6, lane = threadIdx.x & 63;
  int gw = blockIdx.x * 4 + wv;     // over NN*2
  int i = gw >> 1, hg = gw & 1;
  int deg = cnt[i];
  const int* nb = nbr + (size_t)i * MAXD;
  float4 f1v = *(const float4*)(F1t + (size_t)i * 8 + hg * 4);

  float4 p4[4];
  int jreg[4];
  float mx = -1e30f, my = -1e30f, mz = -1e30f, mw = -1e30f;
#pragma unroll
  for (int r = 0; r < 4; ++r) {
    int t = r * 64 + lane;
    jreg[r] = 0;
    p4[r] = make_float4(-1e30f, -1e30f, -1e30f, -1e30f);
    if (t < deg) {
      int j = nb[t];
      jreg[r] = j;
      float4 f2v = *(const float4*)(F2t + (size_t)j * 8 + hg * 4);
      float4 x;
      x.x = f1v.x + f2v.x; x.x = x.x >= 0.f ? x.x : 0.2f * x.x;
      x.y = f1v.y + f2v.y; x.y = x.y >= 0.f ? x.y : 0.2f * x.y;
      x.z = f1v.z + f2v.z; x.z = x.z >= 0.f ? x.z : 0.2f * x.z;
      x.w = f1v.w + f2v.w; x.w = x.w >= 0.f ? x.w : 0.2f * x.w;
      p4[r] = x;
      mx = fmaxf(mx, x.x); my = fmaxf(my, x.y);
      mz = fmaxf(mz, x.z); mw = fmaxf(mw, x.w);
    }
  }
  mx = wave_max64(mx); my = wave_max64(my);
  mz = wave_max64(mz); mw = wave_max64(mw);
  float sx = 0.f, sy = 0.f, sz = 0.f, sw = 0.f;
#pragma unroll
  for (int r = 0; r < 4; ++r) {
    int t = r * 64 + lane;
    float4 e = make_float4(0.f, 0.f, 0.f, 0.f);
    if (t < deg) {
      e.x = __expf(p4[r].x - mx); e.y = __expf(p4[r].y - my);
      e.z = __expf(p4[r].z - mz); e.w = __expf(p4[r].w - mw);
    }
    p4[r] = e;
    sx += e.x; sy += e.y; sz += e.z; sw += e.w;
  }
  sx = wave_sum64(sx); sy = wave_sum64(sy);
  sz = wave_sum64(sz); sw = wave_sum64(sw);

  int q = lane >> 4;
  float invh = (q < 2) ? (q == 0 ? 1.f / sx : 1.f / sy)
                       : (q == 2 ? 1.f / sz : 1.f / sw);

  float4 accA = make_float4(0.f, 0.f, 0.f, 0.f);
  float4 accB = make_float4(0.f, 0.f, 0.f, 0.f);
  const float* Fb = FTS + hg * 256;
#pragma unroll
  for (int r = 0; r < 4; ++r) {
    int base = r * 64;
    if (base >= deg) break;
    int lim = deg - base;
    lim = lim < 64 ? lim : 64;
    int sl = 0;
    for (; sl + 2 <= lim; sl += 2) {
      int j0 = readlane_i(jreg[r], sl);
      int j1 = readlane_i(jreg[r], sl + 1);
      float w00 = readlane_f(p4[r].x, sl),     w01 = readlane_f(p4[r].y, sl);
      float w02 = readlane_f(p4[r].z, sl),     w03 = readlane_f(p4[r].w, sl);
      float w10 = readlane_f(p4[r].x, sl + 1), w11 = readlane_f(p4[r].y, sl + 1);
      float w12 = readlane_f(p4[r].z, sl + 1), w13 = readlane_f(p4[r].w, sl + 1);
      float wA = (q < 2) ? (q == 0 ? w00 : w01) : (q == 2 ? w02 : w03);
      float wB = (q < 2) ? (q == 0 ? w10 : w11) : (q == 2 ? w12 : w13);
      float4 f0 = *(const float4*)(Fb + (size_t)j0 * FDIM + lane * 4);
      float4 f1 = *(const float4*)(Fb + (size_t)j1 * FDIM + lane * 4);
      accA.x += wA * f0.x; accA.y += wA * f0.y; accA.z += wA * f0.z; accA.w += wA * f0.w;
      accB.x += wB * f1.x; accB.y += wB * f1.y; accB.z += wB * f1.z; accB.w += wB * f1.w;
    }
    if (sl < lim) {
      int j0 = readlane_i(jreg[r], sl);
      float w00 = readlane_f(p4[r].x, sl), w01 = readlane_f(p4[r].y, sl);
      float w02 = readlane_f(p4[r].z, sl), w03 = readlane_f(p4[r].w, sl);
      float wA = (q < 2) ? (q == 0 ? w00 : w01) : (q == 2 ? w02 : w03);
      float4 f0 = *(const float4*)(Fb + (size_t)j0 * FDIM + lane * 4);
      accA.x += wA * f0.x; accA.y += wA * f0.y; accA.z += wA * f0.z; accA.w += wA * f0.w;
    }
  }
  float vx = (accA.x + accB.x) * invh, vy = (accA.y + accB.y) * invh;
  float vz = (accA.z + accB.z) * invh, vw = (accA.w + accB.w) * invh;
  unsigned short hx = f2bf(vx), hy = f2bf(vy), hz = f2bf(vz), hw = f2bf(vw);
  size_t o = (size_t)i * FDIM + hg * 256 + lane * 4;
  *(short4*)(VALShi + o) = make_short4((short)hx, (short)hy, (short)hz, (short)hw);
  *(short4*)(VALSlo + o) = make_short4(
      (short)f2bf(vx - bf2f(hx)), (short)f2bf(vy - bf2f(hy)),
      (short)f2bf(vz - bf2f(hz)), (short)f2bf(vw - bf2f(hw)));
}

// ---------------- Kernel 4: H1 = elu(VALS @ blockdiag(W2) + bW), MFMA -------
// grid (NN/64, NHEAD); block 256; wave = one 32x32 frag; K=64.
__global__ __launch_bounds__(256) void k_w2(
    const short* __restrict__ VALShi, const short* __restrict__ VALSlo,
    const short* __restrict__ W2thi, const short* __restrict__ W2tlo,
    const float* __restrict__ bW, short* __restrict__ H1hi, short* __restrict__ H1lo) {
  __shared__ short AH[4][64][16], AL[4][64][16];
  __shared__ short BH[4][64][16], BL[4][64][16];
  const int rb = blockIdx.x, h = blockIdx.y;
  const int tid = threadIdx.x, lane = tid & 63, w = tid >> 6;
  const int wm = w >> 1, wn = w & 1;
  const int ml = lane & 31, g = lane >> 5, g8 = g * 8;
  const int tn = tid >> 2, k8 = tid & 3;
  {
    const short* pa = VALShi + ((size_t)(rb * 64 + tn) << 9) + h * 64 + k8 * 16;
    const short* pl = VALSlo + ((size_t)(rb * 64 + tn) << 9) + h * 64 + k8 * 16;
    *(int4*)&AH[k8][tn][0] = *(const int4*)pa;
    *(int4*)&AH[k8][tn][8] = *(const int4*)(pa + 8);
    *(int4*)&AL[k8][tn][0] = *(const int4*)pl;
    *(int4*)&AL[k8][tn][8] = *(const int4*)(pl + 8);
    const short* pb = W2thi + (size_t)h * 4096 + tn * 64 + k8 * 16;
    const short* pbl = W2tlo + (size_t)h * 4096 + tn * 64 + k8 * 16;
    *(int4*)&BH[k8][tn][0] = *(const int4*)pb;
    *(int4*)&BH[k8][tn][8] = *(const int4*)(pb + 8);
    *(int4*)&BL[k8][tn][0] = *(const int4*)pbl;
    *(int4*)&BL[k8][tn][8] = *(const int4*)(pbl + 8);
  }
  __syncthreads();
  f32x16 acc;
#pragma unroll
  for (int r = 0; r < 16; ++r) acc[r] = 0.f;
#pragma unroll
  for (int t = 0; t < 4; ++t) {
    bf16x8 ah = *(const bf16x8*)&AH[t][wm * 32 + ml][g8];
    bf16x8 al = *(const bf16x8*)&AL[t][wm * 32 + ml][g8];
    bf16x8 bh = *(const bf16x8*)&BH[t][wn * 32 + ml][g8];
    bf16x8 bl = *(const bf16x8*)&BL[t][wn * 32 + ml][g8];
    acc = __builtin_amdgcn_mfma_f32_32x32x16_bf16(ah, bh, acc, 0, 0, 0);
    acc = __builtin_amdgcn_mfma_f32_32x32x16_bf16(al, bh, acc, 0, 0, 0);
    acc = __builtin_amdgcn_mfma_f32_32x32x16_bf16(ah, bl, acc, 0, 0, 0);
  }
  const int col = wn * 32 + ml;
  const float bwv = bW[h * 64 + col];
  const int row0 = rb * 64 + wm * 32 + 4 * g;
#pragma unroll
  for (int r = 0; r < 16; ++r) {
    int row = row0 + (r & 3) + 8 * (r >> 2);
    float v = acc[r] + bwv;
    v = v > 0.f ? v : __expf(v) - 1.f;
    unsigned short hv = f2bf(v);
    size_t o = ((size_t)row << 9) + h * 64 + col;
    H1hi[o] = (short)hv;
    H1lo[o] = (short)f2bf(v - bf2f(hv));
  }
}

// ---------------- Kernel 5: fts2 = H1 @ Wo1 (MFMA) + f1o/f2o ----------------
// grid NN/64; N=64 (cols 40-63 are zero pad); K=512 in 8 chunks.
__global__ __launch_bounds__(256) void k_fts2(
    const short* __restrict__ H1hi, const short* __restrict__ H1lo,
    const short* __restrict__ Wo1thi, const short* __restrict__ Wo1tlo,
    const float* __restrict__ ao1, const float* __restrict__ bo1s,
    const float* __restrict__ ao2, const float* __restrict__ bo2s,
    float* __restrict__ FTS2, float* __restrict__ F1O, float* __restrict__ F2O) {
  __shared__ short AH[4][64][16], AL[4][64][16];
  __shared__ short BH[4][64][16], BL[4][64][16];
  __shared__ float p1buf[2][64], p2buf[2][64];
  const int i0 = blockIdx.x * 64;
  const int tid = threadIdx.x, lane = tid & 63, w = tid >> 6;
  const int wm = w >> 1, wn = w & 1;
  const int ml = lane & 31, g = lane >> 5, g8 = g * 8;
  const int tn = tid >> 2, k8 = tid & 3;

  f32x16 acc;
#pragma unroll
  for (int r = 0; r < 16; ++r) acc[r] = 0.f;

  for (int c = 0; c < 8; ++c) {
    const size_t ka = ((size_t)(i0 + tn) << 9) + c * 64 + k8 * 16;
    *(int4*)&AH[k8][tn][0] = *(const int4*)(H1hi + ka);
    *(int4*)&AH[k8][tn][8] = *(const int4*)(H1hi + ka + 8);
    *(int4*)&AL[k8][tn][0] = *(const int4*)(H1lo + ka);
    *(int4*)&AL[k8][tn][8] = *(const int4*)(H1lo + ka + 8);
    const size_t kb = ((size_t)tn << 9) + c * 64 + k8 * 16;
    *(int4*)&BH[k8][tn][0] = *(const int4*)(Wo1thi + kb);
    *(int4*)&BH[k8][tn][8] = *(const int4*)(Wo1thi + kb + 8);
    *(int4*)&BL[k8][tn][0] = *(const int4*)(Wo1tlo + kb);
    *(int4*)&BL[k8][tn][8] = *(const int4*)(Wo1tlo + kb + 8);
    __syncthreads();
#pragma unroll
    for (int t = 0; t < 4; ++t) {
      bf16x8 ah = *(const bf16x8*)&AH[t][wm * 32 + ml][g8];
      bf16x8 al = *(const bf16x8*)&AL[t][wm * 32 + ml][g8];
      bf16x8 bh = *(const bf16x8*)&BH[t][wn * 32 + ml][g8];
      bf16x8 bl = *(const bf16x8*)&BL[t][wn * 32 + ml][g8];
      acc = __builtin_amdgcn_mfma_f32_32x32x16_bf16(ah, bh, acc, 0, 0, 0);
      acc = __builtin_amdgcn_mfma_f32_32x32x16_bf16(al, bh, acc, 0, 0, 0);
      acc = __builtin_amdgcn_mfma_f32_32x32x16_bf16(ah, bl, acc, 0, 0, 0);
    }
    __syncthreads();
  }

  const int col = wn * 32 + ml;
  const bool act = col < CDIM;
  const float aov1 = act ? ao1[col] : 0.f;
  const float aov2 = act ? ao2[col] : 0.f;
  const int lrow0 = wm * 32 + 4 * g;
#pragma unroll
  for (int r = 0; r < 16; ++r) {
    int lrow = lrow0 + (r & 3) + 8 * (r >> 2);
    float v = acc[r];
    if (act) FTS2[(size_t)(i0 + lrow) * CDIM + col] = v;
    float p1 = v * aov1, p2 = v * aov2;
#pragma unroll
    for (int o = 1; o < 32; o <<= 1) {
      p1 += __shfl_xor(p1, o);
      p2 += __shfl_xor(p2, o);
    }
    if (ml == 0) {
      p1buf[wn][lrow] = p1;
      p2buf[wn][lrow] = p2;
    }
  }
  __syncthreads();
  if (tid < 64) {
    F1O[i0 + tid] = p1buf[0][tid] + p1buf[1][tid] + bo1s[0];
    F2O[i0 + tid] = p2buf[0][tid] + p2buf[1][tid] + bo2s[0];
  }
}

// ---------------- Kernel 6: layer-2 attention + output GEMM (fused) ---------
__global__ __launch_bounds__(256) void k_agg2(
    const float* __restrict__ FTS2, const float* __restrict__ F1O,
    const float* __restrict__ F2O, const int* __restrict__ nbr,
    const int* __restrict__ cnt, const float* __restrict__ Wo2,
    const float* __restrict__ bo, float* __restrict__ out) {
  int i = blockIdx.x * 4 + (threadIdx.x >> 6);
  int lane = threadIdx.x & 63;
  int deg = cnt[i];
  const int* nb = nbr + (size_t)i * MAXD;
  float f1i = F1O[i];

  int jreg[4];
  float p[4];
  float m = -1e30f;
#pragma unroll
  for (int r = 0; r < 4; ++r) { jreg[r] = 0; p[r] = -1e30f; }
#pragma unroll
  for (int r = 0; r < 4; ++r) {
    int t = r * 64 + lane;
    if (t < deg) {
      int j = nb[t];
      jreg[r] = j;
      float x = f1i + F2O[j];
      x = x >= 0.f ? x : 0.2f * x;
      p[r] = x;
      m = fmaxf(m, x);
    }
  }
  m = wave_max64(m);
  float s = 0.f;
#pragma unroll
  for (int r = 0; r < 4; ++r) {
    int t = r * 64 + lane;
    float e = (t < deg) ? __expf(p[r] - m) : 0.f;
    p[r] = e;
    s += e;
  }
  s = wave_sum64(s);

  const bool act = lane < CDIM;
  float acc = 0.f;
#pragma unroll
  for (int r = 0; r < 4; ++r) {
    int base = r * 64;
    if (base >= deg) break;
    int lim = deg - base;
    lim = lim < 64 ? lim : 64;
    for (int sl = 0; sl < lim; ++sl) {
      float w = readlane_f(p[r], sl);
      int j   = readlane_i(jreg[r], sl);
      float fv = act ? FTS2[(size_t)j * CDIM + lane] : 0.f;
      acc += w * fv;
    }
  }
  float v = acc / s;

  float o = act ? bo[lane] : 0.f;
  for (int kk = 0; kk < CDIM; ++kk) {
    float w = readlane_f(v, kk);
    float b = act ? Wo2[kk * CDIM + lane] : 0.f;
    o += w * b;
  }
  if (act) out[(size_t)i * CDIM + lane] = o;
}

extern "C" void kernel_launch(void* const* d_in, const int* in_sizes, int n_in,
                              void* d_out, int out_size, void* d_ws, size_t ws_size,
                              hipStream_t stream) {
  const float* seq  = (const float*)d_in[0];
  const float* bias = (const float*)d_in[1];
  const float* W1   = (const float*)d_in[2];
  const float* a1   = (const float*)d_in[3];
  const float* b1   = (const float*)d_in[4];
  const float* a2   = (const float*)d_in[5];
  const float* b2   = (const float*)d_in[6];
  const float* W2   = (const float*)d_in[7];
  const float* bW   = (const float*)d_in[8];
  const float* Wo1  = (const float*)d_in[9];
  const float* ao1  = (const float*)d_in[10];
  const float* bo1  = (const float*)d_in[11];
  const float* ao2  = (const float*)d_in[12];
  const float* bo2  = (const float*)d_in[13];
  const float* Wo2  = (const float*)d_in[14];
  const float* bo   = (const float*)d_in[15];
  float* out = (float*)d_out;

  float* ws    = (float*)d_ws;
  float* FTS   = ws;                          // N*512 f32
  float* F1t   = FTS  + (size_t)NN * FDIM;    // N*8
  float* F2t   = F1t  + (size_t)NN * NHEAD;   // N*8
  float* FTS2  = F2t  + (size_t)NN * NHEAD;   // N*40
  float* F1O   = FTS2 + (size_t)NN * CDIM;    // N
  float* F2O   = F1O  + NN;                   // N
  short* Ahi   = (short*)(F2O + NN);          // N*512 bf16
  short* Alo   = Ahi + (size_t)NN * FDIM;
  short* Bhi   = Alo + (size_t)NN * FDIM;     // 8*64*512
  short* Blo   = Bhi + (size_t)NHEAD * HDIM * FDIM;
  short* VALShi= Blo + (size_t)NHEAD * HDIM * FDIM;  // N*512
  short* VALSlo= VALShi + (size_t)NN * FDIM;
  short* H1hi  = VALSlo + (size_t)NN * FDIM;         // N*512
  short* H1lo  = H1hi + (size_t)NN * FDIM;
  short* W2thi = H1lo + (size_t)NN * FDIM;           // 8*64*64
  short* W2tlo = W2thi + (size_t)NHEAD * HDIM * HDIM;
  short* Wo1thi= W2tlo + (size_t)NHEAD * HDIM * HDIM; // 64*512
  short* Wo1tlo= Wo1thi + (size_t)64 * FDIM;
  int*   nbr   = (int*)(Wo1tlo + (size_t)64 * FDIM);  // N*MAXD
  int*   cnt   = nbr + (size_t)NN * MAXD;     // N

  // 1. CSR + all weight/input conversions
  k_prep<<<NN + 1024 + 64 + 8 + 8, 256, 0, stream>>>(
      bias, nbr, cnt, seq, Ahi, Alo, W1, Bhi, Blo, W2, W2thi, W2tlo,
      Wo1, Wo1thi, Wo1tlo);
  // 2. MFMA hi/lo GEMM (full K) + fused f1/f2
  k_gemm<<<dim3(NN / 64, NHEAD / 2), 256, 0, stream>>>(
      Ahi, Alo, Bhi, Blo, a1, b1, a2, b2, FTS, F1t, F2t);
  // 3. sparse softmax + aggregation -> VALS bf16 hi/lo
  k_agg1<<<NN * 2 / 4, 256, 0, stream>>>(FTS, F1t, F2t, nbr, cnt, VALShi, VALSlo);
  // 4. per-head W2 MFMA + elu -> H1 bf16 hi/lo
  k_w2<<<dim3(NN / 64, NHEAD), 256, 0, stream>>>(VALShi, VALSlo, W2thi, W2tlo,
                                                 bW, H1hi, H1lo);
  // 5. layer-2 features MFMA + f1o/f2o
  k_fts2<<<NN / 64, 256, 0, stream>>>(H1hi, H1lo, Wo1thi, Wo1tlo,
                                      ao1, bo1, ao2, bo2, FTS2, F1O, F2O);
  // 6. layer-2 sparse attention + final dense + bias
  k_agg2<<<NN / 4, 256, 0, stream>>>(FTS2, F1O, F2O, nbr, cnt, Wo2, bo, out);
}

// Round 9
// 101.812 us; speedup vs baseline: 2.6502x; 1.0012x over previous
//
#include <hip/hip_runtime.h>
#include <cstdint>
#include <cstddef>

#define NN 4096
#define FDIM 512
#define HDIM 64
#define NHEAD 8
#define CDIM 40
#define MAXD 256   // max neighbors kept per row (~41 expected)

typedef __attribute__((ext_vector_type(8))) short bf16x8;
typedef __attribute__((ext_vector_type(16))) float f32x16;

__device__ __forceinline__ float wave_max64(float v) {
  for (int o = 32; o; o >>= 1) v = fmaxf(v, __shfl_xor(v, o));
  return v;
}
__device__ __forceinline__ float wave_sum64(float v) {
  for (int o = 32; o; o >>= 1) v += __shfl_xor(v, o);
  return v;
}
__device__ __forceinline__ float readlane_f(float v, int sl) {
  return __uint_as_float((unsigned)__builtin_amdgcn_readlane((int)__float_as_uint(v), sl));
}
__device__ __forceinline__ int readlane_i(int v, int sl) {
  return __builtin_amdgcn_readlane(v, sl);
}
// fp32 -> bf16 (RNE) and back, via bit ops
__device__ __forceinline__ unsigned short f2bf(float x) {
  unsigned u = __float_as_uint(x);
  return (unsigned short)((u + 0x7fffu + ((u >> 16) & 1u)) >> 16);
}
__device__ __forceinline__ float bf2f(unsigned short b) {
  return __uint_as_float(((unsigned)b) << 16);
}

// ---------------- Kernel 1: prep -------------------------------------------
// Grid = 4096 csr + 1024 seq-cvt + 64 W1 + 8 W2t + 8 Wo1t = 5200 blocks.
__global__ __launch_bounds__(256) void k_prep(
    const float* __restrict__ bias, int* __restrict__ nbr, int* __restrict__ cnt,
    const float* __restrict__ seq, short* __restrict__ Ahi, short* __restrict__ Alo,
    const float* __restrict__ W1, short* __restrict__ Bhi, short* __restrict__ Blo,
    const float* __restrict__ W2, short* __restrict__ W2thi, short* __restrict__ W2tlo,
    const float* __restrict__ Wo1, short* __restrict__ Wo1thi, short* __restrict__ Wo1tlo) {
  __shared__ int wtot[4];
  __shared__ float T[64][65];
  int bx = blockIdx.x, tid = threadIdx.x;
  if (bx < NN) {       // ---- CSR: one block per row, thread owns 16 cols
    int row = bx;
    int lane = tid & 63, wv = tid >> 6;
    const float4* r = (const float4*)(bias + (size_t)row * NN);
    unsigned mask = 0;
#pragma unroll
    for (int i = 0; i < 4; ++i) {
      float4 v = r[tid * 4 + i];
      mask |= (unsigned)((v.x == 0.f ? 1 : 0) | (v.y == 0.f ? 2 : 0) |
                         (v.z == 0.f ? 4 : 0) | (v.w == 0.f ? 8 : 0)) << (i * 4);
    }
    int c = __popc(mask);
    int pre = c;
#pragma unroll
    for (int o = 1; o < 64; o <<= 1) {
      int u = __shfl_up(pre, o);
      if (lane >= o) pre += u;
    }
    if (lane == 63) wtot[wv] = pre;
    __syncthreads();
    int woff = 0;
#pragma unroll
    for (int w = 0; w < 4; ++w)
      if (w < wv) woff += wtot[w];
    int excl = woff + pre - c;
    int* out = nbr + (size_t)row * MAXD;
    int col0 = tid * 16, k = 0;
#pragma unroll
    for (int i = 0; i < 16; ++i) {
      if ((mask >> i) & 1) {
        int p = excl + k;
        if (p < MAXD) out[p] = col0 + i;
        ++k;
      }
    }
    if (tid == 0) {
      int total = wtot[0] + wtot[1] + wtot[2] + wtot[3];
      cnt[row] = total < MAXD ? total : MAXD;
    }
    return;
  }
  bx -= NN;
  if (bx < 1024) {     // ---- seq -> bf16 hi/lo (8 elems/thread)
    size_t off = (size_t)bx * 2048 + (size_t)tid * 8;
    float4 v0 = *(const float4*)(seq + off);
    float4 v1 = *(const float4*)(seq + off + 4);
    unsigned short h0 = f2bf(v0.x), h1 = f2bf(v0.y), h2 = f2bf(v0.z), h3 = f2bf(v0.w);
    unsigned short h4 = f2bf(v1.x), h5 = f2bf(v1.y), h6 = f2bf(v1.z), h7 = f2bf(v1.w);
    *(uint4*)(Ahi + off) = make_uint4(
        (unsigned)h0 | ((unsigned)h1 << 16), (unsigned)h2 | ((unsigned)h3 << 16),
        (unsigned)h4 | ((unsigned)h5 << 16), (unsigned)h6 | ((unsigned)h7 << 16));
    unsigned short l0 = f2bf(v0.x - bf2f(h0)), l1 = f2bf(v0.y - bf2f(h1));
    unsigned short l2 = f2bf(v0.z - bf2f(h2)), l3 = f2bf(v0.w - bf2f(h3));
    unsigned short l4 = f2bf(v1.x - bf2f(h4)), l5 = f2bf(v1.y - bf2f(h5));
    unsigned short l6 = f2bf(v1.z - bf2f(h6)), l7 = f2bf(v1.w - bf2f(h7));
    *(uint4*)(Alo + off) = make_uint4(
        (unsigned)l0 | ((unsigned)l1 << 16), (unsigned)l2 | ((unsigned)l3 << 16),
        (unsigned)l4 | ((unsigned)l5 << 16), (unsigned)l6 | ((unsigned)l7 << 16));
    return;
  }
  bx -= 1024;
  if (bx < 64) {       // ---- W1 tile transpose + bf16 hi/lo: [k][n] -> [n][k]
    int h = bx >> 3, kb = bx & 7;
    const float* src = W1 + ((size_t)h * FDIM + kb * 64) * HDIM;
#pragma unroll
    for (int q = 0; q < 4; ++q) {
      int fi = q * 256 + tid, kk = fi >> 4, n4 = fi & 15;
      float4 v = *(const float4*)(src + (size_t)kk * HDIM + n4 * 4);
      T[n4 * 4 + 0][kk] = v.x; T[n4 * 4 + 1][kk] = v.y;
      T[n4 * 4 + 2][kk] = v.z; T[n4 * 4 + 3][kk] = v.w;
    }
    __syncthreads();
#pragma unroll
    for (int q = 0; q < 4; ++q) {
      int fi = q * 256 + tid, n = fi >> 4, k4 = fi & 15;
      float a = T[n][k4 * 4], b = T[n][k4 * 4 + 1];
      float c = T[n][k4 * 4 + 2], d = T[n][k4 * 4 + 3];
      size_t o = ((size_t)h * 64 + n) * FDIM + kb * 64 + k4 * 4;
      unsigned short ha = f2bf(a), hb = f2bf(b), hc = f2bf(c), hd = f2bf(d);
      *(short4*)(Bhi + o) = make_short4((short)ha, (short)hb, (short)hc, (short)hd);
      *(short4*)(Blo + o) = make_short4((short)f2bf(a - bf2f(ha)), (short)f2bf(b - bf2f(hb)),
                                        (short)f2bf(c - bf2f(hc)), (short)f2bf(d - bf2f(hd)));
    }
    return;
  }
  bx -= 64;
  if (bx < 8) {        // ---- W2[h] transpose [64k][64n] -> [n][k] hi/lo
    int h = bx;
    const float* src = W2 + (size_t)h * HDIM * HDIM;
#pragma unroll
    for (int q = 0; q < 4; ++q) {
      int fi = q * 256 + tid, kk = fi >> 4, n4 = fi & 15;
      float4 v = *(const float4*)(src + (size_t)kk * HDIM + n4 * 4);
      T[n4 * 4 + 0][kk] = v.x; T[n4 * 4 + 1][kk] = v.y;
      T[n4 * 4 + 2][kk] = v.z; T[n4 * 4 + 3][kk] = v.w;
    }
    __syncthreads();
#pragma unroll
    for (int q = 0; q < 4; ++q) {
      int fi = q * 256 + tid, n = fi >> 4, k4 = fi & 15;
      float a = T[n][k4 * 4], b = T[n][k4 * 4 + 1];
      float c = T[n][k4 * 4 + 2], d = T[n][k4 * 4 + 3];
      size_t o = (size_t)h * 4096 + (size_t)n * 64 + k4 * 4;
      unsigned short ha = f2bf(a), hb = f2bf(b), hc = f2bf(c), hd = f2bf(d);
      *(short4*)(W2thi + o) = make_short4((short)ha, (short)hb, (short)hc, (short)hd);
      *(short4*)(W2tlo + o) = make_short4((short)f2bf(a - bf2f(ha)), (short)f2bf(b - bf2f(hb)),
                                          (short)f2bf(c - bf2f(hc)), (short)f2bf(d - bf2f(hd)));
    }
    return;
  }
  bx -= 8;
  {                    // ---- Wo1 transpose+pad [512][40] -> [64][512] hi/lo
#pragma unroll
    for (int q = 0; q < 16; ++q) {
      int idx = q * 256 + tid;          // 0..4095
      int n = bx * 8 + (idx >> 9), k = idx & 511;
      float v = (n < CDIM) ? Wo1[(size_t)k * CDIM + n] : 0.f;
      unsigned short hv = f2bf(v);
      Wo1thi[(size_t)n * FDIM + k] = (short)hv;
      Wo1tlo[(size_t)n * FDIM + k] = (short)f2bf(v - bf2f(hv));
    }
  }
}

// ---------------- Kernel 2: MFMA GEMM (full K) + fused f1/f2 ---------------
__global__ __launch_bounds__(256) void k_gemm(
    const short* __restrict__ Ahi, const short* __restrict__ Alo,
    const short* __restrict__ Bhi, const short* __restrict__ Blo,
    const float* __restrict__ a1, const float* __restrict__ b1,
    const float* __restrict__ a2, const float* __restrict__ b2,
    float* __restrict__ FTS, float* __restrict__ F1t, float* __restrict__ F2t) {
  __shared__ short AH[4][64][16], AL[4][64][16];    // [kstep16][m][k-slot]
  __shared__ short BH[4][128][16], BL[4][128][16];  // [kstep16][n][k-slot]
  const int mtile = blockIdx.x, npair = blockIdx.y;
  const int tid = threadIdx.x, lane = tid & 63, w = tid >> 6;
  const int wm = w >> 1, wn = w & 1;
  const int ml = lane & 31, g = lane >> 5, g8 = g * 8;

  f32x16 acc0, acc1;
#pragma unroll
  for (int r = 0; r < 16; ++r) { acc0[r] = 0.f; acc1[r] = 0.f; }

  const short* Abh = Ahi + (((size_t)mtile * 64) << 9);
  const short* Abl = Alo + (((size_t)mtile * 64) << 9);
  const short* Bbh = Bhi + (((size_t)npair * 128) << 9);
  const short* Bbl = Blo + (((size_t)npair * 128) << 9);

  const int tn = tid >> 3, k8 = tid & 7;
  const int ks = k8 >> 1, ko = (k8 & 1) * 8;
  const size_t so = ((size_t)tn << 9) + (size_t)k8 * 8;

  int4 rah0, rah1, ral0, ral1, rbh0, rbh1, rbh2, rbh3, rbl0, rbl1, rbl2, rbl3;
  {
    rah0 = *(const int4*)(Abh + so);              ral0 = *(const int4*)(Abl + so);
    rah1 = *(const int4*)(Abh + so + (32 << 9));  ral1 = *(const int4*)(Abl + so + (32 << 9));
    rbh0 = *(const int4*)(Bbh + so);              rbl0 = *(const int4*)(Bbl + so);
    rbh1 = *(const int4*)(Bbh + so + (32 << 9));  rbl1 = *(const int4*)(Bbl + so + (32 << 9));
    rbh2 = *(const int4*)(Bbh + so + (64 << 9));  rbl2 = *(const int4*)(Bbl + so + (64 << 9));
    rbh3 = *(const int4*)(Bbh + so + (96 << 9));  rbl3 = *(const int4*)(Bbl + so + (96 << 9));
  }

  const int NCH = FDIM / 64;   // 8 chunks
  for (int c = 0; c < NCH; ++c) {
    *(int4*)&AH[ks][tn][ko] = rah0;       *(int4*)&AL[ks][tn][ko] = ral0;
    *(int4*)&AH[ks][32 + tn][ko] = rah1;  *(int4*)&AL[ks][32 + tn][ko] = ral1;
    *(int4*)&BH[ks][tn][ko] = rbh0;       *(int4*)&BL[ks][tn][ko] = rbl0;
    *(int4*)&BH[ks][32 + tn][ko] = rbh1;  *(int4*)&BL[ks][32 + tn][ko] = rbl1;
    *(int4*)&BH[ks][64 + tn][ko] = rbh2;  *(int4*)&BL[ks][64 + tn][ko] = rbl2;
    *(int4*)&BH[ks][96 + tn][ko] = rbh3;  *(int4*)&BL[ks][96 + tn][ko] = rbl3;
    __syncthreads();
    if (c + 1 < NCH) {
      size_t o = so + (size_t)(c + 1) * 64;
      rah0 = *(const int4*)(Abh + o);              ral0 = *(const int4*)(Abl + o);
      rah1 = *(const int4*)(Abh + o + (32 << 9));  ral1 = *(const int4*)(Abl + o + (32 << 9));
      rbh0 = *(const int4*)(Bbh + o);              rbl0 = *(const int4*)(Bbl + o);
      rbh1 = *(const int4*)(Bbh + o + (32 << 9));  rbl1 = *(const int4*)(Bbl + o + (32 << 9));
      rbh2 = *(const int4*)(Bbh + o + (64 << 9));  rbl2 = *(const int4*)(Bbl + o + (64 << 9));
      rbh3 = *(const int4*)(Bbh + o + (96 << 9));  rbl3 = *(const int4*)(Bbl + o + (96 << 9));
    }
#pragma unroll
    for (int t = 0; t < 4; ++t) {
      bf16x8 ah = *(const bf16x8*)&AH[t][wm * 32 + ml][g8];
      bf16x8 al = *(const bf16x8*)&AL[t][wm * 32 + ml][g8];
      bf16x8 bh0 = *(const bf16x8*)&BH[t][wn * 64 + ml][g8];
      bf16x8 bl0 = *(const bf16x8*)&BL[t][wn * 64 + ml][g8];
      acc0 = __builtin_amdgcn_mfma_f32_32x32x16_bf16(ah, bh0, acc0, 0, 0, 0);
      acc0 = __builtin_amdgcn_mfma_f32_32x32x16_bf16(al, bh0, acc0, 0, 0, 0);
      acc0 = __builtin_amdgcn_mfma_f32_32x32x16_bf16(ah, bl0, acc0, 0, 0, 0);
      bf16x8 bh1 = *(const bf16x8*)&BH[t][wn * 64 + 32 + ml][g8];
      bf16x8 bl1 = *(const bf16x8*)&BL[t][wn * 64 + 32 + ml][g8];
      acc1 = __builtin_amdgcn_mfma_f32_32x32x16_bf16(ah, bh1, acc1, 0, 0, 0);
      acc1 = __builtin_amdgcn_mfma_f32_32x32x16_bf16(al, bh1, acc1, 0, 0, 0);
      acc1 = __builtin_amdgcn_mfma_f32_32x32x16_bf16(ah, bl1, acc1, 0, 0, 0);
    }
    __syncthreads();
  }

  // epilogue: C layout col=lane&31, row=(r&3)+8*(r>>2)+4*(lane>>5)
  const int h = npair * 2 + wn;
  const float a1lo = a1[h * 64 + ml], a1hi = a1[h * 64 + 32 + ml];
  const float a2lo = a2[h * 64 + ml], a2hi = a2[h * 64 + 32 + ml];
  const float b1h = b1[h], b2h = b2[h];
  const int row0 = mtile * 64 + wm * 32 + 4 * g;
  const int col0 = npair * 128 + wn * 64 + ml;
#pragma unroll
  for (int r = 0; r < 16; ++r) {
    int row = row0 + (r & 3) + 8 * (r >> 2);
    FTS[(size_t)row * FDIM + col0] = acc0[r];
    FTS[(size_t)row * FDIM + col0 + 32] = acc1[r];
    float p1 = acc0[r] * a1lo + acc1[r] * a1hi;
    float p2 = acc0[r] * a2lo + acc1[r] * a2hi;
#pragma unroll
    for (int o = 1; o < 32; o <<= 1) {
      p1 += __shfl_xor(p1, o);
      p2 += __shfl_xor(p2, o);
    }
    if (ml == 0) {
      F1t[(size_t)row * 8 + h] = p1 + b1h;
      F2t[(size_t)row * 8 + h] = p2 + b2h;
    }
  }
}

// ---------------- Kernel 3: sparse softmax + aggregation (4 heads/wave) -----
// Weights broadcast via wave-private LDS (1 ds_read vs 4 readlane + selects).
__global__ __launch_bounds__(256) void k_agg1(
    const float* __restrict__ FTS, const float* __restrict__ F1t,
    const float* __restrict__ F2t, const int* __restrict__ nbr,
    const int* __restrict__ cnt, short* __restrict__ VALShi,
    short* __restrict__ VALSlo) {
  __shared__ float plds[4][MAXD][4];   // [wave][slot][head-q] = 16 KB
  int wv = threadIdx.x >> 6, lane = threadIdx.x & 63;
  int gw = blockIdx.x * 4 + wv;     // over NN*2
  int i = gw >> 1, hg = gw & 1;
  int deg = cnt[i];
  const int* nb = nbr + (size_t)i * MAXD;
  float4 f1v = *(const float4*)(F1t + (size_t)i * 8 + hg * 4);

  float4 p4[4];
  int jreg[4];
  float mx = -1e30f, my = -1e30f, mz = -1e30f, mw = -1e30f;
#pragma unroll
  for (int r = 0; r < 4; ++r) {
    int t = r * 64 + lane;
    jreg[r] = 0;
    p4[r] = make_float4(-1e30f, -1e30f, -1e30f, -1e30f);
    if (t < deg) {
      int j = nb[t];
      jreg[r] = j;
      float4 f2v = *(const float4*)(F2t + (size_t)j * 8 + hg * 4);
      float4 x;
      x.x = f1v.x + f2v.x; x.x = x.x >= 0.f ? x.x : 0.2f * x.x;
      x.y = f1v.y + f2v.y; x.y = x.y >= 0.f ? x.y : 0.2f * x.y;
      x.z = f1v.z + f2v.z; x.z = x.z >= 0.f ? x.z : 0.2f * x.z;
      x.w = f1v.w + f2v.w; x.w = x.w >= 0.f ? x.w : 0.2f * x.w;
      p4[r] = x;
      mx = fmaxf(mx, x.x); my = fmaxf(my, x.y);
      mz = fmaxf(mz, x.z); mw = fmaxf(mw, x.w);
    }
  }
  mx = wave_max64(mx); my = wave_max64(my);
  mz = wave_max64(mz); mw = wave_max64(mw);
  float sx = 0.f, sy = 0.f, sz = 0.f, sw = 0.f;
#pragma unroll
  for (int r = 0; r < 4; ++r) {
    int t = r * 64 + lane;
    float4 e = make_float4(0.f, 0.f, 0.f, 0.f);
    if (t < deg) {
      e.x = __expf(p4[r].x - mx); e.y = __expf(p4[r].y - my);
      e.z = __expf(p4[r].z - mz); e.w = __expf(p4[r].w - mw);
    }
    p4[r] = e;
    sx += e.x; sy += e.y; sz += e.z; sw += e.w;
    // publish weights for broadcast reads (wave-private; no barrier needed)
    *(float4*)&plds[wv][r * 64 + lane][0] = e;
  }
  sx = wave_sum64(sx); sy = wave_sum64(sy);
  sz = wave_sum64(sz); sw = wave_sum64(sw);

  int q = lane >> 4;
  float invh = (q < 2) ? (q == 0 ? 1.f / sx : 1.f / sy)
                       : (q == 2 ? 1.f / sz : 1.f / sw);

  float4 accA = make_float4(0.f, 0.f, 0.f, 0.f);
  float4 accB = make_float4(0.f, 0.f, 0.f, 0.f);
  const float* Fb = FTS + hg * 256;
#pragma unroll
  for (int r = 0; r < 4; ++r) {
    int base = r * 64;
    if (base >= deg) break;
    int lim = deg - base;
    lim = lim < 64 ? lim : 64;
    int sl = 0;
    for (; sl + 2 <= lim; sl += 2) {
      int j0 = readlane_i(jreg[r], sl);
      int j1 = readlane_i(jreg[r], sl + 1);
      float wA = plds[wv][base + sl][q];
      float wB = plds[wv][base + sl + 1][q];
      float4 f0 = *(const float4*)(Fb + (size_t)j0 * FDIM + lane * 4);
      float4 f1 = *(const float4*)(Fb + (size_t)j1 * FDIM + lane * 4);
      accA.x += wA * f0.x; accA.y += wA * f0.y; accA.z += wA * f0.z; accA.w += wA * f0.w;
      accB.x += wB * f1.x; accB.y += wB * f1.y; accB.z += wB * f1.z; accB.w += wB * f1.w;
    }
    if (sl < lim) {
      int j0 = readlane_i(jreg[r], sl);
      float wA = plds[wv][base + sl][q];
      float4 f0 = *(const float4*)(Fb + (size_t)j0 * FDIM + lane * 4);
      accA.x += wA * f0.x; accA.y += wA * f0.y; accA.z += wA * f0.z; accA.w += wA * f0.w;
    }
  }
  float vx = (accA.x + accB.x) * invh, vy = (accA.y + accB.y) * invh;
  float vz = (accA.z + accB.z) * invh, vw = (accA.w + accB.w) * invh;
  unsigned short hx = f2bf(vx), hy = f2bf(vy), hz = f2bf(vz), hw = f2bf(vw);
  size_t o = (size_t)i * FDIM + hg * 256 + lane * 4;
  *(short4*)(VALShi + o) = make_short4((short)hx, (short)hy, (short)hz, (short)hw);
  *(short4*)(VALSlo + o) = make_short4(
      (short)f2bf(vx - bf2f(hx)), (short)f2bf(vy - bf2f(hy)),
      (short)f2bf(vz - bf2f(hz)), (short)f2bf(vw - bf2f(hw)));
}

// ---------------- Kernel 4: fused tail: H1 = elu(VALS@W2+bW); FTS2 = H1@Wo1 -
// grid NN/64 = 64 blocks; per head h: W2-MFMA -> elu -> bf16 hi/lo scatter to
// LDS -> fts2-MFMA accumulate (FTS2 = sum_h H1_h @ Wo1[h-block]).
__global__ __launch_bounds__(256) void k_tail(
    const short* __restrict__ VALShi, const short* __restrict__ VALSlo,
    const short* __restrict__ W2thi, const short* __restrict__ W2tlo,
    const float* __restrict__ bW,
    const short* __restrict__ Wo1thi, const short* __restrict__ Wo1tlo,
    const float* __restrict__ ao1, const float* __restrict__ bo1s,
    const float* __restrict__ ao2, const float* __restrict__ bo2s,
    float* __restrict__ FTS2, float* __restrict__ F1O, float* __restrict__ F2O) {
  __shared__ short AH[4][64][16], AL[4][64][16];   // VALS tile (A of W2 mfma)
  __shared__ short BH[4][64][16], BL[4][64][16];   // W2t[h]    (B of W2 mfma)
  __shared__ short CH[4][64][16], CL[4][64][16];   // H1_h      (A of fts2 mfma)
  __shared__ short DH[4][64][16], DL[4][64][16];   // Wo1t[h]   (B of fts2 mfma)
  __shared__ float p1buf[2][64], p2buf[2][64];
  const int i0 = blockIdx.x * 64;
  const int tid = threadIdx.x, lane = tid & 63, w = tid >> 6;
  const int wm = w >> 1, wn = w & 1;
  const int ml = lane & 31, g = lane >> 5, g8 = g * 8;
  const int tn = tid >> 2, k8 = tid & 3;
  const int colw = wn * 32 + ml;
  const int rowl0 = wm * 32 + 4 * g;

  f32x16 acc2;
#pragma unroll
  for (int r = 0; r < 16; ++r) acc2[r] = 0.f;

  for (int h = 0; h < NHEAD; ++h) {
    // stage A (VALS), B (W2t[h]), D (Wo1t k-block h)
    {
      const short* pa = VALShi + ((size_t)(i0 + tn) << 9) + h * 64 + k8 * 16;
      const short* pl = VALSlo + ((size_t)(i0 + tn) << 9) + h * 64 + k8 * 16;
      *(int4*)&AH[k8][tn][0] = *(const int4*)pa;
      *(int4*)&AH[k8][tn][8] = *(const int4*)(pa + 8);
      *(int4*)&AL[k8][tn][0] = *(const int4*)pl;
      *(int4*)&AL[k8][tn][8] = *(const int4*)(pl + 8);
      const short* pb  = W2thi + (size_t)h * 4096 + tn * 64 + k8 * 16;
      const short* pbl = W2tlo + (size_t)h * 4096 + tn * 64 + k8 * 16;
      *(int4*)&BH[k8][tn][0] = *(const int4*)pb;
      *(int4*)&BH[k8][tn][8] = *(const int4*)(pb + 8);
      *(int4*)&BL[k8][tn][0] = *(const int4*)pbl;
      *(int4*)&BL[k8][tn][8] = *(const int4*)(pbl + 8);
      const short* pd  = Wo1thi + (size_t)tn * FDIM + h * 64 + k8 * 16;
      const short* pdl = Wo1tlo + (size_t)tn * FDIM + h * 64 + k8 * 16;
      *(int4*)&DH[k8][tn][0] = *(const int4*)pd;
      *(int4*)&DH[k8][tn][8] = *(const int4*)(pd + 8);
      *(int4*)&DL[k8][tn][0] = *(const int4*)pdl;
      *(int4*)&DL[k8][tn][8] = *(const int4*)(pdl + 8);
    }
    __syncthreads();
    // W2 MFMA (K=64)
    f32x16 accw;
#pragma unroll
    for (int r = 0; r < 16; ++r) accw[r] = 0.f;
#pragma unroll
    for (int t = 0; t < 4; ++t) {
      bf16x8 ah = *(const bf16x8*)&AH[t][wm * 32 + ml][g8];
      bf16x8 al = *(const bf16x8*)&AL[t][wm * 32 + ml][g8];
      bf16x8 bh = *(const bf16x8*)&BH[t][wn * 32 + ml][g8];
      bf16x8 bl = *(const bf16x8*)&BL[t][wn * 32 + ml][g8];
      accw = __builtin_amdgcn_mfma_f32_32x32x16_bf16(ah, bh, accw, 0, 0, 0);
      accw = __builtin_amdgcn_mfma_f32_32x32x16_bf16(al, bh, accw, 0, 0, 0);
      accw = __builtin_amdgcn_mfma_f32_32x32x16_bf16(ah, bl, accw, 0, 0, 0);
    }
    // bW + elu, scatter H1_h into CH/CL (col fixed per lane, rows vary)
    const float bwv = bW[h * 64 + colw];
    const int ts = colw >> 4, ss = colw & 15;
#pragma unroll
    for (int r = 0; r < 16; ++r) {
      int rl = rowl0 + (r & 3) + 8 * (r >> 2);
      float v = accw[r] + bwv;
      v = v > 0.f ? v : __expf(v) - 1.f;
      unsigned short hv = f2bf(v);
      CH[ts][rl][ss] = (short)hv;
      CL[ts][rl][ss] = (short)f2bf(v - bf2f(hv));
    }
    __syncthreads();
    // fts2 MFMA accumulate (K=64, this head's k-block)
#pragma unroll
    for (int t = 0; t < 4; ++t) {
      bf16x8 ah = *(const bf16x8*)&CH[t][wm * 32 + ml][g8];
      bf16x8 al = *(const bf16x8*)&CL[t][wm * 32 + ml][g8];
      bf16x8 bh = *(const bf16x8*)&DH[t][wn * 32 + ml][g8];
      bf16x8 bl = *(const bf16x8*)&DL[t][wn * 32 + ml][g8];
      acc2 = __builtin_amdgcn_mfma_f32_32x32x16_bf16(ah, bh, acc2, 0, 0, 0);
      acc2 = __builtin_amdgcn_mfma_f32_32x32x16_bf16(al, bh, acc2, 0, 0, 0);
      acc2 = __builtin_amdgcn_mfma_f32_32x32x16_bf16(ah, bl, acc2, 0, 0, 0);
    }
    __syncthreads();
  }

  // epilogue: FTS2 + f1o/f2o
  const bool act = colw < CDIM;
  const float aov1 = act ? ao1[colw] : 0.f;
  const float aov2 = act ? ao2[colw] : 0.f;
#pragma unroll
  for (int r = 0; r < 16; ++r) {
    int rl = rowl0 + (r & 3) + 8 * (r >> 2);
    float v = acc2[r];
    if (act) FTS2[(size_t)(i0 + rl) * CDIM + colw] = v;
    float p1 = v * aov1, p2 = v * aov2;
#pragma unroll
    for (int o = 1; o < 32; o <<= 1) {
      p1 += __shfl_xor(p1, o);
      p2 += __shfl_xor(p2, o);
    }
    if (ml == 0) {
      p1buf[wn][rl] = p1;
      p2buf[wn][rl] = p2;
    }
  }
  __syncthreads();
  if (tid < 64) {
    F1O[i0 + tid] = p1buf[0][tid] + p1buf[1][tid] + bo1s[0];
    F2O[i0 + tid] = p2buf[0][tid] + p2buf[1][tid] + bo2s[0];
  }
}

// ---------------- Kernel 5: layer-2 attention + output GEMM (fused) ---------
__global__ __launch_bounds__(256) void k_agg2(
    const float* __restrict__ FTS2, const float* __restrict__ F1O,
    const float* __restrict__ F2O, const int* __restrict__ nbr,
    const int* __restrict__ cnt, const float* __restrict__ Wo2,
    const float* __restrict__ bo, float* __restrict__ out) {
  int i = blockIdx.x * 4 + (threadIdx.x >> 6);
  int lane = threadIdx.x & 63;
  int deg = cnt[i];
  const int* nb = nbr + (size_t)i * MAXD;
  float f1i = F1O[i];

  int jreg[4];
  float p[4];
  float m = -1e30f;
#pragma unroll
  for (int r = 0; r < 4; ++r) { jreg[r] = 0; p[r] = -1e30f; }
#pragma unroll
  for (int r = 0; r < 4; ++r) {
    int t = r * 64 + lane;
    if (t < deg) {
      int j = nb[t];
      jreg[r] = j;
      float x = f1i + F2O[j];
      x = x >= 0.f ? x : 0.2f * x;
      p[r] = x;
      m = fmaxf(m, x);
    }
  }
  m = wave_max64(m);
  float s = 0.f;
#pragma unroll
  for (int r = 0; r < 4; ++r) {
    int t = r * 64 + lane;
    float e = (t < deg) ? __expf(p[r] - m) : 0.f;
    p[r] = e;
    s += e;
  }
  s = wave_sum64(s);

  const bool act = lane < CDIM;
  float accA = 0.f, accB = 0.f;
#pragma unroll
  for (int r = 0; r < 4; ++r) {
    int base = r * 64;
    if (base >= deg) break;
    int lim = deg - base;
    lim = lim < 64 ? lim : 64;
    int sl = 0;
    for (; sl + 2 <= lim; sl += 2) {
      float w0 = readlane_f(p[r], sl);
      float w1 = readlane_f(p[r], sl + 1);
      int j0 = readlane_i(jreg[r], sl);
      int j1 = readlane_i(jreg[r], sl + 1);
      float f0 = act ? FTS2[(size_t)j0 * CDIM + lane] : 0.f;
      float f1 = act ? FTS2[(size_t)j1 * CDIM + lane] : 0.f;
      accA += w0 * f0;
      accB += w1 * f1;
    }
    if (sl < lim) {
      float w0 = readlane_f(p[r], sl);
      int j0 = readlane_i(jreg[r], sl);
      float f0 = act ? FTS2[(size_t)j0 * CDIM + lane] : 0.f;
      accA += w0 * f0;
    }
  }
  float v = (accA + accB) / s;

  float o = act ? bo[lane] : 0.f;
  for (int kk = 0; kk < CDIM; ++kk) {
    float w = readlane_f(v, kk);
    float b = act ? Wo2[kk * CDIM + lane] : 0.f;
    o += w * b;
  }
  if (act) out[(size_t)i * CDIM + lane] = o;
}

extern "C" void kernel_launch(void* const* d_in, const int* in_sizes, int n_in,
                              void* d_out, int out_size, void* d_ws, size_t ws_size,
                              hipStream_t stream) {
  const float* seq  = (const float*)d_in[0];
  const float* bias = (const float*)d_in[1];
  const float* W1   = (const float*)d_in[2];
  const float* a1   = (const float*)d_in[3];
  const float* b1   = (const float*)d_in[4];
  const float* a2   = (const float*)d_in[5];
  const float* b2   = (const float*)d_in[6];
  const float* W2   = (const float*)d_in[7];
  const float* bW   = (const float*)d_in[8];
  const float* Wo1  = (const float*)d_in[9];
  const float* ao1  = (const float*)d_in[10];
  const float* bo1  = (const float*)d_in[11];
  const float* ao2  = (const float*)d_in[12];
  const float* bo2  = (const float*)d_in[13];
  const float* Wo2  = (const float*)d_in[14];
  const float* bo   = (const float*)d_in[15];
  float* out = (float*)d_out;

  float* ws    = (float*)d_ws;
  float* FTS   = ws;                          // N*512 f32
  float* F1t   = FTS  + (size_t)NN * FDIM;    // N*8
  float* F2t   = F1t  + (size_t)NN * NHEAD;   // N*8
  float* FTS2  = F2t  + (size_t)NN * NHEAD;   // N*40
  float* F1O   = FTS2 + (size_t)NN * CDIM;    // N
  float* F2O   = F1O  + NN;                   // N
  short* Ahi   = (short*)(F2O + NN);          // N*512 bf16
  short* Alo   = Ahi + (size_t)NN * FDIM;
  short* Bhi   = Alo + (size_t)NN * FDIM;     // 8*64*512
  short* Blo   = Bhi + (size_t)NHEAD * HDIM * FDIM;
  short* VALShi= Blo + (size_t)NHEAD * HDIM * FDIM;  // N*512
  short* VALSlo= VALShi + (size_t)NN * FDIM;
  short* W2thi = VALSlo + (size_t)NN * FDIM;         // 8*64*64
  short* W2tlo = W2thi + (size_t)NHEAD * HDIM * HDIM;
  short* Wo1thi= W2tlo + (size_t)NHEAD * HDIM * HDIM; // 64*512
  short* Wo1tlo= Wo1thi + (size_t)64 * FDIM;
  int*   nbr   = (int*)(Wo1tlo + (size_t)64 * FDIM);  // N*MAXD
  int*   cnt   = nbr + (size_t)NN * MAXD;     // N

  // 1. CSR + all weight/input conversions
  k_prep<<<NN + 1024 + 64 + 8 + 8, 256, 0, stream>>>(
      bias, nbr, cnt, seq, Ahi, Alo, W1, Bhi, Blo, W2, W2thi, W2tlo,
      Wo1, Wo1thi, Wo1tlo);
  // 2. MFMA hi/lo GEMM (full K) + fused f1/f2
  k_gemm<<<dim3(NN / 64, NHEAD / 2), 256, 0, stream>>>(
      Ahi, Alo, Bhi, Blo, a1, b1, a2, b2, FTS, F1t, F2t);
  // 3. sparse softmax + aggregation -> VALS bf16 hi/lo
  k_agg1<<<NN * 2 / 4, 256, 0, stream>>>(FTS, F1t, F2t, nbr, cnt, VALShi, VALSlo);
  // 4. fused W2+elu+fts2 MFMA tail
  k_tail<<<NN / 64, 256, 0, stream>>>(VALShi, VALSlo, W2thi, W2tlo, bW,
                                      Wo1thi, Wo1tlo, ao1, bo1, ao2, bo2,
                                      FTS2, F1O, F2O);
  // 5. layer-2 sparse attention + final dense + bias
  k_agg2<<<NN / 4, 256, 0, stream>>>(FTS2, F1O, F2O, nbr, cnt, Wo2, bo, out);
}

// Round 10
// 95.309 us; speedup vs baseline: 2.8310x; 1.0682x over previous
//
#include <hip/hip_runtime.h>
#include <cstdint>
#include <cstddef>

#define NN 4096
#define FDIM 512
#define HDIM 64
#define NHEAD 8
#define CDIM 40
#define MAXD 256   // max neighbors kept per row (~41 expected)

typedef __attribute__((ext_vector_type(8))) short bf16x8;
typedef __attribute__((ext_vector_type(16))) float f32x16;

__device__ __forceinline__ float wave_max64(float v) {
  for (int o = 32; o; o >>= 1) v = fmaxf(v, __shfl_xor(v, o));
  return v;
}
__device__ __forceinline__ float wave_sum64(float v) {
  for (int o = 32; o; o >>= 1) v += __shfl_xor(v, o);
  return v;
}
__device__ __forceinline__ float readlane_f(float v, int sl) {
  return __uint_as_float((unsigned)__builtin_amdgcn_readlane((int)__float_as_uint(v), sl));
}
__device__ __forceinline__ int readlane_i(int v, int sl) {
  return __builtin_amdgcn_readlane(v, sl);
}
// fp32 -> bf16 (RNE) and back, via bit ops
__device__ __forceinline__ unsigned short f2bf(float x) {
  unsigned u = __float_as_uint(x);
  return (unsigned short)((u + 0x7fffu + ((u >> 16) & 1u)) >> 16);
}
__device__ __forceinline__ float bf2f(unsigned short b) {
  return __uint_as_float(((unsigned)b) << 16);
}

// ---------------- Kernel 1: prep -------------------------------------------
// Grid = 4096 csr + 1024 seq-cvt + 64 W1 + 8 W2t + 8 Wo1t = 5200 blocks.
__global__ __launch_bounds__(256) void k_prep(
    const float* __restrict__ bias, int* __restrict__ nbr, int* __restrict__ cnt,
    const float* __restrict__ seq, short* __restrict__ Ahi, short* __restrict__ Alo,
    const float* __restrict__ W1, short* __restrict__ Bhi, short* __restrict__ Blo,
    const float* __restrict__ W2, short* __restrict__ W2thi, short* __restrict__ W2tlo,
    const float* __restrict__ Wo1, short* __restrict__ Wo1thi, short* __restrict__ Wo1tlo) {
  __shared__ int wtot[4];
  __shared__ float T[64][65];
  int bx = blockIdx.x, tid = threadIdx.x;
  if (bx < NN) {       // ---- CSR: one block per row, thread owns 16 cols
    int row = bx;
    int lane = tid & 63, wv = tid >> 6;
    const float4* r = (const float4*)(bias + (size_t)row * NN);
    unsigned mask = 0;
#pragma unroll
    for (int i = 0; i < 4; ++i) {
      float4 v = r[tid * 4 + i];
      mask |= (unsigned)((v.x == 0.f ? 1 : 0) | (v.y == 0.f ? 2 : 0) |
                         (v.z == 0.f ? 4 : 0) | (v.w == 0.f ? 8 : 0)) << (i * 4);
    }
    int c = __popc(mask);
    int pre = c;
#pragma unroll
    for (int o = 1; o < 64; o <<= 1) {
      int u = __shfl_up(pre, o);
      if (lane >= o) pre += u;
    }
    if (lane == 63) wtot[wv] = pre;
    __syncthreads();
    int woff = 0;
#pragma unroll
    for (int w = 0; w < 4; ++w)
      if (w < wv) woff += wtot[w];
    int excl = woff + pre - c;
    int* out = nbr + (size_t)row * MAXD;
    int col0 = tid * 16, k = 0;
#pragma unroll
    for (int i = 0; i < 16; ++i) {
      if ((mask >> i) & 1) {
        int p = excl + k;
        if (p < MAXD) out[p] = col0 + i;
        ++k;
      }
    }
    if (tid == 0) {
      int total = wtot[0] + wtot[1] + wtot[2] + wtot[3];
      cnt[row] = total < MAXD ? total : MAXD;
    }
    return;
  }
  bx -= NN;
  if (bx < 1024) {     // ---- seq -> bf16 hi/lo (8 elems/thread)
    size_t off = (size_t)bx * 2048 + (size_t)tid * 8;
    float4 v0 = *(const float4*)(seq + off);
    float4 v1 = *(const float4*)(seq + off + 4);
    unsigned short h0 = f2bf(v0.x), h1 = f2bf(v0.y), h2 = f2bf(v0.z), h3 = f2bf(v0.w);
    unsigned short h4 = f2bf(v1.x), h5 = f2bf(v1.y), h6 = f2bf(v1.z), h7 = f2bf(v1.w);
    *(uint4*)(Ahi + off) = make_uint4(
        (unsigned)h0 | ((unsigned)h1 << 16), (unsigned)h2 | ((unsigned)h3 << 16),
        (unsigned)h4 | ((unsigned)h5 << 16), (unsigned)h6 | ((unsigned)h7 << 16));
    unsigned short l0 = f2bf(v0.x - bf2f(h0)), l1 = f2bf(v0.y - bf2f(h1));
    unsigned short l2 = f2bf(v0.z - bf2f(h2)), l3 = f2bf(v0.w - bf2f(h3));
    unsigned short l4 = f2bf(v1.x - bf2f(h4)), l5 = f2bf(v1.y - bf2f(h5));
    unsigned short l6 = f2bf(v1.z - bf2f(h6)), l7 = f2bf(v1.w - bf2f(h7));
    *(uint4*)(Alo + off) = make_uint4(
        (unsigned)l0 | ((unsigned)l1 << 16), (unsigned)l2 | ((unsigned)l3 << 16),
        (unsigned)l4 | ((unsigned)l5 << 16), (unsigned)l6 | ((unsigned)l7 << 16));
    return;
  }
  bx -= 1024;
  if (bx < 64) {       // ---- W1 tile transpose + bf16 hi/lo: [k][n] -> [n][k]
    int h = bx >> 3, kb = bx & 7;
    const float* src = W1 + ((size_t)h * FDIM + kb * 64) * HDIM;
#pragma unroll
    for (int q = 0; q < 4; ++q) {
      int fi = q * 256 + tid, kk = fi >> 4, n4 = fi & 15;
      float4 v = *(const float4*)(src + (size_t)kk * HDIM + n4 * 4);
      T[n4 * 4 + 0][kk] = v.x; T[n4 * 4 + 1][kk] = v.y;
      T[n4 * 4 + 2][kk] = v.z; T[n4 * 4 + 3][kk] = v.w;
    }
    __syncthreads();
#pragma unroll
    for (int q = 0; q < 4; ++q) {
      int fi = q * 256 + tid, n = fi >> 4, k4 = fi & 15;
      float a = T[n][k4 * 4], b = T[n][k4 * 4 + 1];
      float c = T[n][k4 * 4 + 2], d = T[n][k4 * 4 + 3];
      size_t o = ((size_t)h * 64 + n) * FDIM + kb * 64 + k4 * 4;
      unsigned short ha = f2bf(a), hb = f2bf(b), hc = f2bf(c), hd = f2bf(d);
      *(short4*)(Bhi + o) = make_short4((short)ha, (short)hb, (short)hc, (short)hd);
      *(short4*)(Blo + o) = make_short4((short)f2bf(a - bf2f(ha)), (short)f2bf(b - bf2f(hb)),
                                        (short)f2bf(c - bf2f(hc)), (short)f2bf(d - bf2f(hd)));
    }
    return;
  }
  bx -= 64;
  if (bx < 8) {        // ---- W2[h] transpose [64k][64n] -> [n][k] hi/lo
    int h = bx;
    const float* src = W2 + (size_t)h * HDIM * HDIM;
#pragma unroll
    for (int q = 0; q < 4; ++q) {
      int fi = q * 256 + tid, kk = fi >> 4, n4 = fi & 15;
      float4 v = *(const float4*)(src + (size_t)kk * HDIM + n4 * 4);
      T[n4 * 4 + 0][kk] = v.x; T[n4 * 4 + 1][kk] = v.y;
      T[n4 * 4 + 2][kk] = v.z; T[n4 * 4 + 3][kk] = v.w;
    }
    __syncthreads();
#pragma unroll
    for (int q = 0; q < 4; ++q) {
      int fi = q * 256 + tid, n = fi >> 4, k4 = fi & 15;
      float a = T[n][k4 * 4], b = T[n][k4 * 4 + 1];
      float c = T[n][k4 * 4 + 2], d = T[n][k4 * 4 + 3];
      size_t o = (size_t)h * 4096 + (size_t)n * 64 + k4 * 4;
      unsigned short ha = f2bf(a), hb = f2bf(b), hc = f2bf(c), hd = f2bf(d);
      *(short4*)(W2thi + o) = make_short4((short)ha, (short)hb, (short)hc, (short)hd);
      *(short4*)(W2tlo + o) = make_short4((short)f2bf(a - bf2f(ha)), (short)f2bf(b - bf2f(hb)),
                                          (short)f2bf(c - bf2f(hc)), (short)f2bf(d - bf2f(hd)));
    }
    return;
  }
  bx -= 8;
  {                    // ---- Wo1 transpose+pad [512][40] -> [64][512] hi/lo
#pragma unroll
    for (int q = 0; q < 16; ++q) {
      int idx = q * 256 + tid;          // 0..4095
      int n = bx * 8 + (idx >> 9), k = idx & 511;
      float v = (n < CDIM) ? Wo1[(size_t)k * CDIM + n] : 0.f;
      unsigned short hv = f2bf(v);
      Wo1thi[(size_t)n * FDIM + k] = (short)hv;
      Wo1tlo[(size_t)n * FDIM + k] = (short)f2bf(v - bf2f(hv));
    }
  }
}

// ---------------- Kernel 2: MFMA GEMM (full K) + fused f1/f2 ---------------
// FTS now emitted as bf16 (RNE) — halves the agg1 gather traffic.
// f1/f2 still computed from fp32 accumulators (logits stay fp32-exact).
__global__ __launch_bounds__(256) void k_gemm(
    const short* __restrict__ Ahi, const short* __restrict__ Alo,
    const short* __restrict__ Bhi, const short* __restrict__ Blo,
    const float* __restrict__ a1, const float* __restrict__ b1,
    const float* __restrict__ a2, const float* __restrict__ b2,
    short* __restrict__ FTSb, float* __restrict__ F1t, float* __restrict__ F2t) {
  __shared__ short AH[4][64][16], AL[4][64][16];    // [kstep16][m][k-slot]
  __shared__ short BH[4][128][16], BL[4][128][16];  // [kstep16][n][k-slot]
  const int mtile = blockIdx.x, npair = blockIdx.y;
  const int tid = threadIdx.x, lane = tid & 63, w = tid >> 6;
  const int wm = w >> 1, wn = w & 1;
  const int ml = lane & 31, g = lane >> 5, g8 = g * 8;

  f32x16 acc0, acc1;
#pragma unroll
  for (int r = 0; r < 16; ++r) { acc0[r] = 0.f; acc1[r] = 0.f; }

  const short* Abh = Ahi + (((size_t)mtile * 64) << 9);
  const short* Abl = Alo + (((size_t)mtile * 64) << 9);
  const short* Bbh = Bhi + (((size_t)npair * 128) << 9);
  const short* Bbl = Blo + (((size_t)npair * 128) << 9);

  const int tn = tid >> 3, k8 = tid & 7;
  const int ks = k8 >> 1, ko = (k8 & 1) * 8;
  const size_t so = ((size_t)tn << 9) + (size_t)k8 * 8;

  int4 rah0, rah1, ral0, ral1, rbh0, rbh1, rbh2, rbh3, rbl0, rbl1, rbl2, rbl3;
  {
    rah0 = *(const int4*)(Abh + so);              ral0 = *(const int4*)(Abl + so);
    rah1 = *(const int4*)(Abh + so + (32 << 9));  ral1 = *(const int4*)(Abl + so + (32 << 9));
    rbh0 = *(const int4*)(Bbh + so);              rbl0 = *(const int4*)(Bbl + so);
    rbh1 = *(const int4*)(Bbh + so + (32 << 9));  rbl1 = *(const int4*)(Bbl + so + (32 << 9));
    rbh2 = *(const int4*)(Bbh + so + (64 << 9));  rbl2 = *(const int4*)(Bbl + so + (64 << 9));
    rbh3 = *(const int4*)(Bbh + so + (96 << 9));  rbl3 = *(const int4*)(Bbl + so + (96 << 9));
  }

  const int NCH = FDIM / 64;   // 8 chunks
  for (int c = 0; c < NCH; ++c) {
    *(int4*)&AH[ks][tn][ko] = rah0;       *(int4*)&AL[ks][tn][ko] = ral0;
    *(int4*)&AH[ks][32 + tn][ko] = rah1;  *(int4*)&AL[ks][32 + tn][ko] = ral1;
    *(int4*)&BH[ks][tn][ko] = rbh0;       *(int4*)&BL[ks][tn][ko] = rbl0;
    *(int4*)&BH[ks][32 + tn][ko] = rbh1;  *(int4*)&BL[ks][32 + tn][ko] = rbl1;
    *(int4*)&BH[ks][64 + tn][ko] = rbh2;  *(int4*)&BL[ks][64 + tn][ko] = rbl2;
    *(int4*)&BH[ks][96 + tn][ko] = rbh3;  *(int4*)&BL[ks][96 + tn][ko] = rbl3;
    __syncthreads();
    if (c + 1 < NCH) {
      size_t o = so + (size_t)(c + 1) * 64;
      rah0 = *(const int4*)(Abh + o);              ral0 = *(const int4*)(Abl + o);
      rah1 = *(const int4*)(Abh + o + (32 << 9));  ral1 = *(const int4*)(Abl + o + (32 << 9));
      rbh0 = *(const int4*)(Bbh + o);              rbl0 = *(const int4*)(Bbl + o);
      rbh1 = *(const int4*)(Bbh + o + (32 << 9));  rbl1 = *(const int4*)(Bbl + o + (32 << 9));
      rbh2 = *(const int4*)(Bbh + o + (64 << 9));  rbl2 = *(const int4*)(Bbl + o + (64 << 9));
      rbh3 = *(const int4*)(Bbh + o + (96 << 9));  rbl3 = *(const int4*)(Bbl + o + (96 << 9));
    }
#pragma unroll
    for (int t = 0; t < 4; ++t) {
      bf16x8 ah = *(const bf16x8*)&AH[t][wm * 32 + ml][g8];
      bf16x8 al = *(const bf16x8*)&AL[t][wm * 32 + ml][g8];
      bf16x8 bh0 = *(const bf16x8*)&BH[t][wn * 64 + ml][g8];
      bf16x8 bl0 = *(const bf16x8*)&BL[t][wn * 64 + ml][g8];
      acc0 = __builtin_amdgcn_mfma_f32_32x32x16_bf16(ah, bh0, acc0, 0, 0, 0);
      acc0 = __builtin_amdgcn_mfma_f32_32x32x16_bf16(al, bh0, acc0, 0, 0, 0);
      acc0 = __builtin_amdgcn_mfma_f32_32x32x16_bf16(ah, bl0, acc0, 0, 0, 0);
      bf16x8 bh1 = *(const bf16x8*)&BH[t][wn * 64 + 32 + ml][g8];
      bf16x8 bl1 = *(const bf16x8*)&BL[t][wn * 64 + 32 + ml][g8];
      acc1 = __builtin_amdgcn_mfma_f32_32x32x16_bf16(ah, bh1, acc1, 0, 0, 0);
      acc1 = __builtin_amdgcn_mfma_f32_32x32x16_bf16(al, bh1, acc1, 0, 0, 0);
      acc1 = __builtin_amdgcn_mfma_f32_32x32x16_bf16(ah, bl1, acc1, 0, 0, 0);
    }
    __syncthreads();
  }

  // epilogue: C layout col=lane&31, row=(r&3)+8*(r>>2)+4*(lane>>5)
  const int h = npair * 2 + wn;
  const float a1lo = a1[h * 64 + ml], a1hi = a1[h * 64 + 32 + ml];
  const float a2lo = a2[h * 64 + ml], a2hi = a2[h * 64 + 32 + ml];
  const float b1h = b1[h], b2h = b2[h];
  const int row0 = mtile * 64 + wm * 32 + 4 * g;
  const int col0 = npair * 128 + wn * 64 + ml;
#pragma unroll
  for (int r = 0; r < 16; ++r) {
    int row = row0 + (r & 3) + 8 * (r >> 2);
    FTSb[(size_t)row * FDIM + col0] = (short)f2bf(acc0[r]);
    FTSb[(size_t)row * FDIM + col0 + 32] = (short)f2bf(acc1[r]);
    float p1 = acc0[r] * a1lo + acc1[r] * a1hi;
    float p2 = acc0[r] * a2lo + acc1[r] * a2hi;
#pragma unroll
    for (int o = 1; o < 32; o <<= 1) {
      p1 += __shfl_xor(p1, o);
      p2 += __shfl_xor(p2, o);
    }
    if (ml == 0) {
      F1t[(size_t)row * 8 + h] = p1 + b1h;
      F2t[(size_t)row * 8 + h] = p2 + b2h;
    }
  }
}

// ---------------- Kernel 3: sparse softmax + aggregation (4 heads/wave) -----
// bf16 FTS gather: 8 B/lane, 512 B/wave — half the bytes of fp32.
__global__ __launch_bounds__(256) void k_agg1(
    const short* __restrict__ FTSb, const float* __restrict__ F1t,
    const float* __restrict__ F2t, const int* __restrict__ nbr,
    const int* __restrict__ cnt, short* __restrict__ VALShi,
    short* __restrict__ VALSlo) {
  __shared__ float plds[4][MAXD][4];   // [wave][slot][head-q] = 16 KB
  int wv = threadIdx.x >> 6, lane = threadIdx.x & 63;
  int gw = blockIdx.x * 4 + wv;     // over NN*2
  int i = gw >> 1, hg = gw & 1;
  int deg = cnt[i];
  const int* nb = nbr + (size_t)i * MAXD;
  float4 f1v = *(const float4*)(F1t + (size_t)i * 8 + hg * 4);

  float4 p4[4];
  int jreg[4];
  float mx = -1e30f, my = -1e30f, mz = -1e30f, mw = -1e30f;
#pragma unroll
  for (int r = 0; r < 4; ++r) {
    int t = r * 64 + lane;
    jreg[r] = 0;
    p4[r] = make_float4(-1e30f, -1e30f, -1e30f, -1e30f);
    if (t < deg) {
      int j = nb[t];
      jreg[r] = j;
      float4 f2v = *(const float4*)(F2t + (size_t)j * 8 + hg * 4);
      float4 x;
      x.x = f1v.x + f2v.x; x.x = x.x >= 0.f ? x.x : 0.2f * x.x;
      x.y = f1v.y + f2v.y; x.y = x.y >= 0.f ? x.y : 0.2f * x.y;
      x.z = f1v.z + f2v.z; x.z = x.z >= 0.f ? x.z : 0.2f * x.z;
      x.w = f1v.w + f2v.w; x.w = x.w >= 0.f ? x.w : 0.2f * x.w;
      p4[r] = x;
      mx = fmaxf(mx, x.x); my = fmaxf(my, x.y);
      mz = fmaxf(mz, x.z); mw = fmaxf(mw, x.w);
    }
  }
  mx = wave_max64(mx); my = wave_max64(my);
  mz = wave_max64(mz); mw = wave_max64(mw);
  float sx = 0.f, sy = 0.f, sz = 0.f, sw = 0.f;
#pragma unroll
  for (int r = 0; r < 4; ++r) {
    int t = r * 64 + lane;
    float4 e = make_float4(0.f, 0.f, 0.f, 0.f);
    if (t < deg) {
      e.x = __expf(p4[r].x - mx); e.y = __expf(p4[r].y - my);
      e.z = __expf(p4[r].z - mz); e.w = __expf(p4[r].w - mw);
    }
    p4[r] = e;
    sx += e.x; sy += e.y; sz += e.z; sw += e.w;
    *(float4*)&plds[wv][r * 64 + lane][0] = e;
  }
  sx = wave_sum64(sx); sy = wave_sum64(sy);
  sz = wave_sum64(sz); sw = wave_sum64(sw);

  int q = lane >> 4;
  float invh = (q < 2) ? (q == 0 ? 1.f / sx : 1.f / sy)
                       : (q == 2 ? 1.f / sz : 1.f / sw);

  float4 accA = make_float4(0.f, 0.f, 0.f, 0.f);
  float4 accB = make_float4(0.f, 0.f, 0.f, 0.f);
  const short* Fb = FTSb + hg * 256;
#pragma unroll
  for (int r = 0; r < 4; ++r) {
    int base = r * 64;
    if (base >= deg) break;
    int lim = deg - base;
    lim = lim < 64 ? lim : 64;
    int sl = 0;
    for (; sl + 2 <= lim; sl += 2) {
      int j0 = readlane_i(jreg[r], sl);
      int j1 = readlane_i(jreg[r], sl + 1);
      float wA = plds[wv][base + sl][q];
      float wB = plds[wv][base + sl + 1][q];
      short4 s0 = *(const short4*)(Fb + (size_t)j0 * FDIM + lane * 4);
      short4 s1 = *(const short4*)(Fb + (size_t)j1 * FDIM + lane * 4);
      accA.x += wA * bf2f((unsigned short)s0.x);
      accA.y += wA * bf2f((unsigned short)s0.y);
      accA.z += wA * bf2f((unsigned short)s0.z);
      accA.w += wA * bf2f((unsigned short)s0.w);
      accB.x += wB * bf2f((unsigned short)s1.x);
      accB.y += wB * bf2f((unsigned short)s1.y);
      accB.z += wB * bf2f((unsigned short)s1.z);
      accB.w += wB * bf2f((unsigned short)s1.w);
    }
    if (sl < lim) {
      int j0 = readlane_i(jreg[r], sl);
      float wA = plds[wv][base + sl][q];
      short4 s0 = *(const short4*)(Fb + (size_t)j0 * FDIM + lane * 4);
      accA.x += wA * bf2f((unsigned short)s0.x);
      accA.y += wA * bf2f((unsigned short)s0.y);
      accA.z += wA * bf2f((unsigned short)s0.z);
      accA.w += wA * bf2f((unsigned short)s0.w);
    }
  }
  float vx = (accA.x + accB.x) * invh, vy = (accA.y + accB.y) * invh;
  float vz = (accA.z + accB.z) * invh, vw = (accA.w + accB.w) * invh;
  unsigned short hx = f2bf(vx), hy = f2bf(vy), hz = f2bf(vz), hw = f2bf(vw);
  size_t o = (size_t)i * FDIM + hg * 256 + lane * 4;
  *(short4*)(VALShi + o) = make_short4((short)hx, (short)hy, (short)hz, (short)hw);
  *(short4*)(VALSlo + o) = make_short4(
      (short)f2bf(vx - bf2f(hx)), (short)f2bf(vy - bf2f(hy)),
      (short)f2bf(vz - bf2f(hz)), (short)f2bf(vw - bf2f(hw)));
}

// ---------------- Kernel 4: fused tail: H1 = elu(VALS@W2+bW); FTS2 = H1@Wo1 -
__global__ __launch_bounds__(256) void k_tail(
    const short* __restrict__ VALShi, const short* __restrict__ VALSlo,
    const short* __restrict__ W2thi, const short* __restrict__ W2tlo,
    const float* __restrict__ bW,
    const short* __restrict__ Wo1thi, const short* __restrict__ Wo1tlo,
    const float* __restrict__ ao1, const float* __restrict__ bo1s,
    const float* __restrict__ ao2, const float* __restrict__ bo2s,
    float* __restrict__ FTS2, float* __restrict__ F1O, float* __restrict__ F2O) {
  __shared__ short AH[4][64][16], AL[4][64][16];   // VALS tile (A of W2 mfma)
  __shared__ short BH[4][64][16], BL[4][64][16];   // W2t[h]    (B of W2 mfma)
  __shared__ short CH[4][64][16], CL[4][64][16];   // H1_h      (A of fts2 mfma)
  __shared__ short DH[4][64][16], DL[4][64][16];   // Wo1t[h]   (B of fts2 mfma)
  __shared__ float p1buf[2][64], p2buf[2][64];
  const int i0 = blockIdx.x * 64;
  const int tid = threadIdx.x, lane = tid & 63, w = tid >> 6;
  const int wm = w >> 1, wn = w & 1;
  const int ml = lane & 31, g = lane >> 5, g8 = g * 8;
  const int tn = tid >> 2, k8 = tid & 3;
  const int colw = wn * 32 + ml;
  const int rowl0 = wm * 32 + 4 * g;

  f32x16 acc2;
#pragma unroll
  for (int r = 0; r < 16; ++r) acc2[r] = 0.f;

  for (int h = 0; h < NHEAD; ++h) {
    {
      const short* pa = VALShi + ((size_t)(i0 + tn) << 9) + h * 64 + k8 * 16;
      const short* pl = VALSlo + ((size_t)(i0 + tn) << 9) + h * 64 + k8 * 16;
      *(int4*)&AH[k8][tn][0] = *(const int4*)pa;
      *(int4*)&AH[k8][tn][8] = *(const int4*)(pa + 8);
      *(int4*)&AL[k8][tn][0] = *(const int4*)pl;
      *(int4*)&AL[k8][tn][8] = *(const int4*)(pl + 8);
      const short* pb  = W2thi + (size_t)h * 4096 + tn * 64 + k8 * 16;
      const short* pbl = W2tlo + (size_t)h * 4096 + tn * 64 + k8 * 16;
      *(int4*)&BH[k8][tn][0] = *(const int4*)pb;
      *(int4*)&BH[k8][tn][8] = *(const int4*)(pb + 8);
      *(int4*)&BL[k8][tn][0] = *(const int4*)pbl;
      *(int4*)&BL[k8][tn][8] = *(const int4*)(pbl + 8);
      const short* pd  = Wo1thi + (size_t)tn * FDIM + h * 64 + k8 * 16;
      const short* pdl = Wo1tlo + (size_t)tn * FDIM + h * 64 + k8 * 16;
      *(int4*)&DH[k8][tn][0] = *(const int4*)pd;
      *(int4*)&DH[k8][tn][8] = *(const int4*)(pd + 8);
      *(int4*)&DL[k8][tn][0] = *(const int4*)pdl;
      *(int4*)&DL[k8][tn][8] = *(const int4*)(pdl + 8);
    }
    __syncthreads();
    // W2 MFMA (K=64)
    f32x16 accw;
#pragma unroll
    for (int r = 0; r < 16; ++r) accw[r] = 0.f;
#pragma unroll
    for (int t = 0; t < 4; ++t) {
      bf16x8 ah = *(const bf16x8*)&AH[t][wm * 32 + ml][g8];
      bf16x8 al = *(const bf16x8*)&AL[t][wm * 32 + ml][g8];
      bf16x8 bh = *(const bf16x8*)&BH[t][wn * 32 + ml][g8];
      bf16x8 bl = *(const bf16x8*)&BL[t][wn * 32 + ml][g8];
      accw = __builtin_amdgcn_mfma_f32_32x32x16_bf16(ah, bh, accw, 0, 0, 0);
      accw = __builtin_amdgcn_mfma_f32_32x32x16_bf16(al, bh, accw, 0, 0, 0);
      accw = __builtin_amdgcn_mfma_f32_32x32x16_bf16(ah, bl, accw, 0, 0, 0);
    }
    const float bwv = bW[h * 64 + colw];
    const int ts = colw >> 4, ss = colw & 15;
#pragma unroll
    for (int r = 0; r < 16; ++r) {
      int rl = rowl0 + (r & 3) + 8 * (r >> 2);
      float v = accw[r] + bwv;
      v = v > 0.f ? v : __expf(v) - 1.f;
      unsigned short hv = f2bf(v);
      CH[ts][rl][ss] = (short)hv;
      CL[ts][rl][ss] = (short)f2bf(v - bf2f(hv));
    }
    __syncthreads();
#pragma unroll
    for (int t = 0; t < 4; ++t) {
      bf16x8 ah = *(const bf16x8*)&CH[t][wm * 32 + ml][g8];
      bf16x8 al = *(const bf16x8*)&CL[t][wm * 32 + ml][g8];
      bf16x8 bh = *(const bf16x8*)&DH[t][wn * 32 + ml][g8];
      bf16x8 bl = *(const bf16x8*)&DL[t][wn * 32 + ml][g8];
      acc2 = __builtin_amdgcn_mfma_f32_32x32x16_bf16(ah, bh, acc2, 0, 0, 0);
      acc2 = __builtin_amdgcn_mfma_f32_32x32x16_bf16(al, bh, acc2, 0, 0, 0);
      acc2 = __builtin_amdgcn_mfma_f32_32x32x16_bf16(ah, bl, acc2, 0, 0, 0);
    }
    __syncthreads();
  }

  // epilogue: FTS2 + f1o/f2o
  const bool act = colw < CDIM;
  const float aov1 = act ? ao1[colw] : 0.f;
  const float aov2 = act ? ao2[colw] : 0.f;
#pragma unroll
  for (int r = 0; r < 16; ++r) {
    int rl = rowl0 + (r & 3) + 8 * (r >> 2);
    float v = acc2[r];
    if (act) FTS2[(size_t)(i0 + rl) * CDIM + colw] = v;
    float p1 = v * aov1, p2 = v * aov2;
#pragma unroll
    for (int o = 1; o < 32; o <<= 1) {
      p1 += __shfl_xor(p1, o);
      p2 += __shfl_xor(p2, o);
    }
    if (ml == 0) {
      p1buf[wn][rl] = p1;
      p2buf[wn][rl] = p2;
    }
  }
  __syncthreads();
  if (tid < 64) {
    F1O[i0 + tid] = p1buf[0][tid] + p1buf[1][tid] + bo1s[0];
    F2O[i0 + tid] = p2buf[0][tid] + p2buf[1][tid] + bo2s[0];
  }
}

// ---------------- Kernel 5: layer-2 attention + output GEMM (fused) ---------
__global__ __launch_bounds__(256) void k_agg2(
    const float* __restrict__ FTS2, const float* __restrict__ F1O,
    const float* __restrict__ F2O, const int* __restrict__ nbr,
    const int* __restrict__ cnt, const float* __restrict__ Wo2,
    const float* __restrict__ bo, float* __restrict__ out) {
  int i = blockIdx.x * 4 + (threadIdx.x >> 6);
  int lane = threadIdx.x & 63;
  int deg = cnt[i];
  const int* nb = nbr + (size_t)i * MAXD;
  float f1i = F1O[i];

  int jreg[4];
  float p[4];
  float m = -1e30f;
#pragma unroll
  for (int r = 0; r < 4; ++r) { jreg[r] = 0; p[r] = -1e30f; }
#pragma unroll
  for (int r = 0; r < 4; ++r) {
    int t = r * 64 + lane;
    if (t < deg) {
      int j = nb[t];
      jreg[r] = j;
      float x = f1i + F2O[j];
      x = x >= 0.f ? x : 0.2f * x;
      p[r] = x;
      m = fmaxf(m, x);
    }
  }
  m = wave_max64(m);
  float s = 0.f;
#pragma unroll
  for (int r = 0; r < 4; ++r) {
    int t = r * 64 + lane;
    float e = (t < deg) ? __expf(p[r] - m) : 0.f;
    p[r] = e;
    s += e;
  }
  s = wave_sum64(s);

  const bool act = lane < CDIM;
  float accA = 0.f, accB = 0.f;
#pragma unroll
  for (int r = 0; r < 4; ++r) {
    int base = r * 64;
    if (base >= deg) break;
    int lim = deg - base;
    lim = lim < 64 ? lim : 64;
    int sl = 0;
    for (; sl + 2 <= lim; sl += 2) {
      float w0 = readlane_f(p[r], sl);
      float w1 = readlane_f(p[r], sl + 1);
      int j0 = readlane_i(jreg[r], sl);
      int j1 = readlane_i(jreg[r], sl + 1);
      float f0 = act ? FTS2[(size_t)j0 * CDIM + lane] : 0.f;
      float f1 = act ? FTS2[(size_t)j1 * CDIM + lane] : 0.f;
      accA += w0 * f0;
      accB += w1 * f1;
    }
    if (sl < lim) {
      float w0 = readlane_f(p[r], sl);
      int j0 = readlane_i(jreg[r], sl);
      float f0 = act ? FTS2[(size_t)j0 * CDIM + lane] : 0.f;
      accA += w0 * f0;
    }
  }
  float v = (accA + accB) / s;

  float o = act ? bo[lane] : 0.f;
  for (int kk = 0; kk < CDIM; ++kk) {
    float w = readlane_f(v, kk);
    float b = act ? Wo2[kk * CDIM + lane] : 0.f;
    o += w * b;
  }
  if (act) out[(size_t)i * CDIM + lane] = o;
}

extern "C" void kernel_launch(void* const* d_in, const int* in_sizes, int n_in,
                              void* d_out, int out_size, void* d_ws, size_t ws_size,
                              hipStream_t stream) {
  const float* seq  = (const float*)d_in[0];
  const float* bias = (const float*)d_in[1];
  const float* W1   = (const float*)d_in[2];
  const float* a1   = (const float*)d_in[3];
  const float* b1   = (const float*)d_in[4];
  const float* a2   = (const float*)d_in[5];
  const float* b2   = (const float*)d_in[6];
  const float* W2   = (const float*)d_in[7];
  const float* bW   = (const float*)d_in[8];
  const float* Wo1  = (const float*)d_in[9];
  const float* ao1  = (const float*)d_in[10];
  const float* bo1  = (const float*)d_in[11];
  const float* ao2  = (const float*)d_in[12];
  const float* bo2  = (const float*)d_in[13];
  const float* Wo2  = (const float*)d_in[14];
  const float* bo   = (const float*)d_in[15];
  float* out = (float*)d_out;

  float* ws    = (float*)d_ws;
  float* F1t   = ws;                          // N*8
  float* F2t   = F1t  + (size_t)NN * NHEAD;   // N*8
  float* FTS2  = F2t  + (size_t)NN * NHEAD;   // N*40
  float* F1O   = FTS2 + (size_t)NN * CDIM;    // N
  float* F2O   = F1O  + NN;                   // N
  short* FTSb  = (short*)(F2O + NN);          // N*512 bf16
  short* Ahi   = FTSb + (size_t)NN * FDIM;    // N*512 bf16
  short* Alo   = Ahi + (size_t)NN * FDIM;
  short* Bhi   = Alo + (size_t)NN * FDIM;     // 8*64*512
  short* Blo   = Bhi + (size_t)NHEAD * HDIM * FDIM;
  short* VALShi= Blo + (size_t)NHEAD * HDIM * FDIM;  // N*512
  short* VALSlo= VALShi + (size_t)NN * FDIM;
  short* W2thi = VALSlo + (size_t)NN * FDIM;         // 8*64*64
  short* W2tlo = W2thi + (size_t)NHEAD * HDIM * HDIM;
  short* Wo1thi= W2tlo + (size_t)NHEAD * HDIM * HDIM; // 64*512
  short* Wo1tlo= Wo1thi + (size_t)64 * FDIM;
  int*   nbr   = (int*)(Wo1tlo + (size_t)64 * FDIM);  // N*MAXD
  int*   cnt   = nbr + (size_t)NN * MAXD;     // N

  // 1. CSR + all weight/input conversions
  k_prep<<<NN + 1024 + 64 + 8 + 8, 256, 0, stream>>>(
      bias, nbr, cnt, seq, Ahi, Alo, W1, Bhi, Blo, W2, W2thi, W2tlo,
      Wo1, Wo1thi, Wo1tlo);
  // 2. MFMA hi/lo GEMM (full K) + fused f1/f2 -> FTSb (bf16), F1t, F2t
  k_gemm<<<dim3(NN / 64, NHEAD / 2), 256, 0, stream>>>(
      Ahi, Alo, Bhi, Blo, a1, b1, a2, b2, FTSb, F1t, F2t);
  // 3. sparse softmax + aggregation (bf16 gather) -> VALS bf16 hi/lo
  k_agg1<<<NN * 2 / 4, 256, 0, stream>>>(FTSb, F1t, F2t, nbr, cnt, VALShi, VALSlo);
  // 4. fused W2+elu+fts2 MFMA tail
  k_tail<<<NN / 64, 256, 0, stream>>>(VALShi, VALSlo, W2thi, W2tlo, bW,
                                      Wo1thi, Wo1tlo, ao1, bo1, ao2, bo2,
                                      FTS2, F1O, F2O);
  // 5. layer-2 sparse attention + final dense + bias
  k_agg2<<<NN / 4, 256, 0, stream>>>(FTS2, F1O, F2O, nbr, cnt, Wo2, bo, out);
}

// Round 11
// 87.301 us; speedup vs baseline: 3.0907x; 1.0917x over previous
//
#include <hip/hip_runtime.h>
#include <cstdint>
#include <cstddef>

#define NN 4096
#define FDIM 512
#define HDIM 64
#define NHEAD 8
#define CDIM 40
#define MAXD 256   // max neighbors kept per row (~41 expected)

typedef __attribute__((ext_vector_type(8))) short bf16x8;
typedef __attribute__((ext_vector_type(16))) float f32x16;

__device__ __forceinline__ float wave_max64(float v) {
  for (int o = 32; o; o >>= 1) v = fmaxf(v, __shfl_xor(v, o));
  return v;
}
__device__ __forceinline__ float wave_sum64(float v) {
  for (int o = 32; o; o >>= 1) v += __shfl_xor(v, o);
  return v;
}
__device__ __forceinline__ float readlane_f(float v, int sl) {
  return __uint_as_float((unsigned)__builtin_amdgcn_readlane((int)__float_as_uint(v), sl));
}
__device__ __forceinline__ int readlane_i(int v, int sl) {
  return __builtin_amdgcn_readlane(v, sl);
}
// fp32 -> bf16 (RNE) and back, via bit ops
__device__ __forceinline__ unsigned short f2bf(float x) {
  unsigned u = __float_as_uint(x);
  return (unsigned short)((u + 0x7fffu + ((u >> 16) & 1u)) >> 16);
}
__device__ __forceinline__ float bf2f(unsigned short b) {
  return __uint_as_float(((unsigned)b) << 16);
}

// ---------------- Kernel 1: prep (conversions only; CSR moved into k_gemm) --
// Grid = 1024 seq-cvt + 64 W1 + 8 W2t + 8 Wo1t = 1104 blocks.
__global__ __launch_bounds__(256) void k_prep(
    const float* __restrict__ seq, short* __restrict__ Ahi, short* __restrict__ Alo,
    const float* __restrict__ W1, short* __restrict__ Bhi, short* __restrict__ Blo,
    const float* __restrict__ W2, short* __restrict__ W2thi, short* __restrict__ W2tlo,
    const float* __restrict__ Wo1, short* __restrict__ Wo1thi, short* __restrict__ Wo1tlo) {
  __shared__ float T[64][65];
  int bx = blockIdx.x, tid = threadIdx.x;
  if (bx < 1024) {     // ---- seq -> bf16 hi/lo (8 elems/thread)
    size_t off = (size_t)bx * 2048 + (size_t)tid * 8;
    float4 v0 = *(const float4*)(seq + off);
    float4 v1 = *(const float4*)(seq + off + 4);
    unsigned short h0 = f2bf(v0.x), h1 = f2bf(v0.y), h2 = f2bf(v0.z), h3 = f2bf(v0.w);
    unsigned short h4 = f2bf(v1.x), h5 = f2bf(v1.y), h6 = f2bf(v1.z), h7 = f2bf(v1.w);
    *(uint4*)(Ahi + off) = make_uint4(
        (unsigned)h0 | ((unsigned)h1 << 16), (unsigned)h2 | ((unsigned)h3 << 16),
        (unsigned)h4 | ((unsigned)h5 << 16), (unsigned)h6 | ((unsigned)h7 << 16));
    unsigned short l0 = f2bf(v0.x - bf2f(h0)), l1 = f2bf(v0.y - bf2f(h1));
    unsigned short l2 = f2bf(v0.z - bf2f(h2)), l3 = f2bf(v0.w - bf2f(h3));
    unsigned short l4 = f2bf(v1.x - bf2f(h4)), l5 = f2bf(v1.y - bf2f(h5));
    unsigned short l6 = f2bf(v1.z - bf2f(h6)), l7 = f2bf(v1.w - bf2f(h7));
    *(uint4*)(Alo + off) = make_uint4(
        (unsigned)l0 | ((unsigned)l1 << 16), (unsigned)l2 | ((unsigned)l3 << 16),
        (unsigned)l4 | ((unsigned)l5 << 16), (unsigned)l6 | ((unsigned)l7 << 16));
    return;
  }
  bx -= 1024;
  if (bx < 64) {       // ---- W1 tile transpose + bf16 hi/lo: [k][n] -> [n][k]
    int h = bx >> 3, kb = bx & 7;
    const float* src = W1 + ((size_t)h * FDIM + kb * 64) * HDIM;
#pragma unroll
    for (int q = 0; q < 4; ++q) {
      int fi = q * 256 + tid, kk = fi >> 4, n4 = fi & 15;
      float4 v = *(const float4*)(src + (size_t)kk * HDIM + n4 * 4);
      T[n4 * 4 + 0][kk] = v.x; T[n4 * 4 + 1][kk] = v.y;
      T[n4 * 4 + 2][kk] = v.z; T[n4 * 4 + 3][kk] = v.w;
    }
    __syncthreads();
#pragma unroll
    for (int q = 0; q < 4; ++q) {
      int fi = q * 256 + tid, n = fi >> 4, k4 = fi & 15;
      float a = T[n][k4 * 4], b = T[n][k4 * 4 + 1];
      float c = T[n][k4 * 4 + 2], d = T[n][k4 * 4 + 3];
      size_t o = ((size_t)h * 64 + n) * FDIM + kb * 64 + k4 * 4;
      unsigned short ha = f2bf(a), hb = f2bf(b), hc = f2bf(c), hd = f2bf(d);
      *(short4*)(Bhi + o) = make_short4((short)ha, (short)hb, (short)hc, (short)hd);
      *(short4*)(Blo + o) = make_short4((short)f2bf(a - bf2f(ha)), (short)f2bf(b - bf2f(hb)),
                                        (short)f2bf(c - bf2f(hc)), (short)f2bf(d - bf2f(hd)));
    }
    return;
  }
  bx -= 64;
  if (bx < 8) {        // ---- W2[h] transpose [64k][64n] -> [n][k] hi/lo
    int h = bx;
    const float* src = W2 + (size_t)h * HDIM * HDIM;
#pragma unroll
    for (int q = 0; q < 4; ++q) {
      int fi = q * 256 + tid, kk = fi >> 4, n4 = fi & 15;
      float4 v = *(const float4*)(src + (size_t)kk * HDIM + n4 * 4);
      T[n4 * 4 + 0][kk] = v.x; T[n4 * 4 + 1][kk] = v.y;
      T[n4 * 4 + 2][kk] = v.z; T[n4 * 4 + 3][kk] = v.w;
    }
    __syncthreads();
#pragma unroll
    for (int q = 0; q < 4; ++q) {
      int fi = q * 256 + tid, n = fi >> 4, k4 = fi & 15;
      float a = T[n][k4 * 4], b = T[n][k4 * 4 + 1];
      float c = T[n][k4 * 4 + 2], d = T[n][k4 * 4 + 3];
      size_t o = (size_t)h * 4096 + (size_t)n * 64 + k4 * 4;
      unsigned short ha = f2bf(a), hb = f2bf(b), hc = f2bf(c), hd = f2bf(d);
      *(short4*)(W2thi + o) = make_short4((short)ha, (short)hb, (short)hc, (short)hd);
      *(short4*)(W2tlo + o) = make_short4((short)f2bf(a - bf2f(ha)), (short)f2bf(b - bf2f(hb)),
                                          (short)f2bf(c - bf2f(hc)), (short)f2bf(d - bf2f(hd)));
    }
    return;
  }
  bx -= 8;
  {                    // ---- Wo1 transpose+pad [512][40] -> [64][512] hi/lo
#pragma unroll
    for (int q = 0; q < 16; ++q) {
      int idx = q * 256 + tid;          // 0..4095
      int n = bx * 8 + (idx >> 9), k = idx & 511;
      float v = (n < CDIM) ? Wo1[(size_t)k * CDIM + n] : 0.f;
      unsigned short hv = f2bf(v);
      Wo1thi[(size_t)n * FDIM + k] = (short)hv;
      Wo1tlo[(size_t)n * FDIM + k] = (short)f2bf(v - bf2f(hv));
    }
  }
}

// ---------------- Kernel 2: MFMA GEMM + fused f1/f2  ∥  CSR build ----------
// Grid = 256 gemm blocks (mtile = bx&63, npair = bx>>6) + 4096 CSR rows.
// CSR (HBM-streaming) backfills CUs while the GEMM owns the matrix pipe.
__global__ __launch_bounds__(256) void k_gemm(
    const short* __restrict__ Ahi, const short* __restrict__ Alo,
    const short* __restrict__ Bhi, const short* __restrict__ Blo,
    const float* __restrict__ a1, const float* __restrict__ b1,
    const float* __restrict__ a2, const float* __restrict__ b2,
    short* __restrict__ FTSb, float* __restrict__ F1t, float* __restrict__ F2t,
    const float* __restrict__ bias, int* __restrict__ nbr, int* __restrict__ cnt) {
  __shared__ short AH[4][64][16], AL[4][64][16];    // [kstep16][m][k-slot]
  __shared__ short BH[4][128][16], BL[4][128][16];  // [kstep16][n][k-slot]
  __shared__ int wtot[4];
  const int bx = blockIdx.x;
  const int tid = threadIdx.x, lane = tid & 63, w = tid >> 6;

  if (bx >= 256) {     // ---------------- CSR: one block per row ------------
    int row = bx - 256;
    int wv = w;
    const float4* r = (const float4*)(bias + (size_t)row * NN);
    unsigned mask = 0;
#pragma unroll
    for (int i = 0; i < 4; ++i) {
      float4 v = r[tid * 4 + i];
      mask |= (unsigned)((v.x == 0.f ? 1 : 0) | (v.y == 0.f ? 2 : 0) |
                         (v.z == 0.f ? 4 : 0) | (v.w == 0.f ? 8 : 0)) << (i * 4);
    }
    int c = __popc(mask);
    int pre = c;
#pragma unroll
    for (int o = 1; o < 64; o <<= 1) {
      int u = __shfl_up(pre, o);
      if (lane >= o) pre += u;
    }
    if (lane == 63) wtot[wv] = pre;
    __syncthreads();
    int woff = 0;
#pragma unroll
    for (int ww = 0; ww < 4; ++ww)
      if (ww < wv) woff += wtot[ww];
    int excl = woff + pre - c;
    int* outp = nbr + (size_t)row * MAXD;
    int col0 = tid * 16, k = 0;
#pragma unroll
    for (int i = 0; i < 16; ++i) {
      if ((mask >> i) & 1) {
        int p = excl + k;
        if (p < MAXD) outp[p] = col0 + i;
        ++k;
      }
    }
    if (tid == 0) {
      int total = wtot[0] + wtot[1] + wtot[2] + wtot[3];
      cnt[row] = total < MAXD ? total : MAXD;
    }
    return;
  }

  // ---------------- GEMM tile ----------------
  const int mtile = bx & 63, npair = bx >> 6;
  const int wm = w >> 1, wn = w & 1;
  const int ml = lane & 31, g = lane >> 5, g8 = g * 8;

  f32x16 acc0, acc1;
#pragma unroll
  for (int r = 0; r < 16; ++r) { acc0[r] = 0.f; acc1[r] = 0.f; }

  const short* Abh = Ahi + (((size_t)mtile * 64) << 9);
  const short* Abl = Alo + (((size_t)mtile * 64) << 9);
  const short* Bbh = Bhi + (((size_t)npair * 128) << 9);
  const short* Bbl = Blo + (((size_t)npair * 128) << 9);

  const int tn = tid >> 3, k8 = tid & 7;
  const int ks = k8 >> 1, ko = (k8 & 1) * 8;
  const size_t so = ((size_t)tn << 9) + (size_t)k8 * 8;

  int4 rah0, rah1, ral0, ral1, rbh0, rbh1, rbh2, rbh3, rbl0, rbl1, rbl2, rbl3;
  {
    rah0 = *(const int4*)(Abh + so);              ral0 = *(const int4*)(Abl + so);
    rah1 = *(const int4*)(Abh + so + (32 << 9));  ral1 = *(const int4*)(Abl + so + (32 << 9));
    rbh0 = *(const int4*)(Bbh + so);              rbl0 = *(const int4*)(Bbl + so);
    rbh1 = *(const int4*)(Bbh + so + (32 << 9));  rbl1 = *(const int4*)(Bbl + so + (32 << 9));
    rbh2 = *(const int4*)(Bbh + so + (64 << 9));  rbl2 = *(const int4*)(Bbl + so + (64 << 9));
    rbh3 = *(const int4*)(Bbh + so + (96 << 9));  rbl3 = *(const int4*)(Bbl + so + (96 << 9));
  }

  const int NCH = FDIM / 64;   // 8 chunks
  for (int c = 0; c < NCH; ++c) {
    *(int4*)&AH[ks][tn][ko] = rah0;       *(int4*)&AL[ks][tn][ko] = ral0;
    *(int4*)&AH[ks][32 + tn][ko] = rah1;  *(int4*)&AL[ks][32 + tn][ko] = ral1;
    *(int4*)&BH[ks][tn][ko] = rbh0;       *(int4*)&BL[ks][tn][ko] = rbl0;
    *(int4*)&BH[ks][32 + tn][ko] = rbh1;  *(int4*)&BL[ks][32 + tn][ko] = rbl1;
    *(int4*)&BH[ks][64 + tn][ko] = rbh2;  *(int4*)&BL[ks][64 + tn][ko] = rbl2;
    *(int4*)&BH[ks][96 + tn][ko] = rbh3;  *(int4*)&BL[ks][96 + tn][ko] = rbl3;
    __syncthreads();
    if (c + 1 < NCH) {
      size_t o = so + (size_t)(c + 1) * 64;
      rah0 = *(const int4*)(Abh + o);              ral0 = *(const int4*)(Abl + o);
      rah1 = *(const int4*)(Abh + o + (32 << 9));  ral1 = *(const int4*)(Abl + o + (32 << 9));
      rbh0 = *(const int4*)(Bbh + o);              rbl0 = *(const int4*)(Bbl + o);
      rbh1 = *(const int4*)(Bbh + o + (32 << 9));  rbl1 = *(const int4*)(Bbl + o + (32 << 9));
      rbh2 = *(const int4*)(Bbh + o + (64 << 9));  rbl2 = *(const int4*)(Bbl + o + (64 << 9));
      rbh3 = *(const int4*)(Bbh + o + (96 << 9));  rbl3 = *(const int4*)(Bbl + o + (96 << 9));
    }
#pragma unroll
    for (int t = 0; t < 4; ++t) {
      bf16x8 ah = *(const bf16x8*)&AH[t][wm * 32 + ml][g8];
      bf16x8 al = *(const bf16x8*)&AL[t][wm * 32 + ml][g8];
      bf16x8 bh0 = *(const bf16x8*)&BH[t][wn * 64 + ml][g8];
      bf16x8 bl0 = *(const bf16x8*)&BL[t][wn * 64 + ml][g8];
      acc0 = __builtin_amdgcn_mfma_f32_32x32x16_bf16(ah, bh0, acc0, 0, 0, 0);
      acc0 = __builtin_amdgcn_mfma_f32_32x32x16_bf16(al, bh0, acc0, 0, 0, 0);
      acc0 = __builtin_amdgcn_mfma_f32_32x32x16_bf16(ah, bl0, acc0, 0, 0, 0);
      bf16x8 bh1 = *(const bf16x8*)&BH[t][wn * 64 + 32 + ml][g8];
      bf16x8 bl1 = *(const bf16x8*)&BL[t][wn * 64 + 32 + ml][g8];
      acc1 = __builtin_amdgcn_mfma_f32_32x32x16_bf16(ah, bh1, acc1, 0, 0, 0);
      acc1 = __builtin_amdgcn_mfma_f32_32x32x16_bf16(al, bh1, acc1, 0, 0, 0);
      acc1 = __builtin_amdgcn_mfma_f32_32x32x16_bf16(ah, bl1, acc1, 0, 0, 0);
    }
    __syncthreads();
  }

  // epilogue: C layout col=lane&31, row=(r&3)+8*(r>>2)+4*(lane>>5)
  const int h = npair * 2 + wn;
  const float a1lo = a1[h * 64 + ml], a1hi = a1[h * 64 + 32 + ml];
  const float a2lo = a2[h * 64 + ml], a2hi = a2[h * 64 + 32 + ml];
  const float b1h = b1[h], b2h = b2[h];
  const int row0 = mtile * 64 + wm * 32 + 4 * g;
  const int col0 = npair * 128 + wn * 64 + ml;
#pragma unroll
  for (int r = 0; r < 16; ++r) {
    int row = row0 + (r & 3) + 8 * (r >> 2);
    FTSb[(size_t)row * FDIM + col0] = (short)f2bf(acc0[r]);
    FTSb[(size_t)row * FDIM + col0 + 32] = (short)f2bf(acc1[r]);
    float p1 = acc0[r] * a1lo + acc1[r] * a1hi;
    float p2 = acc0[r] * a2lo + acc1[r] * a2hi;
#pragma unroll
    for (int o = 1; o < 32; o <<= 1) {
      p1 += __shfl_xor(p1, o);
      p2 += __shfl_xor(p2, o);
    }
    if (ml == 0) {
      F1t[(size_t)row * 8 + h] = p1 + b1h;
      F2t[(size_t)row * 8 + h] = p2 + b2h;
    }
  }
}

// ---------------- Kernel 3: sparse softmax + aggregation (4 heads/wave) -----
// bf16 gather with 4-deep ILP.
__global__ __launch_bounds__(256) void k_agg1(
    const short* __restrict__ FTSb, const float* __restrict__ F1t,
    const float* __restrict__ F2t, const int* __restrict__ nbr,
    const int* __restrict__ cnt, short* __restrict__ VALShi,
    short* __restrict__ VALSlo) {
  __shared__ float plds[4][MAXD][4];   // [wave][slot][head-q] = 16 KB
  int wv = threadIdx.x >> 6, lane = threadIdx.x & 63;
  int gw = blockIdx.x * 4 + wv;     // over NN*2
  int i = gw >> 1, hg = gw & 1;
  int deg = cnt[i];
  const int* nb = nbr + (size_t)i * MAXD;
  float4 f1v = *(const float4*)(F1t + (size_t)i * 8 + hg * 4);

  float4 p4[4];
  int jreg[4];
  float mx = -1e30f, my = -1e30f, mz = -1e30f, mw = -1e30f;
#pragma unroll
  for (int r = 0; r < 4; ++r) {
    int t = r * 64 + lane;
    jreg[r] = 0;
    p4[r] = make_float4(-1e30f, -1e30f, -1e30f, -1e30f);
    if (t < deg) {
      int j = nb[t];
      jreg[r] = j;
      float4 f2v = *(const float4*)(F2t + (size_t)j * 8 + hg * 4);
      float4 x;
      x.x = f1v.x + f2v.x; x.x = x.x >= 0.f ? x.x : 0.2f * x.x;
      x.y = f1v.y + f2v.y; x.y = x.y >= 0.f ? x.y : 0.2f * x.y;
      x.z = f1v.z + f2v.z; x.z = x.z >= 0.f ? x.z : 0.2f * x.z;
      x.w = f1v.w + f2v.w; x.w = x.w >= 0.f ? x.w : 0.2f * x.w;
      p4[r] = x;
      mx = fmaxf(mx, x.x); my = fmaxf(my, x.y);
      mz = fmaxf(mz, x.z); mw = fmaxf(mw, x.w);
    }
  }
  mx = wave_max64(mx); my = wave_max64(my);
  mz = wave_max64(mz); mw = wave_max64(mw);
  float sx = 0.f, sy = 0.f, sz = 0.f, sw = 0.f;
#pragma unroll
  for (int r = 0; r < 4; ++r) {
    int t = r * 64 + lane;
    float4 e = make_float4(0.f, 0.f, 0.f, 0.f);
    if (t < deg) {
      e.x = __expf(p4[r].x - mx); e.y = __expf(p4[r].y - my);
      e.z = __expf(p4[r].z - mz); e.w = __expf(p4[r].w - mw);
    }
    p4[r] = e;
    sx += e.x; sy += e.y; sz += e.z; sw += e.w;
    *(float4*)&plds[wv][r * 64 + lane][0] = e;
  }
  sx = wave_sum64(sx); sy = wave_sum64(sy);
  sz = wave_sum64(sz); sw = wave_sum64(sw);

  int q = lane >> 4;
  float invh = (q < 2) ? (q == 0 ? 1.f / sx : 1.f / sy)
                       : (q == 2 ? 1.f / sz : 1.f / sw);

  float4 accA = make_float4(0.f, 0.f, 0.f, 0.f);
  float4 accB = make_float4(0.f, 0.f, 0.f, 0.f);
  float4 accC = make_float4(0.f, 0.f, 0.f, 0.f);
  float4 accD = make_float4(0.f, 0.f, 0.f, 0.f);
  const short* Fb = FTSb + hg * 256;
#pragma unroll
  for (int r = 0; r < 4; ++r) {
    int base = r * 64;
    if (base >= deg) break;
    int lim = deg - base;
    lim = lim < 64 ? lim : 64;
    int sl = 0;
    for (; sl + 4 <= lim; sl += 4) {
      int j0 = readlane_i(jreg[r], sl);
      int j1 = readlane_i(jreg[r], sl + 1);
      int j2 = readlane_i(jreg[r], sl + 2);
      int j3 = readlane_i(jreg[r], sl + 3);
      float wA = plds[wv][base + sl][q];
      float wB = plds[wv][base + sl + 1][q];
      float wC = plds[wv][base + sl + 2][q];
      float wD = plds[wv][base + sl + 3][q];
      short4 s0 = *(const short4*)(Fb + (size_t)j0 * FDIM + lane * 4);
      short4 s1 = *(const short4*)(Fb + (size_t)j1 * FDIM + lane * 4);
      short4 s2 = *(const short4*)(Fb + (size_t)j2 * FDIM + lane * 4);
      short4 s3 = *(const short4*)(Fb + (size_t)j3 * FDIM + lane * 4);
      accA.x += wA * bf2f((unsigned short)s0.x); accA.y += wA * bf2f((unsigned short)s0.y);
      accA.z += wA * bf2f((unsigned short)s0.z); accA.w += wA * bf2f((unsigned short)s0.w);
      accB.x += wB * bf2f((unsigned short)s1.x); accB.y += wB * bf2f((unsigned short)s1.y);
      accB.z += wB * bf2f((unsigned short)s1.z); accB.w += wB * bf2f((unsigned short)s1.w);
      accC.x += wC * bf2f((unsigned short)s2.x); accC.y += wC * bf2f((unsigned short)s2.y);
      accC.z += wC * bf2f((unsigned short)s2.z); accC.w += wC * bf2f((unsigned short)s2.w);
      accD.x += wD * bf2f((unsigned short)s3.x); accD.y += wD * bf2f((unsigned short)s3.y);
      accD.z += wD * bf2f((unsigned short)s3.z); accD.w += wD * bf2f((unsigned short)s3.w);
    }
    for (; sl < lim; ++sl) {
      int j0 = readlane_i(jreg[r], sl);
      float wA = plds[wv][base + sl][q];
      short4 s0 = *(const short4*)(Fb + (size_t)j0 * FDIM + lane * 4);
      accA.x += wA * bf2f((unsigned short)s0.x); accA.y += wA * bf2f((unsigned short)s0.y);
      accA.z += wA * bf2f((unsigned short)s0.z); accA.w += wA * bf2f((unsigned short)s0.w);
    }
  }
  float vx = (accA.x + accB.x + accC.x + accD.x) * invh;
  float vy = (accA.y + accB.y + accC.y + accD.y) * invh;
  float vz = (accA.z + accB.z + accC.z + accD.z) * invh;
  float vw = (accA.w + accB.w + accC.w + accD.w) * invh;
  unsigned short hx = f2bf(vx), hy = f2bf(vy), hz = f2bf(vz), hw = f2bf(vw);
  size_t o = (size_t)i * FDIM + hg * 256 + lane * 4;
  *(short4*)(VALShi + o) = make_short4((short)hx, (short)hy, (short)hz, (short)hw);
  *(short4*)(VALSlo + o) = make_short4(
      (short)f2bf(vx - bf2f(hx)), (short)f2bf(vy - bf2f(hy)),
      (short)f2bf(vz - bf2f(hz)), (short)f2bf(vw - bf2f(hw)));
}

// ---------------- Kernel 4: fused tail: H1 = elu(VALS@W2+bW); FTS2 = H1@Wo1 -
__global__ __launch_bounds__(256) void k_tail(
    const short* __restrict__ VALShi, const short* __restrict__ VALSlo,
    const short* __restrict__ W2thi, const short* __restrict__ W2tlo,
    const float* __restrict__ bW,
    const short* __restrict__ Wo1thi, const short* __restrict__ Wo1tlo,
    const float* __restrict__ ao1, const float* __restrict__ bo1s,
    const float* __restrict__ ao2, const float* __restrict__ bo2s,
    float* __restrict__ FTS2, float* __restrict__ F1O, float* __restrict__ F2O) {
  __shared__ short AH[4][64][16], AL[4][64][16];   // VALS tile (A of W2 mfma)
  __shared__ short BH[4][64][16], BL[4][64][16];   // W2t[h]    (B of W2 mfma)
  __shared__ short CH[4][64][16], CL[4][64][16];   // H1_h      (A of fts2 mfma)
  __shared__ short DH[4][64][16], DL[4][64][16];   // Wo1t[h]   (B of fts2 mfma)
  __shared__ float p1buf[2][64], p2buf[2][64];
  const int i0 = blockIdx.x * 64;
  const int tid = threadIdx.x, lane = tid & 63, w = tid >> 6;
  const int wm = w >> 1, wn = w & 1;
  const int ml = lane & 31, g = lane >> 5, g8 = g * 8;
  const int tn = tid >> 2, k8 = tid & 3;
  const int colw = wn * 32 + ml;
  const int rowl0 = wm * 32 + 4 * g;

  f32x16 acc2;
#pragma unroll
  for (int r = 0; r < 16; ++r) acc2[r] = 0.f;

  for (int h = 0; h < NHEAD; ++h) {
    {
      const short* pa = VALShi + ((size_t)(i0 + tn) << 9) + h * 64 + k8 * 16;
      const short* pl = VALSlo + ((size_t)(i0 + tn) << 9) + h * 64 + k8 * 16;
      *(int4*)&AH[k8][tn][0] = *(const int4*)pa;
      *(int4*)&AH[k8][tn][8] = *(const int4*)(pa + 8);
      *(int4*)&AL[k8][tn][0] = *(const int4*)pl;
      *(int4*)&AL[k8][tn][8] = *(const int4*)(pl + 8);
      const short* pb  = W2thi + (size_t)h * 4096 + tn * 64 + k8 * 16;
      const short* pbl = W2tlo + (size_t)h * 4096 + tn * 64 + k8 * 16;
      *(int4*)&BH[k8][tn][0] = *(const int4*)pb;
      *(int4*)&BH[k8][tn][8] = *(const int4*)(pb + 8);
      *(int4*)&BL[k8][tn][0] = *(const int4*)pbl;
      *(int4*)&BL[k8][tn][8] = *(const int4*)(pbl + 8);
      const short* pd  = Wo1thi + (size_t)tn * FDIM + h * 64 + k8 * 16;
      const short* pdl = Wo1tlo + (size_t)tn * FDIM + h * 64 + k8 * 16;
      *(int4*)&DH[k8][tn][0] = *(const int4*)pd;
      *(int4*)&DH[k8][tn][8] = *(const int4*)(pd + 8);
      *(int4*)&DL[k8][tn][0] = *(const int4*)pdl;
      *(int4*)&DL[k8][tn][8] = *(const int4*)(pdl + 8);
    }
    __syncthreads();
    // W2 MFMA (K=64)
    f32x16 accw;
#pragma unroll
    for (int r = 0; r < 16; ++r) accw[r] = 0.f;
#pragma unroll
    for (int t = 0; t < 4; ++t) {
      bf16x8 ah = *(const bf16x8*)&AH[t][wm * 32 + ml][g8];
      bf16x8 al = *(const bf16x8*)&AL[t][wm * 32 + ml][g8];
      bf16x8 bh = *(const bf16x8*)&BH[t][wn * 32 + ml][g8];
      bf16x8 bl = *(const bf16x8*)&BL[t][wn * 32 + ml][g8];
      accw = __builtin_amdgcn_mfma_f32_32x32x16_bf16(ah, bh, accw, 0, 0, 0);
      accw = __builtin_amdgcn_mfma_f32_32x32x16_bf16(al, bh, accw, 0, 0, 0);
      accw = __builtin_amdgcn_mfma_f32_32x32x16_bf16(ah, bl, accw, 0, 0, 0);
    }
    const float bwv = bW[h * 64 + colw];
    const int ts = colw >> 4, ss = colw & 15;
#pragma unroll
    for (int r = 0; r < 16; ++r) {
      int rl = rowl0 + (r & 3) + 8 * (r >> 2);
      float v = accw[r] + bwv;
      v = v > 0.f ? v : __expf(v) - 1.f;
      unsigned short hv = f2bf(v);
      CH[ts][rl][ss] = (short)hv;
      CL[ts][rl][ss] = (short)f2bf(v - bf2f(hv));
    }
    __syncthreads();
#pragma unroll
    for (int t = 0; t < 4; ++t) {
      bf16x8 ah = *(const bf16x8*)&CH[t][wm * 32 + ml][g8];
      bf16x8 al = *(const bf16x8*)&CL[t][wm * 32 + ml][g8];
      bf16x8 bh = *(const bf16x8*)&DH[t][wn * 32 + ml][g8];
      bf16x8 bl = *(const bf16x8*)&DL[t][wn * 32 + ml][g8];
      acc2 = __builtin_amdgcn_mfma_f32_32x32x16_bf16(ah, bh, acc2, 0, 0, 0);
      acc2 = __builtin_amdgcn_mfma_f32_32x32x16_bf16(al, bh, acc2, 0, 0, 0);
      acc2 = __builtin_amdgcn_mfma_f32_32x32x16_bf16(ah, bl, acc2, 0, 0, 0);
    }
    __syncthreads();
  }

  // epilogue: FTS2 + f1o/f2o
  const bool act = colw < CDIM;
  const float aov1 = act ? ao1[colw] : 0.f;
  const float aov2 = act ? ao2[colw] : 0.f;
#pragma unroll
  for (int r = 0; r < 16; ++r) {
    int rl = rowl0 + (r & 3) + 8 * (r >> 2);
    float v = acc2[r];
    if (act) FTS2[(size_t)(i0 + rl) * CDIM + colw] = v;
    float p1 = v * aov1, p2 = v * aov2;
#pragma unroll
    for (int o = 1; o < 32; o <<= 1) {
      p1 += __shfl_xor(p1, o);
      p2 += __shfl_xor(p2, o);
    }
    if (ml == 0) {
      p1buf[wn][rl] = p1;
      p2buf[wn][rl] = p2;
    }
  }
  __syncthreads();
  if (tid < 64) {
    F1O[i0 + tid] = p1buf[0][tid] + p1buf[1][tid] + bo1s[0];
    F2O[i0 + tid] = p2buf[0][tid] + p2buf[1][tid] + bo2s[0];
  }
}

// ---------------- Kernel 5: layer-2 attention + output GEMM (fused) ---------
__global__ __launch_bounds__(256) void k_agg2(
    const float* __restrict__ FTS2, const float* __restrict__ F1O,
    const float* __restrict__ F2O, const int* __restrict__ nbr,
    const int* __restrict__ cnt, const float* __restrict__ Wo2,
    const float* __restrict__ bo, float* __restrict__ out) {
  int i = blockIdx.x * 4 + (threadIdx.x >> 6);
  int lane = threadIdx.x & 63;
  int deg = cnt[i];
  const int* nb = nbr + (size_t)i * MAXD;
  float f1i = F1O[i];

  int jreg[4];
  float p[4];
  float m = -1e30f;
#pragma unroll
  for (int r = 0; r < 4; ++r) { jreg[r] = 0; p[r] = -1e30f; }
#pragma unroll
  for (int r = 0; r < 4; ++r) {
    int t = r * 64 + lane;
    if (t < deg) {
      int j = nb[t];
      jreg[r] = j;
      float x = f1i + F2O[j];
      x = x >= 0.f ? x : 0.2f * x;
      p[r] = x;
      m = fmaxf(m, x);
    }
  }
  m = wave_max64(m);
  float s = 0.f;
#pragma unroll
  for (int r = 0; r < 4; ++r) {
    int t = r * 64 + lane;
    float e = (t < deg) ? __expf(p[r] - m) : 0.f;
    p[r] = e;
    s += e;
  }
  s = wave_sum64(s);

  const bool act = lane < CDIM;
  float accA = 0.f, accB = 0.f, accC = 0.f, accD = 0.f;
#pragma unroll
  for (int r = 0; r < 4; ++r) {
    int base = r * 64;
    if (base >= deg) break;
    int lim = deg - base;
    lim = lim < 64 ? lim : 64;
    int sl = 0;
    for (; sl + 4 <= lim; sl += 4) {
      float w0 = readlane_f(p[r], sl);
      float w1 = readlane_f(p[r], sl + 1);
      float w2 = readlane_f(p[r], sl + 2);
      float w3 = readlane_f(p[r], sl + 3);
      int j0 = readlane_i(jreg[r], sl);
      int j1 = readlane_i(jreg[r], sl + 1);
      int j2 = readlane_i(jreg[r], sl + 2);
      int j3 = readlane_i(jreg[r], sl + 3);
      float f0 = act ? FTS2[(size_t)j0 * CDIM + lane] : 0.f;
      float f1 = act ? FTS2[(size_t)j1 * CDIM + lane] : 0.f;
      float f2 = act ? FTS2[(size_t)j2 * CDIM + lane] : 0.f;
      float f3 = act ? FTS2[(size_t)j3 * CDIM + lane] : 0.f;
      accA += w0 * f0;
      accB += w1 * f1;
      accC += w2 * f2;
      accD += w3 * f3;
    }
    for (; sl < lim; ++sl) {
      float w0 = readlane_f(p[r], sl);
      int j0 = readlane_i(jreg[r], sl);
      float f0 = act ? FTS2[(size_t)j0 * CDIM + lane] : 0.f;
      accA += w0 * f0;
    }
  }
  float v = (accA + accB + accC + accD) / s;

  float o = act ? bo[lane] : 0.f;
  for (int kk = 0; kk < CDIM; ++kk) {
    float w = readlane_f(v, kk);
    float b = act ? Wo2[kk * CDIM + lane] : 0.f;
    o += w * b;
  }
  if (act) out[(size_t)i * CDIM + lane] = o;
}

extern "C" void kernel_launch(void* const* d_in, const int* in_sizes, int n_in,
                              void* d_out, int out_size, void* d_ws, size_t ws_size,
                              hipStream_t stream) {
  const float* seq  = (const float*)d_in[0];
  const float* bias = (const float*)d_in[1];
  const float* W1   = (const float*)d_in[2];
  const float* a1   = (const float*)d_in[3];
  const float* b1   = (const float*)d_in[4];
  const float* a2   = (const float*)d_in[5];
  const float* b2   = (const float*)d_in[6];
  const float* W2   = (const float*)d_in[7];
  const float* bW   = (const float*)d_in[8];
  const float* Wo1  = (const float*)d_in[9];
  const float* ao1  = (const float*)d_in[10];
  const float* bo1  = (const float*)d_in[11];
  const float* ao2  = (const float*)d_in[12];
  const float* bo2  = (const float*)d_in[13];
  const float* Wo2  = (const float*)d_in[14];
  const float* bo   = (const float*)d_in[15];
  float* out = (float*)d_out;

  float* ws    = (float*)d_ws;
  float* F1t   = ws;                          // N*8
  float* F2t   = F1t  + (size_t)NN * NHEAD;   // N*8
  float* FTS2  = F2t  + (size_t)NN * NHEAD;   // N*40
  float* F1O   = FTS2 + (size_t)NN * CDIM;    // N
  float* F2O   = F1O  + NN;                   // N
  short* FTSb  = (short*)(F2O + NN);          // N*512 bf16
  short* Ahi   = FTSb + (size_t)NN * FDIM;    // N*512 bf16
  short* Alo   = Ahi + (size_t)NN * FDIM;
  short* Bhi   = Alo + (size_t)NN * FDIM;     // 8*64*512
  short* Blo   = Bhi + (size_t)NHEAD * HDIM * FDIM;
  short* VALShi= Blo + (size_t)NHEAD * HDIM * FDIM;  // N*512
  short* VALSlo= VALShi + (size_t)NN * FDIM;
  short* W2thi = VALSlo + (size_t)NN * FDIM;         // 8*64*64
  short* W2tlo = W2thi + (size_t)NHEAD * HDIM * HDIM;
  short* Wo1thi= W2tlo + (size_t)NHEAD * HDIM * HDIM; // 64*512
  short* Wo1tlo= Wo1thi + (size_t)64 * FDIM;
  int*   nbr   = (int*)(Wo1tlo + (size_t)64 * FDIM);  // N*MAXD
  int*   cnt   = nbr + (size_t)NN * MAXD;     // N

  // 1. input/weight conversions (CSR moved into kernel 2)
  k_prep<<<1024 + 64 + 8 + 8, 256, 0, stream>>>(
      seq, Ahi, Alo, W1, Bhi, Blo, W2, W2thi, W2tlo, Wo1, Wo1thi, Wo1tlo);
  // 2. MFMA hi/lo GEMM + fused f1/f2  ∥  CSR build (co-scheduled)
  k_gemm<<<256 + NN, 256, 0, stream>>>(
      Ahi, Alo, Bhi, Blo, a1, b1, a2, b2, FTSb, F1t, F2t, bias, nbr, cnt);
  // 3. sparse softmax + aggregation (bf16 gather, ILP4) -> VALS bf16 hi/lo
  k_agg1<<<NN * 2 / 4, 256, 0, stream>>>(FTSb, F1t, F2t, nbr, cnt, VALShi, VALSlo);
  // 4. fused W2+elu+fts2 MFMA tail
  k_tail<<<NN / 64, 256, 0, stream>>>(VALShi, VALSlo, W2thi, W2tlo, bW,
                                      Wo1thi, Wo1tlo, ao1, bo1, ao2, bo2,
                                      FTS2, F1O, F2O);
  // 5. layer-2 sparse attention + final dense + bias (ILP4)
  k_agg2<<<NN / 4, 256, 0, stream>>>(FTS2, F1O, F2O, nbr, cnt, Wo2, bo, out);
}

// Round 14
// 85.004 us; speedup vs baseline: 3.1742x; 1.0270x over previous
//
#include <hip/hip_runtime.h>
#include <cstdint>
#include <cstddef>

#define NN 4096
#define FDIM 512
#define HDIM 64
#define NHEAD 8
#define CDIM 40
#define MAXD 256   // max neighbors kept per row (~41 expected)

typedef __attribute__((ext_vector_type(8))) short bf16x8;
typedef __attribute__((ext_vector_type(16))) float f32x16;

__device__ __forceinline__ float wave_max64(float v) {
  for (int o = 32; o; o >>= 1) v = fmaxf(v, __shfl_xor(v, o));
  return v;
}
__device__ __forceinline__ float wave_sum64(float v) {
  for (int o = 32; o; o >>= 1) v += __shfl_xor(v, o);
  return v;
}
__device__ __forceinline__ float readlane_f(float v, int sl) {
  return __uint_as_float((unsigned)__builtin_amdgcn_readlane((int)__float_as_uint(v), sl));
}
__device__ __forceinline__ int readlane_i(int v, int sl) {
  return __builtin_amdgcn_readlane(v, sl);
}
// fp32 -> bf16 (RNE) and back, via bit ops
__device__ __forceinline__ unsigned short f2bf(float x) {
  unsigned u = __float_as_uint(x);
  return (unsigned short)((u + 0x7fffu + ((u >> 16) & 1u)) >> 16);
}
__device__ __forceinline__ float bf2f(unsigned short b) {
  return __uint_as_float(((unsigned)b) << 16);
}
// unpack packed bf16 pair (int) -> floats
__device__ __forceinline__ float lo16f(int u) { return __int_as_float(u << 16); }
__device__ __forceinline__ float hi16f(int u) { return __int_as_float(u & 0xffff0000); }
// 8 fp32 -> 8 bf16 hi + 8 bf16 lo, packed
__device__ __forceinline__ void cvt8(const float4& a, const float4& b,
                                     int4& hi, int4& lo) {
  unsigned short h0 = f2bf(a.x), h1 = f2bf(a.y), h2 = f2bf(a.z), h3 = f2bf(a.w);
  unsigned short h4 = f2bf(b.x), h5 = f2bf(b.y), h6 = f2bf(b.z), h7 = f2bf(b.w);
  hi = make_int4((int)((unsigned)h0 | ((unsigned)h1 << 16)),
                 (int)((unsigned)h2 | ((unsigned)h3 << 16)),
                 (int)((unsigned)h4 | ((unsigned)h5 << 16)),
                 (int)((unsigned)h6 | ((unsigned)h7 << 16)));
  unsigned short l0 = f2bf(a.x - bf2f(h0)), l1 = f2bf(a.y - bf2f(h1));
  unsigned short l2 = f2bf(a.z - bf2f(h2)), l3 = f2bf(a.w - bf2f(h3));
  unsigned short l4 = f2bf(b.x - bf2f(h4)), l5 = f2bf(b.y - bf2f(h5));
  unsigned short l6 = f2bf(b.z - bf2f(h6)), l7 = f2bf(b.w - bf2f(h7));
  lo = make_int4((int)((unsigned)l0 | ((unsigned)l1 << 16)),
                 (int)((unsigned)l2 | ((unsigned)l3 << 16)),
                 (int)((unsigned)l4 | ((unsigned)l5 << 16)),
                 (int)((unsigned)l6 | ((unsigned)l7 << 16)));
}

// ---------------- Kernel 1: prep (weight conversions only) -----------------
// Grid = 64 W1 + 8 W2t + 8 Wo1t = 80 blocks.
__global__ __launch_bounds__(256) void k_prep(
    const float* __restrict__ W1, short* __restrict__ Bhi, short* __restrict__ Blo,
    const float* __restrict__ W2, short* __restrict__ W2thi, short* __restrict__ W2tlo,
    const float* __restrict__ Wo1, short* __restrict__ Wo1thi, short* __restrict__ Wo1tlo) {
  __shared__ float T[64][65];
  int bx = blockIdx.x, tid = threadIdx.x;
  if (bx < 64) {       // ---- W1 tile transpose + bf16 hi/lo: [k][n] -> [n][k]
    int h = bx >> 3, kb = bx & 7;
    const float* src = W1 + ((size_t)h * FDIM + kb * 64) * HDIM;
#pragma unroll
    for (int q = 0; q < 4; ++q) {
      int fi = q * 256 + tid, kk = fi >> 4, n4 = fi & 15;
      float4 v = *(const float4*)(src + (size_t)kk * HDIM + n4 * 4);
      T[n4 * 4 + 0][kk] = v.x; T[n4 * 4 + 1][kk] = v.y;
      T[n4 * 4 + 2][kk] = v.z; T[n4 * 4 + 3][kk] = v.w;
    }
    __syncthreads();
#pragma unroll
    for (int q = 0; q < 4; ++q) {
      int fi = q * 256 + tid, n = fi >> 4, k4 = fi & 15;
      float a = T[n][k4 * 4], b = T[n][k4 * 4 + 1];
      float c = T[n][k4 * 4 + 2], d = T[n][k4 * 4 + 3];
      size_t o = ((size_t)h * 64 + n) * FDIM + kb * 64 + k4 * 4;
      unsigned short ha = f2bf(a), hb = f2bf(b), hc = f2bf(c), hd = f2bf(d);
      *(short4*)(Bhi + o) = make_short4((short)ha, (short)hb, (short)hc, (short)hd);
      *(short4*)(Blo + o) = make_short4((short)f2bf(a - bf2f(ha)), (short)f2bf(b - bf2f(hb)),
                                        (short)f2bf(c - bf2f(hc)), (short)f2bf(d - bf2f(hd)));
    }
    return;
  }
  bx -= 64;
  if (bx < 8) {        // ---- W2[h] transpose [64k][64n] -> [n][k] hi/lo
    int h = bx;
    const float* src = W2 + (size_t)h * HDIM * HDIM;
#pragma unroll
    for (int q = 0; q < 4; ++q) {
      int fi = q * 256 + tid, kk = fi >> 4, n4 = fi & 15;
      float4 v = *(const float4*)(src + (size_t)kk * HDIM + n4 * 4);
      T[n4 * 4 + 0][kk] = v.x; T[n4 * 4 + 1][kk] = v.y;
      T[n4 * 4 + 2][kk] = v.z; T[n4 * 4 + 3][kk] = v.w;
    }
    __syncthreads();
#pragma unroll
    for (int q = 0; q < 4; ++q) {
      int fi = q * 256 + tid, n = fi >> 4, k4 = fi & 15;
      float a = T[n][k4 * 4], b = T[n][k4 * 4 + 1];
      float c = T[n][k4 * 4 + 2], d = T[n][k4 * 4 + 3];
      size_t o = (size_t)h * 4096 + (size_t)n * 64 + k4 * 4;
      unsigned short ha = f2bf(a), hb = f2bf(b), hc = f2bf(c), hd = f2bf(d);
      *(short4*)(W2thi + o) = make_short4((short)ha, (short)hb, (short)hc, (short)hd);
      *(short4*)(W2tlo + o) = make_short4((short)f2bf(a - bf2f(ha)), (short)f2bf(b - bf2f(hb)),
                                          (short)f2bf(c - bf2f(hc)), (short)f2bf(d - bf2f(hd)));
    }
    return;
  }
  bx -= 8;
  {                    // ---- Wo1 transpose+pad [512][40] -> [64][512] hi/lo
#pragma unroll
    for (int q = 0; q < 16; ++q) {
      int idx = q * 256 + tid;          // 0..4095
      int n = bx * 8 + (idx >> 9), k = idx & 511;
      float v = (n < CDIM) ? Wo1[(size_t)k * CDIM + n] : 0.f;
      unsigned short hv = f2bf(v);
      Wo1thi[(size_t)n * FDIM + k] = (short)hv;
      Wo1tlo[(size_t)n * FDIM + k] = (short)f2bf(v - bf2f(hv));
    }
  }
}

// ---------------- Kernel 2: MFMA GEMM (in-reg seq cvt) + f1/f2  ∥  CSR -----
__global__ __launch_bounds__(256) void k_gemm(
    const float* __restrict__ seq,
    const short* __restrict__ Bhi, const short* __restrict__ Blo,
    const float* __restrict__ a1, const float* __restrict__ b1,
    const float* __restrict__ a2, const float* __restrict__ b2,
    short* __restrict__ FTSb, float* __restrict__ F1t, float* __restrict__ F2t,
    const float* __restrict__ bias, int* __restrict__ nbr, int* __restrict__ cnt) {
  __shared__ short AH[4][64][16], AL[4][64][16];    // [kstep16][m][k-slot]
  __shared__ short BH[4][128][16], BL[4][128][16];  // [kstep16][n][k-slot]
  __shared__ int wtot[4];
  const int bx = blockIdx.x;
  const int tid = threadIdx.x, lane = tid & 63, w = tid >> 6;

  if (bx >= 256) {     // ---------------- CSR: one block per row ------------
    int row = bx - 256;
    int wv = w;
    const float4* r = (const float4*)(bias + (size_t)row * NN);
    unsigned mask = 0;
#pragma unroll
    for (int i = 0; i < 4; ++i) {
      float4 v = r[tid * 4 + i];
      mask |= (unsigned)((v.x == 0.f ? 1 : 0) | (v.y == 0.f ? 2 : 0) |
                         (v.z == 0.f ? 4 : 0) | (v.w == 0.f ? 8 : 0)) << (i * 4);
    }
    int c = __popc(mask);
    int pre = c;
#pragma unroll
    for (int o = 1; o < 64; o <<= 1) {
      int u = __shfl_up(pre, o);
      if (lane >= o) pre += u;
    }
    if (lane == 63) wtot[wv] = pre;
    __syncthreads();
    int woff = 0;
#pragma unroll
    for (int ww = 0; ww < 4; ++ww)
      if (ww < wv) woff += wtot[ww];
    int excl = woff + pre - c;
    int* outp = nbr + (size_t)row * MAXD;
    int col0 = tid * 16, k = 0;
#pragma unroll
    for (int i = 0; i < 16; ++i) {
      if ((mask >> i) & 1) {
        int p = excl + k;
        if (p < MAXD) outp[p] = col0 + i;
        ++k;
      }
    }
    if (tid == 0) {
      int total = wtot[0] + wtot[1] + wtot[2] + wtot[3];
      cnt[row] = total < MAXD ? total : MAXD;
    }
    return;
  }

  // ---------------- GEMM tile ----------------
  const int mtile = bx & 63, npair = bx >> 6;
  const int wm = w >> 1, wn = w & 1;
  const int ml = lane & 31, g = lane >> 5, g8 = g * 8;

  f32x16 acc0, acc1;
#pragma unroll
  for (int r = 0; r < 16; ++r) { acc0[r] = 0.f; acc1[r] = 0.f; }

  const short* Bbh = Bhi + (((size_t)npair * 128) << 9);
  const short* Bbl = Blo + (((size_t)npair * 128) << 9);

  const int tn = tid >> 3, k8 = tid & 7;
  const int ks = k8 >> 1, ko = (k8 & 1) * 8;
  const size_t so = ((size_t)tn << 9) + (size_t)k8 * 8;
  const float* As0 = seq + (((size_t)(mtile * 64 + tn)) << 9) + k8 * 8;
  const float* As1 = As0 + ((size_t)32 << 9);

  float4 fa0a, fa0b, fa1a, fa1b;
  int4 rbh0, rbh1, rbh2, rbh3, rbl0, rbl1, rbl2, rbl3;
  {
    fa0a = *(const float4*)(As0);      fa0b = *(const float4*)(As0 + 4);
    fa1a = *(const float4*)(As1);      fa1b = *(const float4*)(As1 + 4);
    rbh0 = *(const int4*)(Bbh + so);              rbl0 = *(const int4*)(Bbl + so);
    rbh1 = *(const int4*)(Bbh + so + (32 << 9));  rbl1 = *(const int4*)(Bbl + so + (32 << 9));
    rbh2 = *(const int4*)(Bbh + so + (64 << 9));  rbl2 = *(const int4*)(Bbl + so + (64 << 9));
    rbh3 = *(const int4*)(Bbh + so + (96 << 9));  rbl3 = *(const int4*)(Bbl + so + (96 << 9));
  }

  const int NCH = FDIM / 64;   // 8 chunks
  for (int c = 0; c < NCH; ++c) {
    {
      int4 hi0, lo0, hi1, lo1;
      cvt8(fa0a, fa0b, hi0, lo0);
      cvt8(fa1a, fa1b, hi1, lo1);
      *(int4*)&AH[ks][tn][ko] = hi0;       *(int4*)&AL[ks][tn][ko] = lo0;
      *(int4*)&AH[ks][32 + tn][ko] = hi1;  *(int4*)&AL[ks][32 + tn][ko] = lo1;
    }
    *(int4*)&BH[ks][tn][ko] = rbh0;       *(int4*)&BL[ks][tn][ko] = rbl0;
    *(int4*)&BH[ks][32 + tn][ko] = rbh1;  *(int4*)&BL[ks][32 + tn][ko] = rbl1;
    *(int4*)&BH[ks][64 + tn][ko] = rbh2;  *(int4*)&BL[ks][64 + tn][ko] = rbl2;
    *(int4*)&BH[ks][96 + tn][ko] = rbh3;  *(int4*)&BL[ks][96 + tn][ko] = rbl3;
    __syncthreads();
    if (c + 1 < NCH) {
      size_t o = so + (size_t)(c + 1) * 64;
      const float* a0 = As0 + (size_t)(c + 1) * 64;
      const float* a1p = As1 + (size_t)(c + 1) * 64;
      fa0a = *(const float4*)(a0);      fa0b = *(const float4*)(a0 + 4);
      fa1a = *(const float4*)(a1p);     fa1b = *(const float4*)(a1p + 4);
      rbh0 = *(const int4*)(Bbh + o);              rbl0 = *(const int4*)(Bbl + o);
      rbh1 = *(const int4*)(Bbh + o + (32 << 9));  rbl1 = *(const int4*)(Bbl + o + (32 << 9));
      rbh2 = *(const int4*)(Bbh + o + (64 << 9));  rbl2 = *(const int4*)(Bbl + o + (64 << 9));
      rbh3 = *(const int4*)(Bbh + o + (96 << 9));  rbl3 = *(const int4*)(Bbl + o + (96 << 9));
    }
#pragma unroll
    for (int t = 0; t < 4; ++t) {
      bf16x8 ah = *(const bf16x8*)&AH[t][wm * 32 + ml][g8];
      bf16x8 al = *(const bf16x8*)&AL[t][wm * 32 + ml][g8];
      bf16x8 bh0 = *(const bf16x8*)&BH[t][wn * 64 + ml][g8];
      bf16x8 bl0 = *(const bf16x8*)&BL[t][wn * 64 + ml][g8];
      acc0 = __builtin_amdgcn_mfma_f32_32x32x16_bf16(ah, bh0, acc0, 0, 0, 0);
      acc0 = __builtin_amdgcn_mfma_f32_32x32x16_bf16(al, bh0, acc0, 0, 0, 0);
      acc0 = __builtin_amdgcn_mfma_f32_32x32x16_bf16(ah, bl0, acc0, 0, 0, 0);
      bf16x8 bh1 = *(const bf16x8*)&BH[t][wn * 64 + 32 + ml][g8];
      bf16x8 bl1 = *(const bf16x8*)&BL[t][wn * 64 + 32 + ml][g8];
      acc1 = __builtin_amdgcn_mfma_f32_32x32x16_bf16(ah, bh1, acc1, 0, 0, 0);
      acc1 = __builtin_amdgcn_mfma_f32_32x32x16_bf16(al, bh1, acc1, 0, 0, 0);
      acc1 = __builtin_amdgcn_mfma_f32_32x32x16_bf16(ah, bl1, acc1, 0, 0, 0);
    }
    __syncthreads();
  }

  // epilogue: C layout col=lane&31, row=(r&3)+8*(r>>2)+4*(lane>>5)
  const int h = npair * 2 + wn;
  const float a1lo = a1[h * 64 + ml], a1hi = a1[h * 64 + 32 + ml];
  const float a2lo = a2[h * 64 + ml], a2hi = a2[h * 64 + 32 + ml];
  const float b1h = b1[h], b2h = b2[h];
  const int row0 = mtile * 64 + wm * 32 + 4 * g;
  const int col0 = npair * 128 + wn * 64 + ml;
#pragma unroll
  for (int r = 0; r < 16; ++r) {
    int row = row0 + (r & 3) + 8 * (r >> 2);
    FTSb[(size_t)row * FDIM + col0] = (short)f2bf(acc0[r]);
    FTSb[(size_t)row * FDIM + col0 + 32] = (short)f2bf(acc1[r]);
    float p1 = acc0[r] * a1lo + acc1[r] * a1hi;
    float p2 = acc0[r] * a2lo + acc1[r] * a2hi;
#pragma unroll
    for (int o = 1; o < 32; o <<= 1) {
      p1 += __shfl_xor(p1, o);
      p2 += __shfl_xor(p2, o);
    }
    if (ml == 0) {
      F1t[(size_t)row * 8 + h] = p1 + b1h;
      F2t[(size_t)row * 8 + h] = p2 + b2h;
    }
  }
}

// ---------------- Kernel 3: sparse softmax + aggregation (1 wave/row) -------
// All 8 heads per wave; 16B bf16 gathers (1 KB per wave-instruction).
__global__ __launch_bounds__(256) void k_agg1(
    const short* __restrict__ FTSb, const float* __restrict__ F1t,
    const float* __restrict__ F2t, const int* __restrict__ nbr,
    const int* __restrict__ cnt, short* __restrict__ VALShi,
    short* __restrict__ VALSlo) {
  __shared__ float plds[4][MAXD][8];   // [wave][slot][head] = 32 KB
  int wv = threadIdx.x >> 6, lane = threadIdx.x & 63;
  int i = blockIdx.x * 4 + wv;
  int deg = cnt[i];
  const int* nb = nbr + (size_t)i * MAXD;
  float4 f1a = *(const float4*)(F1t + (size_t)i * 8);
  float4 f1b = *(const float4*)(F1t + (size_t)i * 8 + 4);

  float4 pa[4], pb[4];
  int jreg[4];
  float m0 = -1e30f, m1 = -1e30f, m2 = -1e30f, m3 = -1e30f;
  float m4 = -1e30f, m5 = -1e30f, m6 = -1e30f, m7 = -1e30f;
#pragma unroll
  for (int r = 0; r < 4; ++r) {
    int t = r * 64 + lane;
    jreg[r] = 0;
    pa[r] = make_float4(-1e30f, -1e30f, -1e30f, -1e30f);
    pb[r] = pa[r];
    if (t < deg) {
      int j = nb[t];
      jreg[r] = j;
      float4 f2a = *(const float4*)(F2t + (size_t)j * 8);
      float4 f2b = *(const float4*)(F2t + (size_t)j * 8 + 4);
      float4 xa, xb;
      xa.x = f1a.x + f2a.x; xa.x = xa.x >= 0.f ? xa.x : 0.2f * xa.x;
      xa.y = f1a.y + f2a.y; xa.y = xa.y >= 0.f ? xa.y : 0.2f * xa.y;
      xa.z = f1a.z + f2a.z; xa.z = xa.z >= 0.f ? xa.z : 0.2f * xa.z;
      xa.w = f1a.w + f2a.w; xa.w = xa.w >= 0.f ? xa.w : 0.2f * xa.w;
      xb.x = f1b.x + f2b.x; xb.x = xb.x >= 0.f ? xb.x : 0.2f * xb.x;
      xb.y = f1b.y + f2b.y; xb.y = xb.y >= 0.f ? xb.y : 0.2f * xb.y;
      xb.z = f1b.z + f2b.z; xb.z = xb.z >= 0.f ? xb.z : 0.2f * xb.z;
      xb.w = f1b.w + f2b.w; xb.w = xb.w >= 0.f ? xb.w : 0.2f * xb.w;
      pa[r] = xa; pb[r] = xb;
      m0 = fmaxf(m0, xa.x); m1 = fmaxf(m1, xa.y);
      m2 = fmaxf(m2, xa.z); m3 = fmaxf(m3, xa.w);
      m4 = fmaxf(m4, xb.x); m5 = fmaxf(m5, xb.y);
      m6 = fmaxf(m6, xb.z); m7 = fmaxf(m7, xb.w);
    }
  }
  m0 = wave_max64(m0); m1 = wave_max64(m1); m2 = wave_max64(m2); m3 = wave_max64(m3);
  m4 = wave_max64(m4); m5 = wave_max64(m5); m6 = wave_max64(m6); m7 = wave_max64(m7);
  float s0 = 0.f, s1 = 0.f, s2 = 0.f, s3 = 0.f, s4 = 0.f, s5 = 0.f, s6 = 0.f, s7 = 0.f;
#pragma unroll
  for (int r = 0; r < 4; ++r) {
    int t = r * 64 + lane;
    float4 ea = make_float4(0.f, 0.f, 0.f, 0.f), eb = ea;
    if (t < deg) {
      ea.x = __expf(pa[r].x - m0); ea.y = __expf(pa[r].y - m1);
      ea.z = __expf(pa[r].z - m2); ea.w = __expf(pa[r].w - m3);
      eb.x = __expf(pb[r].x - m4); eb.y = __expf(pb[r].y - m5);
      eb.z = __expf(pb[r].z - m6); eb.w = __expf(pb[r].w - m7);
      *(float4*)&plds[wv][t][0] = ea;
      *(float4*)&plds[wv][t][4] = eb;
    }
    s0 += ea.x; s1 += ea.y; s2 += ea.z; s3 += ea.w;
    s4 += eb.x; s5 += eb.y; s6 += eb.z; s7 += eb.w;
  }
  s0 = wave_sum64(s0); s1 = wave_sum64(s1); s2 = wave_sum64(s2); s3 = wave_sum64(s3);
  s4 = wave_sum64(s4); s5 = wave_sum64(s5); s6 = wave_sum64(s6); s7 = wave_sum64(s7);

  const int q = lane >> 3;   // head for this lane's 8 features
  float sq = (q < 4) ? (q < 2 ? (q == 0 ? s0 : s1) : (q == 2 ? s2 : s3))
                     : (q < 6 ? (q == 4 ? s4 : s5) : (q == 6 ? s6 : s7));
  float inv = 1.f / sq;

  float4 aA = make_float4(0.f, 0.f, 0.f, 0.f), bA = aA;
  float4 aB = aA, bB = aA, aC = aA, bC = aA, aD = aA, bD = aA;
  const size_t lo8 = (size_t)lane * 8;
#pragma unroll
  for (int r = 0; r < 4; ++r) {
    int base = r * 64;
    if (base >= deg) break;
    int lim = deg - base;
    lim = lim < 64 ? lim : 64;
    int sl = 0;
    for (; sl + 4 <= lim; sl += 4) {
      int j0 = readlane_i(jreg[r], sl);
      int j1 = readlane_i(jreg[r], sl + 1);
      int j2 = readlane_i(jreg[r], sl + 2);
      int j3 = readlane_i(jreg[r], sl + 3);
      float w0 = plds[wv][base + sl][q];
      float w1 = plds[wv][base + sl + 1][q];
      float w2 = plds[wv][base + sl + 2][q];
      float w3 = plds[wv][base + sl + 3][q];
      int4 g0 = *(const int4*)(FTSb + (size_t)j0 * FDIM + lo8);
      int4 g1 = *(const int4*)(FTSb + (size_t)j1 * FDIM + lo8);
      int4 g2 = *(const int4*)(FTSb + (size_t)j2 * FDIM + lo8);
      int4 g3 = *(const int4*)(FTSb + (size_t)j3 * FDIM + lo8);
      aA.x += w0 * lo16f(g0.x); aA.y += w0 * hi16f(g0.x);
      aA.z += w0 * lo16f(g0.y); aA.w += w0 * hi16f(g0.y);
      bA.x += w0 * lo16f(g0.z); bA.y += w0 * hi16f(g0.z);
      bA.z += w0 * lo16f(g0.w); bA.w += w0 * hi16f(g0.w);
      aB.x += w1 * lo16f(g1.x); aB.y += w1 * hi16f(g1.x);
      aB.z += w1 * lo16f(g1.y); aB.w += w1 * hi16f(g1.y);
      bB.x += w1 * lo16f(g1.z); bB.y += w1 * hi16f(g1.z);
      bB.z += w1 * lo16f(g1.w); bB.w += w1 * hi16f(g1.w);
      aC.x += w2 * lo16f(g2.x); aC.y += w2 * hi16f(g2.x);
      aC.z += w2 * lo16f(g2.y); aC.w += w2 * hi16f(g2.y);
      bC.x += w2 * lo16f(g2.z); bC.y += w2 * hi16f(g2.z);
      bC.z += w2 * lo16f(g2.w); bC.w += w2 * hi16f(g2.w);
      aD.x += w3 * lo16f(g3.x); aD.y += w3 * hi16f(g3.x);
      aD.z += w3 * lo16f(g3.y); aD.w += w3 * hi16f(g3.y);
      bD.x += w3 * lo16f(g3.z); bD.y += w3 * hi16f(g3.z);
      bD.z += w3 * lo16f(g3.w); bD.w += w3 * hi16f(g3.w);
    }
    for (; sl < lim; ++sl) {
      int j0 = readlane_i(jreg[r], sl);
      float w0 = plds[wv][base + sl][q];
      int4 g0 = *(const int4*)(FTSb + (size_t)j0 * FDIM + lo8);
      aA.x += w0 * lo16f(g0.x); aA.y += w0 * hi16f(g0.x);
      aA.z += w0 * lo16f(g0.y); aA.w += w0 * hi16f(g0.y);
      bA.x += w0 * lo16f(g0.z); bA.y += w0 * hi16f(g0.z);
      bA.z += w0 * lo16f(g0.w); bA.w += w0 * hi16f(g0.w);
    }
  }
  float v0 = (aA.x + aB.x + aC.x + aD.x) * inv;
  float v1 = (aA.y + aB.y + aC.y + aD.y) * inv;
  float v2 = (aA.z + aB.z + aC.z + aD.z) * inv;
  float v3 = (aA.w + aB.w + aC.w + aD.w) * inv;
  float v4 = (bA.x + bB.x + bC.x + bD.x) * inv;
  float v5 = (bA.y + bB.y + bC.y + bD.y) * inv;
  float v6 = (bA.z + bB.z + bC.z + bD.z) * inv;
  float v7 = (bA.w + bB.w + bC.w + bD.w) * inv;
  unsigned short h0 = f2bf(v0), h1 = f2bf(v1), h2 = f2bf(v2), h3 = f2bf(v3);
  unsigned short h4 = f2bf(v4), h5 = f2bf(v5), h6 = f2bf(v6), h7 = f2bf(v7);
  *(int4*)(VALShi + (size_t)i * FDIM + lo8) = make_int4(
      (int)((unsigned)h0 | ((unsigned)h1 << 16)), (int)((unsigned)h2 | ((unsigned)h3 << 16)),
      (int)((unsigned)h4 | ((unsigned)h5 << 16)), (int)((unsigned)h6 | ((unsigned)h7 << 16)));
  unsigned short l0 = f2bf(v0 - bf2f(h0)), l1 = f2bf(v1 - bf2f(h1));
  unsigned short l2 = f2bf(v2 - bf2f(h2)), l3 = f2bf(v3 - bf2f(h3));
  unsigned short l4 = f2bf(v4 - bf2f(h4)), l5 = f2bf(v5 - bf2f(h5));
  unsigned short l6 = f2bf(v6 - bf2f(h6)), l7 = f2bf(v7 - bf2f(h7));
  *(int4*)(VALSlo + (size_t)i * FDIM + lo8) = make_int4(
      (int)((unsigned)l0 | ((unsigned)l1 << 16)), (int)((unsigned)l2 | ((unsigned)l3 << 16)),
      (int)((unsigned)l4 | ((unsigned)l5 << 16)), (int)((unsigned)l6 | ((unsigned)l7 << 16)));
}

// ---------------- Kernel 4: fused tail: H1 = elu(VALS@W2+bW); FTS2 = H1@Wo1 -
__global__ __launch_bounds__(256) void k_tail(
    const short* __restrict__ VALShi, const short* __restrict__ VALSlo,
    const short* __restrict__ W2thi, const short* __restrict__ W2tlo,
    const float* __restrict__ bW,
    const short* __restrict__ Wo1thi, const short* __restrict__ Wo1tlo,
    const float* __restrict__ ao1, const float* __restrict__ bo1s,
    const float* __restrict__ ao2, const float* __restrict__ bo2s,
    float* __restrict__ FTS2, float* __restrict__ F1O, float* __restrict__ F2O) {
  __shared__ short AH[4][64][16], AL[4][64][16];   // VALS tile (A of W2 mfma)
  __shared__ short BH[4][64][16], BL[4][64][16];   // W2t[h]    (B of W2 mfma)
  __shared__ short CH[4][64][16], CL[4][64][16];   // H1_h      (A of fts2 mfma)
  __shared__ short DH[4][64][16], DL[4][64][16];   // Wo1t[h]   (B of fts2 mfma)
  __shared__ float p1buf[2][64], p2buf[2][64];
  const int i0 = blockIdx.x * 64;
  const int tid = threadIdx.x, lane = tid & 63, w = tid >> 6;
  const int wm = w >> 1, wn = w & 1;
  const int ml = lane & 31, g = lane >> 5, g8 = g * 8;
  const int tn = tid >> 2, k8 = tid & 3;
  const int colw = wn * 32 + ml;
  const int rowl0 = wm * 32 + 4 * g;

  f32x16 acc2;
#pragma unroll
  for (int r = 0; r < 16; ++r) acc2[r] = 0.f;

  for (int h = 0; h < NHEAD; ++h) {
    {
      const short* pa = VALShi + ((size_t)(i0 + tn) << 9) + h * 64 + k8 * 16;
      const short* pl = VALSlo + ((size_t)(i0 + tn) << 9) + h * 64 + k8 * 16;
      *(int4*)&AH[k8][tn][0] = *(const int4*)pa;
      *(int4*)&AH[k8][tn][8] = *(const int4*)(pa + 8);
      *(int4*)&AL[k8][tn][0] = *(const int4*)pl;
      *(int4*)&AL[k8][tn][8] = *(const int4*)(pl + 8);
      const short* pb  = W2thi + (size_t)h * 4096 + tn * 64 + k8 * 16;
      const short* pbl = W2tlo + (size_t)h * 4096 + tn * 64 + k8 * 16;
      *(int4*)&BH[k8][tn][0] = *(const int4*)pb;
      *(int4*)&BH[k8][tn][8] = *(const int4*)(pb + 8);
      *(int4*)&BL[k8][tn][0] = *(const int4*)pbl;
      *(int4*)&BL[k8][tn][8] = *(const int4*)(pbl + 8);
      const short* pd  = Wo1thi + (size_t)tn * FDIM + h * 64 + k8 * 16;
      const short* pdl = Wo1tlo + (size_t)tn * FDIM + h * 64 + k8 * 16;
      *(int4*)&DH[k8][tn][0] = *(const int4*)pd;
      *(int4*)&DH[k8][tn][8] = *(const int4*)(pd + 8);
      *(int4*)&DL[k8][tn][0] = *(const int4*)pdl;
      *(int4*)&DL[k8][tn][8] = *(const int4*)(pdl + 8);
    }
    __syncthreads();
    // W2 MFMA (K=64)
    f32x16 accw;
#pragma unroll
    for (int r = 0; r < 16; ++r) accw[r] = 0.f;
#pragma unroll
    for (int t = 0; t < 4; ++t) {
      bf16x8 ah = *(const bf16x8*)&AH[t][wm * 32 + ml][g8];
      bf16x8 al = *(const bf16x8*)&AL[t][wm * 32 + ml][g8];
      bf16x8 bh = *(const bf16x8*)&BH[t][wn * 32 + ml][g8];
      bf16x8 bl = *(const bf16x8*)&BL[t][wn * 32 + ml][g8];
      accw = __builtin_amdgcn_mfma_f32_32x32x16_bf16(ah, bh, accw, 0, 0, 0);
      accw = __builtin_amdgcn_mfma_f32_32x32x16_bf16(al, bh, accw, 0, 0, 0);
      accw = __builtin_amdgcn_mfma_f32_32x32x16_bf16(ah, bl, accw, 0, 0, 0);
    }
    const float bwv = bW[h * 64 + colw];
    const int ts = colw >> 4, ss = colw & 15;
#pragma unroll
    for (int r = 0; r < 16; ++r) {
      int rl = rowl0 + (r & 3) + 8 * (r >> 2);
      float v = accw[r] + bwv;
      v = v > 0.f ? v : __expf(v) - 1.f;
      unsigned short hv = f2bf(v);
      CH[ts][rl][ss] = (short)hv;
      CL[ts][rl][ss] = (short)f2bf(v - bf2f(hv));
    }
    __syncthreads();
#pragma unroll
    for (int t = 0; t < 4; ++t) {
      bf16x8 ah = *(const bf16x8*)&CH[t][wm * 32 + ml][g8];
      bf16x8 al = *(const bf16x8*)&CL[t][wm * 32 + ml][g8];
      bf16x8 bh = *(const bf16x8*)&DH[t][wn * 32 + ml][g8];
      bf16x8 bl = *(const bf16x8*)&DL[t][wn * 32 + ml][g8];
      acc2 = __builtin_amdgcn_mfma_f32_32x32x16_bf16(ah, bh, acc2, 0, 0, 0);
      acc2 = __builtin_amdgcn_mfma_f32_32x32x16_bf16(al, bh, acc2, 0, 0, 0);
      acc2 = __builtin_amdgcn_mfma_f32_32x32x16_bf16(ah, bl, acc2, 0, 0, 0);
    }
    __syncthreads();
  }

  // epilogue: FTS2 + f1o/f2o
  const bool act = colw < CDIM;
  const float aov1 = act ? ao1[colw] : 0.f;
  const float aov2 = act ? ao2[colw] : 0.f;
#pragma unroll
  for (int r = 0; r < 16; ++r) {
    int rl = rowl0 + (r & 3) + 8 * (r >> 2);
    float v = acc2[r];
    if (act) FTS2[(size_t)(i0 + rl) * CDIM + colw] = v;
    float p1 = v * aov1, p2 = v * aov2;
#pragma unroll
    for (int o = 1; o < 32; o <<= 1) {
      p1 += __shfl_xor(p1, o);
      p2 += __shfl_xor(p2, o);
    }
    if (ml == 0) {
      p1buf[wn][rl] = p1;
      p2buf[wn][rl] = p2;
    }
  }
  __syncthreads();
  if (tid < 64) {
    F1O[i0 + tid] = p1buf[0][tid] + p1buf[1][tid] + bo1s[0];
    F2O[i0 + tid] = p2buf[0][tid] + p2buf[1][tid] + bo2s[0];
  }
}

// ---------------- Kernel 5: layer-2 attention + output GEMM (fused) ---------
__global__ __launch_bounds__(256) void k_agg2(
    const float* __restrict__ FTS2, const float* __restrict__ F1O,
    const float* __restrict__ F2O, const int* __restrict__ nbr,
    const int* __restrict__ cnt, const float* __restrict__ Wo2,
    const float* __restrict__ bo, float* __restrict__ out) {
  int i = blockIdx.x * 4 + (threadIdx.x >> 6);
  int lane = threadIdx.x & 63;
  int deg = cnt[i];
  const int* nb = nbr + (size_t)i * MAXD;
  float f1i = F1O[i];

  int jreg[4];
  float p[4];
  float m = -1e30f;
#pragma unroll
  for (int r = 0; r < 4; ++r) { jreg[r] = 0; p[r] = -1e30f; }
#pragma unroll
  for (int r = 0; r < 4; ++r) {
    int t = r * 64 + lane;
    if (t < deg) {
      int j = nb[t];
      jreg[r] = j;
      float x = f1i + F2O[j];
      x = x >= 0.f ? x : 0.2f * x;
      p[r] = x;
      m = fmaxf(m, x);
    }
  }
  m = wave_max64(m);
  float s = 0.f;
#pragma unroll
  for (int r = 0; r < 4; ++r) {
    int t = r * 64 + lane;
    float e = (t < deg) ? __expf(p[r] - m) : 0.f;
    p[r] = e;
    s += e;
  }
  s = wave_sum64(s);

  const bool act = lane < CDIM;
  float accA = 0.f, accB = 0.f, accC = 0.f, accD = 0.f;
#pragma unroll
  for (int r = 0; r < 4; ++r) {
    int base = r * 64;
    if (base >= deg) break;
    int lim = deg - base;
    lim = lim < 64 ? lim : 64;
    int sl = 0;
    for (; sl + 4 <= lim; sl += 4) {
      float w0 = readlane_f(p[r], sl);
      float w1 = readlane_f(p[r], sl + 1);
      float w2 = readlane_f(p[r], sl + 2);
      float w3 = readlane_f(p[r], sl + 3);
      int j0 = readlane_i(jreg[r], sl);
      int j1 = readlane_i(jreg[r], sl + 1);
      int j2 = readlane_i(jreg[r], sl + 2);
      int j3 = readlane_i(jreg[r], sl + 3);
      float f0 = act ? FTS2[(size_t)j0 * CDIM + lane] : 0.f;
      float f1 = act ? FTS2[(size_t)j1 * CDIM + lane] : 0.f;
      float f2 = act ? FTS2[(size_t)j2 * CDIM + lane] : 0.f;
      float f3 = act ? FTS2[(size_t)j3 * CDIM + lane] : 0.f;
      accA += w0 * f0;
      accB += w1 * f1;
      accC += w2 * f2;
      accD += w3 * f3;
    }
    for (; sl < lim; ++sl) {
      float w0 = readlane_f(p[r], sl);
      int j0 = readlane_i(jreg[r], sl);
      float f0 = act ? FTS2[(size_t)j0 * CDIM + lane] : 0.f;
      accA += w0 * f0;
    }
  }
  float v = (accA + accB + accC + accD) / s;

  float o = act ? bo[lane] : 0.f;
  for (int kk = 0; kk < CDIM; ++kk) {
    float w = readlane_f(v, kk);
    float b = act ? Wo2[kk * CDIM + lane] : 0.f;
    o += w * b;
  }
  if (act) out[(size_t)i * CDIM + lane] = o;
}

extern "C" void kernel_launch(void* const* d_in, const int* in_sizes, int n_in,
                              void* d_out, int out_size, void* d_ws, size_t ws_size,
                              hipStream_t stream) {
  const float* seq  = (const float*)d_in[0];
  const float* bias = (const float*)d_in[1];
  const float* W1   = (const float*)d_in[2];
  const float* a1   = (const float*)d_in[3];
  const float* b1   = (const float*)d_in[4];
  const float* a2   = (const float*)d_in[5];
  const float* b2   = (const float*)d_in[6];
  const float* W2   = (const float*)d_in[7];
  const float* bW   = (const float*)d_in[8];
  const float* Wo1  = (const float*)d_in[9];
  const float* ao1  = (const float*)d_in[10];
  const float* bo1  = (const float*)d_in[11];
  const float* ao2  = (const float*)d_in[12];
  const float* bo2  = (const float*)d_in[13];
  const float* Wo2  = (const float*)d_in[14];
  const float* bo   = (const float*)d_in[15];
  float* out = (float*)d_out;

  float* ws    = (float*)d_ws;
  float* F1t   = ws;                          // N*8
  float* F2t   = F1t  + (size_t)NN * NHEAD;   // N*8
  float* FTS2  = F2t  + (size_t)NN * NHEAD;   // N*40
  float* F1O   = FTS2 + (size_t)NN * CDIM;    // N
  float* F2O   = F1O  + NN;                   // N
  short* FTSb  = (short*)(F2O + NN);          // N*512 bf16
  short* Bhi   = FTSb + (size_t)NN * FDIM;    // 8*64*512
  short* Blo   = Bhi + (size_t)NHEAD * HDIM * FDIM;
  short* VALShi= Blo + (size_t)NHEAD * HDIM * FDIM;  // N*512
  short* VALSlo= VALShi + (size_t)NN * FDIM;
  short* W2thi = VALSlo + (size_t)NN * FDIM;         // 8*64*64
  short* W2tlo = W2thi + (size_t)NHEAD * HDIM * HDIM;
  short* Wo1thi= W2tlo + (size_t)NHEAD * HDIM * HDIM; // 64*512
  short* Wo1tlo= Wo1thi + (size_t)64 * FDIM;
  int*   nbr   = (int*)(Wo1tlo + (size_t)64 * FDIM);  // N*MAXD
  int*   cnt   = nbr + (size_t)NN * MAXD;     // N

  // 1. weight conversions (seq cvt moved into k_gemm registers)
  k_prep<<<64 + 8 + 8, 256, 0, stream>>>(
      W1, Bhi, Blo, W2, W2thi, W2tlo, Wo1, Wo1thi, Wo1tlo);
  // 2. MFMA GEMM (in-reg seq cvt) + fused f1/f2  ∥  CSR build
  k_gemm<<<256 + NN, 256, 0, stream>>>(
      seq, Bhi, Blo, a1, b1, a2, b2, FTSb, F1t, F2t, bias, nbr, cnt);
  // 3. sparse softmax + aggregation (1 wave/row, 16B gathers, ILP4)
  k_agg1<<<NN / 4, 256, 0, stream>>>(FTSb, F1t, F2t, nbr, cnt, VALShi, VALSlo);
  // 4. fused W2+elu+fts2 MFMA tail
  k_tail<<<NN / 64, 256, 0, stream>>>(VALShi, VALSlo, W2thi, W2tlo, bW,
                                      Wo1thi, Wo1tlo, ao1, bo1, ao2, bo2,
                                      FTS2, F1O, F2O);
  // 5. layer-2 sparse attention + final dense + bias (ILP4)
  k_agg2<<<NN / 4, 256, 0, stream>>>(FTS2, F1O, F2O, nbr, cnt, Wo2, bo, out);
}

// Round 15
// 83.115 us; speedup vs baseline: 3.2464x; 1.0227x over previous
//
#include <hip/hip_runtime.h>
#include <cstdint>
#include <cstddef>

#define NN 4096
#define FDIM 512
#define HDIM 64
#define NHEAD 8
#define CDIM 40
#define MAXD 256   // max neighbors kept per row (~41 expected)

typedef __attribute__((ext_vector_type(8))) short bf16x8;
typedef __attribute__((ext_vector_type(16))) float f32x16;

__device__ __forceinline__ float wave_max64(float v) {
  for (int o = 32; o; o >>= 1) v = fmaxf(v, __shfl_xor(v, o));
  return v;
}
__device__ __forceinline__ float wave_sum64(float v) {
  for (int o = 32; o; o >>= 1) v += __shfl_xor(v, o);
  return v;
}
__device__ __forceinline__ float readlane_f(float v, int sl) {
  return __uint_as_float((unsigned)__builtin_amdgcn_readlane((int)__float_as_uint(v), sl));
}
__device__ __forceinline__ int readlane_i(int v, int sl) {
  return __builtin_amdgcn_readlane(v, sl);
}
// fp32 -> bf16 (RNE) and back, via bit ops
__device__ __forceinline__ unsigned short f2bf(float x) {
  unsigned u = __float_as_uint(x);
  return (unsigned short)((u + 0x7fffu + ((u >> 16) & 1u)) >> 16);
}
__device__ __forceinline__ float bf2f(unsigned short b) {
  return __uint_as_float(((unsigned)b) << 16);
}
// unpack packed bf16 pair (int) -> floats
__device__ __forceinline__ float lo16f(int u) { return __int_as_float(u << 16); }
__device__ __forceinline__ float hi16f(int u) { return __int_as_float(u & 0xffff0000); }
// 8 fp32 -> 8 bf16 hi + 8 bf16 lo, packed
__device__ __forceinline__ void cvt8(const float4& a, const float4& b,
                                     int4& hi, int4& lo) {
  unsigned short h0 = f2bf(a.x), h1 = f2bf(a.y), h2 = f2bf(a.z), h3 = f2bf(a.w);
  unsigned short h4 = f2bf(b.x), h5 = f2bf(b.y), h6 = f2bf(b.z), h7 = f2bf(b.w);
  hi = make_int4((int)((unsigned)h0 | ((unsigned)h1 << 16)),
                 (int)((unsigned)h2 | ((unsigned)h3 << 16)),
                 (int)((unsigned)h4 | ((unsigned)h5 << 16)),
                 (int)((unsigned)h6 | ((unsigned)h7 << 16)));
  unsigned short l0 = f2bf(a.x - bf2f(h0)), l1 = f2bf(a.y - bf2f(h1));
  unsigned short l2 = f2bf(a.z - bf2f(h2)), l3 = f2bf(a.w - bf2f(h3));
  unsigned short l4 = f2bf(b.x - bf2f(h4)), l5 = f2bf(b.y - bf2f(h5));
  unsigned short l6 = f2bf(b.z - bf2f(h6)), l7 = f2bf(b.w - bf2f(h7));
  lo = make_int4((int)((unsigned)l0 | ((unsigned)l1 << 16)),
                 (int)((unsigned)l2 | ((unsigned)l3 << 16)),
                 (int)((unsigned)l4 | ((unsigned)l5 << 16)),
                 (int)((unsigned)l6 | ((unsigned)l7 << 16)));
}

// ---------------- Kernel 1: prep (weight conversions only) -----------------
__global__ __launch_bounds__(256) void k_prep(
    const float* __restrict__ W1, short* __restrict__ Bhi, short* __restrict__ Blo,
    const float* __restrict__ W2, short* __restrict__ W2thi, short* __restrict__ W2tlo,
    const float* __restrict__ Wo1, short* __restrict__ Wo1thi, short* __restrict__ Wo1tlo) {
  __shared__ float T[64][65];
  int bx = blockIdx.x, tid = threadIdx.x;
  if (bx < 64) {       // ---- W1 tile transpose + bf16 hi/lo: [k][n] -> [n][k]
    int h = bx >> 3, kb = bx & 7;
    const float* src = W1 + ((size_t)h * FDIM + kb * 64) * HDIM;
#pragma unroll
    for (int q = 0; q < 4; ++q) {
      int fi = q * 256 + tid, kk = fi >> 4, n4 = fi & 15;
      float4 v = *(const float4*)(src + (size_t)kk * HDIM + n4 * 4);
      T[n4 * 4 + 0][kk] = v.x; T[n4 * 4 + 1][kk] = v.y;
      T[n4 * 4 + 2][kk] = v.z; T[n4 * 4 + 3][kk] = v.w;
    }
    __syncthreads();
#pragma unroll
    for (int q = 0; q < 4; ++q) {
      int fi = q * 256 + tid, n = fi >> 4, k4 = fi & 15;
      float a = T[n][k4 * 4], b = T[n][k4 * 4 + 1];
      float c = T[n][k4 * 4 + 2], d = T[n][k4 * 4 + 3];
      size_t o = ((size_t)h * 64 + n) * FDIM + kb * 64 + k4 * 4;
      unsigned short ha = f2bf(a), hb = f2bf(b), hc = f2bf(c), hd = f2bf(d);
      *(short4*)(Bhi + o) = make_short4((short)ha, (short)hb, (short)hc, (short)hd);
      *(short4*)(Blo + o) = make_short4((short)f2bf(a - bf2f(ha)), (short)f2bf(b - bf2f(hb)),
                                        (short)f2bf(c - bf2f(hc)), (short)f2bf(d - bf2f(hd)));
    }
    return;
  }
  bx -= 64;
  if (bx < 8) {        // ---- W2[h] transpose [64k][64n] -> [n][k] hi/lo
    int h = bx;
    const float* src = W2 + (size_t)h * HDIM * HDIM;
#pragma unroll
    for (int q = 0; q < 4; ++q) {
      int fi = q * 256 + tid, kk = fi >> 4, n4 = fi & 15;
      float4 v = *(const float4*)(src + (size_t)kk * HDIM + n4 * 4);
      T[n4 * 4 + 0][kk] = v.x; T[n4 * 4 + 1][kk] = v.y;
      T[n4 * 4 + 2][kk] = v.z; T[n4 * 4 + 3][kk] = v.w;
    }
    __syncthreads();
#pragma unroll
    for (int q = 0; q < 4; ++q) {
      int fi = q * 256 + tid, n = fi >> 4, k4 = fi & 15;
      float a = T[n][k4 * 4], b = T[n][k4 * 4 + 1];
      float c = T[n][k4 * 4 + 2], d = T[n][k4 * 4 + 3];
      size_t o = (size_t)h * 4096 + (size_t)n * 64 + k4 * 4;
      unsigned short ha = f2bf(a), hb = f2bf(b), hc = f2bf(c), hd = f2bf(d);
      *(short4*)(W2thi + o) = make_short4((short)ha, (short)hb, (short)hc, (short)hd);
      *(short4*)(W2tlo + o) = make_short4((short)f2bf(a - bf2f(ha)), (short)f2bf(b - bf2f(hb)),
                                          (short)f2bf(c - bf2f(hc)), (short)f2bf(d - bf2f(hd)));
    }
    return;
  }
  bx -= 8;
  {                    // ---- Wo1 transpose+pad [512][40] -> [64][512] hi/lo
#pragma unroll
    for (int q = 0; q < 16; ++q) {
      int idx = q * 256 + tid;          // 0..4095
      int n = bx * 8 + (idx >> 9), k = idx & 511;
      float v = (n < CDIM) ? Wo1[(size_t)k * CDIM + n] : 0.f;
      unsigned short hv = f2bf(v);
      Wo1thi[(size_t)n * FDIM + k] = (short)hv;
      Wo1tlo[(size_t)n * FDIM + k] = (short)f2bf(v - bf2f(hv));
    }
  }
}

// ---------------- Kernel 2: MFMA GEMM (in-reg seq cvt) + f1/f2  ∥  CSR -----
__global__ __launch_bounds__(256) void k_gemm(
    const float* __restrict__ seq,
    const short* __restrict__ Bhi, const short* __restrict__ Blo,
    const float* __restrict__ a1, const float* __restrict__ b1,
    const float* __restrict__ a2, const float* __restrict__ b2,
    short* __restrict__ FTSb, float* __restrict__ F1t, float* __restrict__ F2t,
    const float* __restrict__ bias, int* __restrict__ nbr, int* __restrict__ cnt) {
  __shared__ short AH[4][64][16], AL[4][64][16];    // [kstep16][m][k-slot]
  __shared__ short BH[4][128][16], BL[4][128][16];  // [kstep16][n][k-slot]
  __shared__ int wtot[4];
  const int bx = blockIdx.x;
  const int tid = threadIdx.x, lane = tid & 63, w = tid >> 6;

  if (bx >= 256) {     // ---------------- CSR: one block per row ------------
    int row = bx - 256;
    int wv = w;
    const float4* r = (const float4*)(bias + (size_t)row * NN);
    unsigned mask = 0;
#pragma unroll
    for (int i = 0; i < 4; ++i) {
      float4 v = r[tid * 4 + i];
      mask |= (unsigned)((v.x == 0.f ? 1 : 0) | (v.y == 0.f ? 2 : 0) |
                         (v.z == 0.f ? 4 : 0) | (v.w == 0.f ? 8 : 0)) << (i * 4);
    }
    int c = __popc(mask);
    int pre = c;
#pragma unroll
    for (int o = 1; o < 64; o <<= 1) {
      int u = __shfl_up(pre, o);
      if (lane >= o) pre += u;
    }
    if (lane == 63) wtot[wv] = pre;
    __syncthreads();
    int woff = 0;
#pragma unroll
    for (int ww = 0; ww < 4; ++ww)
      if (ww < wv) woff += wtot[ww];
    int excl = woff + pre - c;
    int* outp = nbr + (size_t)row * MAXD;
    int col0 = tid * 16, k = 0;
#pragma unroll
    for (int i = 0; i < 16; ++i) {
      if ((mask >> i) & 1) {
        int p = excl + k;
        if (p < MAXD) outp[p] = col0 + i;
        ++k;
      }
    }
    if (tid == 0) {
      int total = wtot[0] + wtot[1] + wtot[2] + wtot[3];
      cnt[row] = total < MAXD ? total : MAXD;
    }
    return;
  }

  // ---------------- GEMM tile ----------------
  const int mtile = bx & 63, npair = bx >> 6;
  const int wm = w >> 1, wn = w & 1;
  const int ml = lane & 31, g = lane >> 5, g8 = g * 8;

  f32x16 acc0, acc1;
#pragma unroll
  for (int r = 0; r < 16; ++r) { acc0[r] = 0.f; acc1[r] = 0.f; }

  const short* Bbh = Bhi + (((size_t)npair * 128) << 9);
  const short* Bbl = Blo + (((size_t)npair * 128) << 9);

  const int tn = tid >> 3, k8 = tid & 7;
  const int ks = k8 >> 1, ko = (k8 & 1) * 8;
  const size_t so = ((size_t)tn << 9) + (size_t)k8 * 8;
  const float* As0 = seq + (((size_t)(mtile * 64 + tn)) << 9) + k8 * 8;
  const float* As1 = As0 + ((size_t)32 << 9);

  float4 fa0a, fa0b, fa1a, fa1b;
  int4 rbh0, rbh1, rbh2, rbh3, rbl0, rbl1, rbl2, rbl3;
  {
    fa0a = *(const float4*)(As0);      fa0b = *(const float4*)(As0 + 4);
    fa1a = *(const float4*)(As1);      fa1b = *(const float4*)(As1 + 4);
    rbh0 = *(const int4*)(Bbh + so);              rbl0 = *(const int4*)(Bbl + so);
    rbh1 = *(const int4*)(Bbh + so + (32 << 9));  rbl1 = *(const int4*)(Bbl + so + (32 << 9));
    rbh2 = *(const int4*)(Bbh + so + (64 << 9));  rbl2 = *(const int4*)(Bbl + so + (64 << 9));
    rbh3 = *(const int4*)(Bbh + so + (96 << 9));  rbl3 = *(const int4*)(Bbl + so + (96 << 9));
  }

  const int NCH = FDIM / 64;   // 8 chunks
  for (int c = 0; c < NCH; ++c) {
    {
      int4 hi0, lo0, hi1, lo1;
      cvt8(fa0a, fa0b, hi0, lo0);
      cvt8(fa1a, fa1b, hi1, lo1);
      *(int4*)&AH[ks][tn][ko] = hi0;       *(int4*)&AL[ks][tn][ko] = lo0;
      *(int4*)&AH[ks][32 + tn][ko] = hi1;  *(int4*)&AL[ks][32 + tn][ko] = lo1;
    }
    *(int4*)&BH[ks][tn][ko] = rbh0;       *(int4*)&BL[ks][tn][ko] = rbl0;
    *(int4*)&BH[ks][32 + tn][ko] = rbh1;  *(int4*)&BL[ks][32 + tn][ko] = rbl1;
    *(int4*)&BH[ks][64 + tn][ko] = rbh2;  *(int4*)&BL[ks][64 + tn][ko] = rbl2;
    *(int4*)&BH[ks][96 + tn][ko] = rbh3;  *(int4*)&BL[ks][96 + tn][ko] = rbl3;
    __syncthreads();
    if (c + 1 < NCH) {
      size_t o = so + (size_t)(c + 1) * 64;
      const float* a0 = As0 + (size_t)(c + 1) * 64;
      const float* a1p = As1 + (size_t)(c + 1) * 64;
      fa0a = *(const float4*)(a0);      fa0b = *(const float4*)(a0 + 4);
      fa1a = *(const float4*)(a1p);     fa1b = *(const float4*)(a1p + 4);
      rbh0 = *(const int4*)(Bbh + o);              rbl0 = *(const int4*)(Bbl + o);
      rbh1 = *(const int4*)(Bbh + o + (32 << 9));  rbl1 = *(const int4*)(Bbl + o + (32 << 9));
      rbh2 = *(const int4*)(Bbh + o + (64 << 9));  rbl2 = *(const int4*)(Bbl + o + (64 << 9));
      rbh3 = *(const int4*)(Bbh + o + (96 << 9));  rbl3 = *(const int4*)(Bbl + o + (96 << 9));
    }
#pragma unroll
    for (int t = 0; t < 4; ++t) {
      bf16x8 ah = *(const bf16x8*)&AH[t][wm * 32 + ml][g8];
      bf16x8 al = *(const bf16x8*)&AL[t][wm * 32 + ml][g8];
      bf16x8 bh0 = *(const bf16x8*)&BH[t][wn * 64 + ml][g8];
      bf16x8 bl0 = *(const bf16x8*)&BL[t][wn * 64 + ml][g8];
      acc0 = __builtin_amdgcn_mfma_f32_32x32x16_bf16(ah, bh0, acc0, 0, 0, 0);
      acc0 = __builtin_amdgcn_mfma_f32_32x32x16_bf16(al, bh0, acc0, 0, 0, 0);
      acc0 = __builtin_amdgcn_mfma_f32_32x32x16_bf16(ah, bl0, acc0, 0, 0, 0);
      bf16x8 bh1 = *(const bf16x8*)&BH[t][wn * 64 + 32 + ml][g8];
      bf16x8 bl1 = *(const bf16x8*)&BL[t][wn * 64 + 32 + ml][g8];
      acc1 = __builtin_amdgcn_mfma_f32_32x32x16_bf16(ah, bh1, acc1, 0, 0, 0);
      acc1 = __builtin_amdgcn_mfma_f32_32x32x16_bf16(al, bh1, acc1, 0, 0, 0);
      acc1 = __builtin_amdgcn_mfma_f32_32x32x16_bf16(ah, bl1, acc1, 0, 0, 0);
    }
    __syncthreads();
  }

  // epilogue: C layout col=lane&31, row=(r&3)+8*(r>>2)+4*(lane>>5)
  const int h = npair * 2 + wn;
  const float a1lo = a1[h * 64 + ml], a1hi = a1[h * 64 + 32 + ml];
  const float a2lo = a2[h * 64 + ml], a2hi = a2[h * 64 + 32 + ml];
  const float b1h = b1[h], b2h = b2[h];
  const int row0 = mtile * 64 + wm * 32 + 4 * g;
  const int col0 = npair * 128 + wn * 64 + ml;
#pragma unroll
  for (int r = 0; r < 16; ++r) {
    int row = row0 + (r & 3) + 8 * (r >> 2);
    FTSb[(size_t)row * FDIM + col0] = (short)f2bf(acc0[r]);
    FTSb[(size_t)row * FDIM + col0 + 32] = (short)f2bf(acc1[r]);
    float p1 = acc0[r] * a1lo + acc1[r] * a1hi;
    float p2 = acc0[r] * a2lo + acc1[r] * a2hi;
#pragma unroll
    for (int o = 1; o < 32; o <<= 1) {
      p1 += __shfl_xor(p1, o);
      p2 += __shfl_xor(p2, o);
    }
    if (ml == 0) {
      F1t[(size_t)row * 8 + h] = p1 + b1h;
      F2t[(size_t)row * 8 + h] = p2 + b2h;
    }
  }
}

// ---------------- Kernel 3: sparse softmax + aggregation (1 wave/row) -------
__global__ __launch_bounds__(256) void k_agg1(
    const short* __restrict__ FTSb, const float* __restrict__ F1t,
    const float* __restrict__ F2t, const int* __restrict__ nbr,
    const int* __restrict__ cnt, short* __restrict__ VALShi,
    short* __restrict__ VALSlo) {
  __shared__ float plds[4][MAXD][8];   // [wave][slot][head] = 32 KB
  int wv = threadIdx.x >> 6, lane = threadIdx.x & 63;
  int i = blockIdx.x * 4 + wv;
  int deg = cnt[i];
  const int* nb = nbr + (size_t)i * MAXD;
  float4 f1a = *(const float4*)(F1t + (size_t)i * 8);
  float4 f1b = *(const float4*)(F1t + (size_t)i * 8 + 4);

  float4 pa[4], pb[4];
  int jreg[4];
  float m0 = -1e30f, m1 = -1e30f, m2 = -1e30f, m3 = -1e30f;
  float m4 = -1e30f, m5 = -1e30f, m6 = -1e30f, m7 = -1e30f;
#pragma unroll
  for (int r = 0; r < 4; ++r) {
    int t = r * 64 + lane;
    jreg[r] = 0;
    pa[r] = make_float4(-1e30f, -1e30f, -1e30f, -1e30f);
    pb[r] = pa[r];
    if (t < deg) {
      int j = nb[t];
      jreg[r] = j;
      float4 f2a = *(const float4*)(F2t + (size_t)j * 8);
      float4 f2b = *(const float4*)(F2t + (size_t)j * 8 + 4);
      float4 xa, xb;
      xa.x = f1a.x + f2a.x; xa.x = xa.x >= 0.f ? xa.x : 0.2f * xa.x;
      xa.y = f1a.y + f2a.y; xa.y = xa.y >= 0.f ? xa.y : 0.2f * xa.y;
      xa.z = f1a.z + f2a.z; xa.z = xa.z >= 0.f ? xa.z : 0.2f * xa.z;
      xa.w = f1a.w + f2a.w; xa.w = xa.w >= 0.f ? xa.w : 0.2f * xa.w;
      xb.x = f1b.x + f2b.x; xb.x = xb.x >= 0.f ? xb.x : 0.2f * xb.x;
      xb.y = f1b.y + f2b.y; xb.y = xb.y >= 0.f ? xb.y : 0.2f * xb.y;
      xb.z = f1b.z + f2b.z; xb.z = xb.z >= 0.f ? xb.z : 0.2f * xb.z;
      xb.w = f1b.w + f2b.w; xb.w = xb.w >= 0.f ? xb.w : 0.2f * xb.w;
      pa[r] = xa; pb[r] = xb;
      m0 = fmaxf(m0, xa.x); m1 = fmaxf(m1, xa.y);
      m2 = fmaxf(m2, xa.z); m3 = fmaxf(m3, xa.w);
      m4 = fmaxf(m4, xb.x); m5 = fmaxf(m5, xb.y);
      m6 = fmaxf(m6, xb.z); m7 = fmaxf(m7, xb.w);
    }
  }
  m0 = wave_max64(m0); m1 = wave_max64(m1); m2 = wave_max64(m2); m3 = wave_max64(m3);
  m4 = wave_max64(m4); m5 = wave_max64(m5); m6 = wave_max64(m6); m7 = wave_max64(m7);
  float s0 = 0.f, s1 = 0.f, s2 = 0.f, s3 = 0.f, s4 = 0.f, s5 = 0.f, s6 = 0.f, s7 = 0.f;
#pragma unroll
  for (int r = 0; r < 4; ++r) {
    int t = r * 64 + lane;
    float4 ea = make_float4(0.f, 0.f, 0.f, 0.f), eb = ea;
    if (t < deg) {
      ea.x = __expf(pa[r].x - m0); ea.y = __expf(pa[r].y - m1);
      ea.z = __expf(pa[r].z - m2); ea.w = __expf(pa[r].w - m3);
      eb.x = __expf(pb[r].x - m4); eb.y = __expf(pb[r].y - m5);
      eb.z = __expf(pb[r].z - m6); eb.w = __expf(pb[r].w - m7);
      *(float4*)&plds[wv][t][0] = ea;
      *(float4*)&plds[wv][t][4] = eb;
    }
    s0 += ea.x; s1 += ea.y; s2 += ea.z; s3 += ea.w;
    s4 += eb.x; s5 += eb.y; s6 += eb.z; s7 += eb.w;
  }
  s0 = wave_sum64(s0); s1 = wave_sum64(s1); s2 = wave_sum64(s2); s3 = wave_sum64(s3);
  s4 = wave_sum64(s4); s5 = wave_sum64(s5); s6 = wave_sum64(s6); s7 = wave_sum64(s7);

  const int q = lane >> 3;   // head for this lane's 8 features
  float sq = (q < 4) ? (q < 2 ? (q == 0 ? s0 : s1) : (q == 2 ? s2 : s3))
                     : (q < 6 ? (q == 4 ? s4 : s5) : (q == 6 ? s6 : s7));
  float inv = 1.f / sq;

  float4 aA = make_float4(0.f, 0.f, 0.f, 0.f), bA = aA;
  float4 aB = aA, bB = aA, aC = aA, bC = aA, aD = aA, bD = aA;
  const size_t lo8 = (size_t)lane * 8;
#pragma unroll
  for (int r = 0; r < 4; ++r) {
    int base = r * 64;
    if (base >= deg) break;
    int lim = deg - base;
    lim = lim < 64 ? lim : 64;
    int sl = 0;
    for (; sl + 4 <= lim; sl += 4) {
      int j0 = readlane_i(jreg[r], sl);
      int j1 = readlane_i(jreg[r], sl + 1);
      int j2 = readlane_i(jreg[r], sl + 2);
      int j3 = readlane_i(jreg[r], sl + 3);
      float w0 = plds[wv][base + sl][q];
      float w1 = plds[wv][base + sl + 1][q];
      float w2 = plds[wv][base + sl + 2][q];
      float w3 = plds[wv][base + sl + 3][q];
      int4 g0 = *(const int4*)(FTSb + (size_t)j0 * FDIM + lo8);
      int4 g1 = *(const int4*)(FTSb + (size_t)j1 * FDIM + lo8);
      int4 g2 = *(const int4*)(FTSb + (size_t)j2 * FDIM + lo8);
      int4 g3 = *(const int4*)(FTSb + (size_t)j3 * FDIM + lo8);
      aA.x += w0 * lo16f(g0.x); aA.y += w0 * hi16f(g0.x);
      aA.z += w0 * lo16f(g0.y); aA.w += w0 * hi16f(g0.y);
      bA.x += w0 * lo16f(g0.z); bA.y += w0 * hi16f(g0.z);
      bA.z += w0 * lo16f(g0.w); bA.w += w0 * hi16f(g0.w);
      aB.x += w1 * lo16f(g1.x); aB.y += w1 * hi16f(g1.x);
      aB.z += w1 * lo16f(g1.y); aB.w += w1 * hi16f(g1.y);
      bB.x += w1 * lo16f(g1.z); bB.y += w1 * hi16f(g1.z);
      bB.z += w1 * lo16f(g1.w); bB.w += w1 * hi16f(g1.w);
      aC.x += w2 * lo16f(g2.x); aC.y += w2 * hi16f(g2.x);
      aC.z += w2 * lo16f(g2.y); aC.w += w2 * hi16f(g2.y);
      bC.x += w2 * lo16f(g2.z); bC.y += w2 * hi16f(g2.z);
      bC.z += w2 * lo16f(g2.w); bC.w += w2 * hi16f(g2.w);
      aD.x += w3 * lo16f(g3.x); aD.y += w3 * hi16f(g3.x);
      aD.z += w3 * lo16f(g3.y); aD.w += w3 * hi16f(g3.y);
      bD.x += w3 * lo16f(g3.z); bD.y += w3 * hi16f(g3.z);
      bD.z += w3 * lo16f(g3.w); bD.w += w3 * hi16f(g3.w);
    }
    for (; sl < lim; ++sl) {
      int j0 = readlane_i(jreg[r], sl);
      float w0 = plds[wv][base + sl][q];
      int4 g0 = *(const int4*)(FTSb + (size_t)j0 * FDIM + lo8);
      aA.x += w0 * lo16f(g0.x); aA.y += w0 * hi16f(g0.x);
      aA.z += w0 * lo16f(g0.y); aA.w += w0 * hi16f(g0.y);
      bA.x += w0 * lo16f(g0.z); bA.y += w0 * hi16f(g0.z);
      bA.z += w0 * lo16f(g0.w); bA.w += w0 * hi16f(g0.w);
    }
  }
  float v0 = (aA.x + aB.x + aC.x + aD.x) * inv;
  float v1 = (aA.y + aB.y + aC.y + aD.y) * inv;
  float v2 = (aA.z + aB.z + aC.z + aD.z) * inv;
  float v3 = (aA.w + aB.w + aC.w + aD.w) * inv;
  float v4 = (bA.x + bB.x + bC.x + bD.x) * inv;
  float v5 = (bA.y + bB.y + bC.y + bD.y) * inv;
  float v6 = (bA.z + bB.z + bC.z + bD.z) * inv;
  float v7 = (bA.w + bB.w + bC.w + bD.w) * inv;
  unsigned short h0 = f2bf(v0), h1 = f2bf(v1), h2 = f2bf(v2), h3 = f2bf(v3);
  unsigned short h4 = f2bf(v4), h5 = f2bf(v5), h6 = f2bf(v6), h7 = f2bf(v7);
  *(int4*)(VALShi + (size_t)i * FDIM + lo8) = make_int4(
      (int)((unsigned)h0 | ((unsigned)h1 << 16)), (int)((unsigned)h2 | ((unsigned)h3 << 16)),
      (int)((unsigned)h4 | ((unsigned)h5 << 16)), (int)((unsigned)h6 | ((unsigned)h7 << 16)));
  unsigned short l0 = f2bf(v0 - bf2f(h0)), l1 = f2bf(v1 - bf2f(h1));
  unsigned short l2 = f2bf(v2 - bf2f(h2)), l3 = f2bf(v3 - bf2f(h3));
  unsigned short l4 = f2bf(v4 - bf2f(h4)), l5 = f2bf(v5 - bf2f(h5));
  unsigned short l6 = f2bf(v6 - bf2f(h6)), l7 = f2bf(v7 - bf2f(h7));
  *(int4*)(VALSlo + (size_t)i * FDIM + lo8) = make_int4(
      (int)((unsigned)l0 | ((unsigned)l1 << 16)), (int)((unsigned)l2 | ((unsigned)l3 << 16)),
      (int)((unsigned)l4 | ((unsigned)l5 << 16)), (int)((unsigned)l6 | ((unsigned)l7 << 16)));
}

// ---------------- Kernel 4: split tail: per head-group partial FTS2/F1O/F2O -
// grid 128: (row-tile i0, head-group hg of 4 heads). Biases deferred to agg2.
__global__ __launch_bounds__(256) void k_tail(
    const short* __restrict__ VALShi, const short* __restrict__ VALSlo,
    const short* __restrict__ W2thi, const short* __restrict__ W2tlo,
    const float* __restrict__ bW,
    const short* __restrict__ Wo1thi, const short* __restrict__ Wo1tlo,
    const float* __restrict__ ao1, const float* __restrict__ ao2,
    float* __restrict__ FTS2, float* __restrict__ F1O, float* __restrict__ F2O) {
  __shared__ short AH[4][64][16], AL[4][64][16];   // VALS tile (A of W2 mfma)
  __shared__ short BH[4][64][16], BL[4][64][16];   // W2t[h]    (B of W2 mfma)
  __shared__ short CH[4][64][16], CL[4][64][16];   // H1_h      (A of fts2 mfma)
  __shared__ short DH[4][64][16], DL[4][64][16];   // Wo1t[h]   (B of fts2 mfma)
  __shared__ float p1buf[2][64], p2buf[2][64];
  const int bx = blockIdx.x;
  const int i0 = (bx >> 1) * 64;
  const int hg = bx & 1;
  const int tid = threadIdx.x, lane = tid & 63, w = tid >> 6;
  const int wm = w >> 1, wn = w & 1;
  const int ml = lane & 31, g = lane >> 5, g8 = g * 8;
  const int tn = tid >> 2, k8 = tid & 3;
  const int colw = wn * 32 + ml;
  const int rowl0 = wm * 32 + 4 * g;

  f32x16 acc2;
#pragma unroll
  for (int r = 0; r < 16; ++r) acc2[r] = 0.f;

  for (int hh = 0; hh < 4; ++hh) {
    const int h = hg * 4 + hh;
    {
      const short* pa = VALShi + ((size_t)(i0 + tn) << 9) + h * 64 + k8 * 16;
      const short* pl = VALSlo + ((size_t)(i0 + tn) << 9) + h * 64 + k8 * 16;
      *(int4*)&AH[k8][tn][0] = *(const int4*)pa;
      *(int4*)&AH[k8][tn][8] = *(const int4*)(pa + 8);
      *(int4*)&AL[k8][tn][0] = *(const int4*)pl;
      *(int4*)&AL[k8][tn][8] = *(const int4*)(pl + 8);
      const short* pb  = W2thi + (size_t)h * 4096 + tn * 64 + k8 * 16;
      const short* pbl = W2tlo + (size_t)h * 4096 + tn * 64 + k8 * 16;
      *(int4*)&BH[k8][tn][0] = *(const int4*)pb;
      *(int4*)&BH[k8][tn][8] = *(const int4*)(pb + 8);
      *(int4*)&BL[k8][tn][0] = *(const int4*)pbl;
      *(int4*)&BL[k8][tn][8] = *(const int4*)(pbl + 8);
      const short* pd  = Wo1thi + (size_t)tn * FDIM + h * 64 + k8 * 16;
      const short* pdl = Wo1tlo + (size_t)tn * FDIM + h * 64 + k8 * 16;
      *(int4*)&DH[k8][tn][0] = *(const int4*)pd;
      *(int4*)&DH[k8][tn][8] = *(const int4*)(pd + 8);
      *(int4*)&DL[k8][tn][0] = *(const int4*)pdl;
      *(int4*)&DL[k8][tn][8] = *(const int4*)(pdl + 8);
    }
    __syncthreads();
    // W2 MFMA (K=64)
    f32x16 accw;
#pragma unroll
    for (int r = 0; r < 16; ++r) accw[r] = 0.f;
#pragma unroll
    for (int t = 0; t < 4; ++t) {
      bf16x8 ah = *(const bf16x8*)&AH[t][wm * 32 + ml][g8];
      bf16x8 al = *(const bf16x8*)&AL[t][wm * 32 + ml][g8];
      bf16x8 bh = *(const bf16x8*)&BH[t][wn * 32 + ml][g8];
      bf16x8 bl = *(const bf16x8*)&BL[t][wn * 32 + ml][g8];
      accw = __builtin_amdgcn_mfma_f32_32x32x16_bf16(ah, bh, accw, 0, 0, 0);
      accw = __builtin_amdgcn_mfma_f32_32x32x16_bf16(al, bh, accw, 0, 0, 0);
      accw = __builtin_amdgcn_mfma_f32_32x32x16_bf16(ah, bl, accw, 0, 0, 0);
    }
    const float bwv = bW[h * 64 + colw];
    const int ts = colw >> 4, ss = colw & 15;
#pragma unroll
    for (int r = 0; r < 16; ++r) {
      int rl = rowl0 + (r & 3) + 8 * (r >> 2);
      float v = accw[r] + bwv;
      v = v > 0.f ? v : __expf(v) - 1.f;
      unsigned short hv = f2bf(v);
      CH[ts][rl][ss] = (short)hv;
      CL[ts][rl][ss] = (short)f2bf(v - bf2f(hv));
    }
    __syncthreads();
#pragma unroll
    for (int t = 0; t < 4; ++t) {
      bf16x8 ah = *(const bf16x8*)&CH[t][wm * 32 + ml][g8];
      bf16x8 al = *(const bf16x8*)&CL[t][wm * 32 + ml][g8];
      bf16x8 bh = *(const bf16x8*)&DH[t][wn * 32 + ml][g8];
      bf16x8 bl = *(const bf16x8*)&DL[t][wn * 32 + ml][g8];
      acc2 = __builtin_amdgcn_mfma_f32_32x32x16_bf16(ah, bh, acc2, 0, 0, 0);
      acc2 = __builtin_amdgcn_mfma_f32_32x32x16_bf16(al, bh, acc2, 0, 0, 0);
      acc2 = __builtin_amdgcn_mfma_f32_32x32x16_bf16(ah, bl, acc2, 0, 0, 0);
    }
    __syncthreads();
  }

  // epilogue: partial FTS2 + partial f1o/f2o (no bias)
  float* FTS2p = FTS2 + (size_t)hg * NN * CDIM;
  const bool act = colw < CDIM;
  const float aov1 = act ? ao1[colw] : 0.f;
  const float aov2 = act ? ao2[colw] : 0.f;
#pragma unroll
  for (int r = 0; r < 16; ++r) {
    int rl = rowl0 + (r & 3) + 8 * (r >> 2);
    float v = acc2[r];
    if (act) FTS2p[(size_t)(i0 + rl) * CDIM + colw] = v;
    float p1 = v * aov1, p2 = v * aov2;
#pragma unroll
    for (int o = 1; o < 32; o <<= 1) {
      p1 += __shfl_xor(p1, o);
      p2 += __shfl_xor(p2, o);
    }
    if (ml == 0) {
      p1buf[wn][rl] = p1;
      p2buf[wn][rl] = p2;
    }
  }
  __syncthreads();
  if (tid < 64) {
    F1O[(size_t)hg * NN + i0 + tid] = p1buf[0][tid] + p1buf[1][tid];
    F2O[(size_t)hg * NN + i0 + tid] = p2buf[0][tid] + p2buf[1][tid];
  }
}

// ---------------- Kernel 5: layer-2 attention + output GEMM (sums parts) ----
__global__ __launch_bounds__(256) void k_agg2(
    const float* __restrict__ FTS2, const float* __restrict__ F1O,
    const float* __restrict__ F2O, const int* __restrict__ nbr,
    const int* __restrict__ cnt, const float* __restrict__ Wo2,
    const float* __restrict__ bo, const float* __restrict__ bo1s,
    const float* __restrict__ bo2s, float* __restrict__ out) {
  int i = blockIdx.x * 4 + (threadIdx.x >> 6);
  int lane = threadIdx.x & 63;
  int deg = cnt[i];
  const int* nb = nbr + (size_t)i * MAXD;
  const float* F2Ob = F2O + NN;
  const float* FTS2b = FTS2 + (size_t)NN * CDIM;
  // f1i includes both parts + bo1; fold bo2 in as well (added once per logit)
  float f1ib = F1O[i] + F1O[NN + i] + bo1s[0] + bo2s[0];

  int jreg[4];
  float p[4];
  float m = -1e30f;
#pragma unroll
  for (int r = 0; r < 4; ++r) { jreg[r] = 0; p[r] = -1e30f; }
#pragma unroll
  for (int r = 0; r < 4; ++r) {
    int t = r * 64 + lane;
    if (t < deg) {
      int j = nb[t];
      jreg[r] = j;
      float x = f1ib + F2O[j] + F2Ob[j];
      x = x >= 0.f ? x : 0.2f * x;
      p[r] = x;
      m = fmaxf(m, x);
    }
  }
  m = wave_max64(m);
  float s = 0.f;
#pragma unroll
  for (int r = 0; r < 4; ++r) {
    int t = r * 64 + lane;
    float e = (t < deg) ? __expf(p[r] - m) : 0.f;
    p[r] = e;
    s += e;
  }
  s = wave_sum64(s);

  const bool act = lane < CDIM;
  float accA = 0.f, accB = 0.f, accC = 0.f, accD = 0.f;
#pragma unroll
  for (int r = 0; r < 4; ++r) {
    int base = r * 64;
    if (base >= deg) break;
    int lim = deg - base;
    lim = lim < 64 ? lim : 64;
    int sl = 0;
    for (; sl + 4 <= lim; sl += 4) {
      float w0 = readlane_f(p[r], sl);
      float w1 = readlane_f(p[r], sl + 1);
      float w2 = readlane_f(p[r], sl + 2);
      float w3 = readlane_f(p[r], sl + 3);
      int j0 = readlane_i(jreg[r], sl);
      int j1 = readlane_i(jreg[r], sl + 1);
      int j2 = readlane_i(jreg[r], sl + 2);
      int j3 = readlane_i(jreg[r], sl + 3);
      float f0 = act ? (FTS2[(size_t)j0 * CDIM + lane] + FTS2b[(size_t)j0 * CDIM + lane]) : 0.f;
      float f1 = act ? (FTS2[(size_t)j1 * CDIM + lane] + FTS2b[(size_t)j1 * CDIM + lane]) : 0.f;
      float f2 = act ? (FTS2[(size_t)j2 * CDIM + lane] + FTS2b[(size_t)j2 * CDIM + lane]) : 0.f;
      float f3 = act ? (FTS2[(size_t)j3 * CDIM + lane] + FTS2b[(size_t)j3 * CDIM + lane]) : 0.f;
      accA += w0 * f0;
      accB += w1 * f1;
      accC += w2 * f2;
      accD += w3 * f3;
    }
    for (; sl < lim; ++sl) {
      float w0 = readlane_f(p[r], sl);
      int j0 = readlane_i(jreg[r], sl);
      float f0 = act ? (FTS2[(size_t)j0 * CDIM + lane] + FTS2b[(size_t)j0 * CDIM + lane]) : 0.f;
      accA += w0 * f0;
    }
  }
  float v = (accA + accB + accC + accD) / s;

  float o = act ? bo[lane] : 0.f;
  for (int kk = 0; kk < CDIM; ++kk) {
    float w = readlane_f(v, kk);
    float b = act ? Wo2[kk * CDIM + lane] : 0.f;
    o += w * b;
  }
  if (act) out[(size_t)i * CDIM + lane] = o;
}

extern "C" void kernel_launch(void* const* d_in, const int* in_sizes, int n_in,
                              void* d_out, int out_size, void* d_ws, size_t ws_size,
                              hipStream_t stream) {
  const float* seq  = (const float*)d_in[0];
  const float* bias = (const float*)d_in[1];
  const float* W1   = (const float*)d_in[2];
  const float* a1   = (const float*)d_in[3];
  const float* b1   = (const float*)d_in[4];
  const float* a2   = (const float*)d_in[5];
  const float* b2   = (const float*)d_in[6];
  const float* W2   = (const float*)d_in[7];
  const float* bW   = (const float*)d_in[8];
  const float* Wo1  = (const float*)d_in[9];
  const float* ao1  = (const float*)d_in[10];
  const float* bo1  = (const float*)d_in[11];
  const float* ao2  = (const float*)d_in[12];
  const float* bo2  = (const float*)d_in[13];
  const float* Wo2  = (const float*)d_in[14];
  const float* bo   = (const float*)d_in[15];
  float* out = (float*)d_out;

  float* ws    = (float*)d_ws;
  float* F1t   = ws;                          // N*8
  float* F2t   = F1t  + (size_t)NN * NHEAD;   // N*8
  float* FTS2  = F2t  + (size_t)NN * NHEAD;   // 2*N*40 (two head-group parts)
  float* F1O   = FTS2 + (size_t)2 * NN * CDIM; // 2*N
  float* F2O   = F1O  + 2 * NN;               // 2*N
  short* FTSb  = (short*)(F2O + 2 * NN);      // N*512 bf16
  short* Bhi   = FTSb + (size_t)NN * FDIM;    // 8*64*512
  short* Blo   = Bhi + (size_t)NHEAD * HDIM * FDIM;
  short* VALShi= Blo + (size_t)NHEAD * HDIM * FDIM;  // N*512
  short* VALSlo= VALShi + (size_t)NN * FDIM;
  short* W2thi = VALSlo + (size_t)NN * FDIM;         // 8*64*64
  short* W2tlo = W2thi + (size_t)NHEAD * HDIM * HDIM;
  short* Wo1thi= W2tlo + (size_t)NHEAD * HDIM * HDIM; // 64*512
  short* Wo1tlo= Wo1thi + (size_t)64 * FDIM;
  int*   nbr   = (int*)(Wo1tlo + (size_t)64 * FDIM);  // N*MAXD
  int*   cnt   = nbr + (size_t)NN * MAXD;     // N

  // 1. weight conversions
  k_prep<<<64 + 8 + 8, 256, 0, stream>>>(
      W1, Bhi, Blo, W2, W2thi, W2tlo, Wo1, Wo1thi, Wo1tlo);
  // 2. MFMA GEMM (in-reg seq cvt) + fused f1/f2  ∥  CSR build
  k_gemm<<<256 + NN, 256, 0, stream>>>(
      seq, Bhi, Blo, a1, b1, a2, b2, FTSb, F1t, F2t, bias, nbr, cnt);
  // 3. sparse softmax + aggregation (1 wave/row, 16B gathers, ILP4)
  k_agg1<<<NN / 4, 256, 0, stream>>>(FTSb, F1t, F2t, nbr, cnt, VALShi, VALSlo);
  // 4. split tail (2 head-groups x 64 row-tiles = 128 blocks)
  k_tail<<<NN / 64 * 2, 256, 0, stream>>>(VALShi, VALSlo, W2thi, W2tlo, bW,
                                          Wo1thi, Wo1tlo, ao1, ao2,
                                          FTS2, F1O, F2O);
  // 5. layer-2 sparse attention (sums tail parts) + final dense + bias
  k_agg2<<<NN / 4, 256, 0, stream>>>(FTS2, F1O, F2O, nbr, cnt, Wo2, bo,
                                     bo1, bo2, out);
}